// Round 14
// baseline (290.743 us; speedup 1.0000x reference)
//
#include <hip/hip_runtime.h>
#include <math.h>

#define NB 16
#define NPG 1024
#define DIN 16
#define ED 8
#define NHEADS 5
#define OUT1 6
#define HID 30
#define C1 32
#define C2 4
#define NN (NB*NPG)      // 16384 nodes
#define EE (NN*32)       // 524288 edges
#define EPG 32768        // edges per graph (graph-contiguous in edge_index)
#define CH 16            // chunks per graph
#define CE 2048          // edges per chunk

__device__ __forceinline__ float lrelu(float v){ return v >= 0.f ? v : 0.2f*v; }

// chunk mapping for 256-block edge kernels: XCD-affine, block -> (g, c)
__device__ __forceinline__ void chunk_gc(int& g, int& c){
    int x = blockIdx.x & 7;
    int j = blockIdx.x >> 3;     // 0..31
    g = x + 8*(j >> 4);          // 2 graphs per XCD
    c = j & 15;
}

// XCD-affinity mapping for 2048-block edge kernels
__device__ __forceinline__ size_t xcd_chunk_base(){
    int x = blockIdx.x & 7;
    int j = blockIdx.x >> 3;            // 0..255 position within this XCD
    int g = x + 8*(j >> 7);             // 2 graphs per XCD
    int c = j & 127;                    // 128 chunks per graph
    return (size_t)g*EPG + (size_t)c*256;
}

// ---------- merged: per-chunk dual LDS histograms (blocks 0..255) + node projection ----------
__global__ void k_hist_chunk(const int* __restrict__ src, const int* __restrict__ dst,
                             int* __restrict__ histD, int* __restrict__ histS,
                             const float* __restrict__ x, const float* __restrict__ W1,
                             const float* __restrict__ as1, const float* __restrict__ ad1,
                             float* __restrict__ h1, float* __restrict__ hs1, float* __restrict__ hd1){
    int t = threadIdx.x;
    if (blockIdx.x < 256){
        __shared__ int hD[NPG], hS[NPG];
        for (int i = t; i < NPG; i += 256){ hD[i] = 0; hS[i] = 0; }
        __syncthreads();
        int g, c; chunk_gc(g, c);
        size_t e0 = ((size_t)g*CH + c)*CE;
        #pragma unroll
        for (int i = 0; i < 8; i++){
            size_t e = e0 + i*256 + t;
            atomicAdd(&hD[dst[e] & (NPG-1)], 1);
            atomicAdd(&hS[src[e] & (NPG-1)], 1);
        }
        __syncthreads();
        size_t hb = ((size_t)g*CH + c)*NPG;
        for (int i = t; i < NPG; i += 256){
            histD[hb + i] = hD[i];
            histS[hb + i] = hS[i];
        }
        return;
    }
    // node projection part (blocks 256..319)
    __shared__ float Ws[DIN*HID];
    __shared__ float as_s[HID], ad_s[HID];
    for (int i = t; i < DIN*HID; i += blockDim.x) Ws[i] = W1[i];
    if (t < HID){ as_s[t] = as1[t]; ad_s[t] = ad1[t]; }
    __syncthreads();
    int n = (blockIdx.x - 256)*blockDim.x + t;
    if (n >= NN) return;
    float xv[DIN];
    #pragma unroll
    for (int i = 0; i < DIN; i++) xv[i] = x[n*DIN + i];
    float hv[HID];
    #pragma unroll
    for (int j = 0; j < HID; j++){
        float a = 0.f;
        #pragma unroll
        for (int i = 0; i < DIN; i++) a += xv[i]*Ws[i*HID + j];
        hv[j] = a; h1[(size_t)n*HID + j] = a;
    }
    #pragma unroll
    for (int h = 0; h < NHEADS; h++){
        float s = 0.f, d = 0.f;
        #pragma unroll
        for (int c2 = 0; c2 < OUT1; c2++){ s += hv[h*OUT1+c2]*as_s[h*OUT1+c2]; d += hv[h*OUT1+c2]*ad_s[h*OUT1+c2]; }
        hs1[n*NHEADS + h] = s; hd1[n*NHEADS + h] = d;
    }
}

// ---------- fused: per-(g,n) chunk scan (in place) + per-graph node scan -> rowptr ----------
// 32 blocks x 1024: blocks 0..15 -> histD/rowptr, 16..31 -> histS/rowptrS.
// Each graph has exactly EPG edges, so the node-prefix scan is graph-local.
__global__ __launch_bounds__(1024) void k_cumscan(int* __restrict__ histD, int* __restrict__ histS,
                                                  int* __restrict__ rowptr, int* __restrict__ rowptrS){
    __shared__ int wtot[16], wbase[16];
    bool isD = (blockIdx.x < NB);
    int b = isD ? blockIdx.x : (blockIdx.x - NB);
    int* hist = isD ? histD : histS;
    int* rp   = isD ? rowptr : rowptrS;
    int n = threadIdx.x;
    int run = 0;
    #pragma unroll
    for (int c = 0; c < CH; c++){
        size_t idx = ((size_t)b*CH + c)*NPG + n;
        int v = hist[idx];
        hist[idx] = run;
        run += v;
    }
    // run = deg of node (b,n); exclusive scan over n
    int lane = n & 63, wv = n >> 6;
    int sincl = run;
    #pragma unroll
    for (int off = 1; off < 64; off <<= 1){
        int v = __shfl_up(sincl, off, 64);
        if (lane >= off) sincl += v;
    }
    if (lane == 63) wtot[wv] = sincl;
    __syncthreads();
    if (n == 0){
        int r = 0;
        #pragma unroll
        for (int w = 0; w < 16; w++){ wbase[w] = r; r += wtot[w]; }
    }
    __syncthreads();
    int excl = wbase[wv] + sincl - run;
    rp[b*NPG + n] = b*EPG + excl;
    if (b == NB-1 && n == NPG-1) rp[NN] = EE;
}

// ---------- deterministic scatter: slot = rowptr + chunk-base + LDS rank (no global atomics) ----------
__global__ void k_scatter_det(const int* __restrict__ src, const int* __restrict__ dst,
                              const int* __restrict__ rowptr, const int* __restrict__ rowptrS,
                              const int* __restrict__ histD, const int* __restrict__ histS,
                              int* __restrict__ srcs, int* __restrict__ eid,
                              int* __restrict__ dsts, int* __restrict__ nbrS){
    __shared__ int baseD[NPG], baseS[NPG];
    int t = threadIdx.x;
    int g, c; chunk_gc(g, c);
    size_t hb = ((size_t)g*CH + c)*NPG;
    for (int i = t; i < NPG; i += 256){
        baseD[i] = rowptr[g*NPG + i] + histD[hb + i];
        baseS[i] = rowptrS[g*NPG + i] + histS[hb + i];
    }
    __syncthreads();
    size_t e0 = ((size_t)g*CH + c)*CE;
    #pragma unroll
    for (int i = 0; i < 8; i++){
        size_t e = e0 + i*256 + t;
        int s = src[e], d = dst[e];
        int p = atomicAdd(&baseD[d & (NPG-1)], 1);
        srcs[p] = s; eid[p] = (int)e; dsts[p] = d;
        int pS = atomicAdd(&baseS[s & (NPG-1)], 1);
        nbrS[pS] = d;
    }
}

// ---------- edge proj + conv1 LOGITS into per-head planes (2048 blocks) ----------
// lg1T[h*EE+k] = lrelu(hs1[s]+hd1[d]+ea[e]@We1[:,h]); ewp1s[k] = ea[e]@Wep1.
__global__ void k_elogit(const float* __restrict__ ea, const float* __restrict__ We1,
                         const float* __restrict__ Wep1,
                         const int* __restrict__ srcs, const int* __restrict__ eid,
                         const int* __restrict__ dsts,
                         const float* __restrict__ hs1, const float* __restrict__ hd1,
                         float* __restrict__ lg1T, float* __restrict__ ewp1s){
    __shared__ float W[ED*NHEADS];
    __shared__ float Wp[ED];
    int t = threadIdx.x;
    if (t < ED*NHEADS) W[t] = We1[t];
    if (t < ED) Wp[t] = Wep1[t];
    __syncthreads();
    size_t k = xcd_chunk_base() + t;
    int s = srcs[k], e = eid[k], d = dsts[k];
    float a[ED];
    #pragma unroll
    for (int i = 0; i < ED; i++) a[i] = ea[(size_t)e*ED + i];
    const float* hsr = hs1 + (size_t)s*NHEADS;
    const float* hdr = hd1 + (size_t)d*NHEADS;
    #pragma unroll
    for (int h = 0; h < NHEADS; h++){
        float sv = 0.f;
        #pragma unroll
        for (int i = 0; i < ED; i++) sv += a[i]*W[i*NHEADS + h];
        lg1T[(size_t)h*EE + k] = lrelu(hsr[h] + hdr[h] + sv);
    }
    float sv = 0.f;
    #pragma unroll
    for (int i = 0; i < ED; i++) sv += a[i]*Wp[i];
    ewp1s[k] = sv;
}

// ---------- dedup via per-thread LDS bitmap (64 blocks) ----------
__global__ void k_dedup(const int* __restrict__ rowptrS, const int* __restrict__ nbrS,
                        int* __restrict__ unbr, int* __restrict__ ucnt,
                        float* __restrict__ scal){
    __shared__ unsigned int bm[256*33];   // 33-word stride: bank = (t + w) & 31
    __shared__ int red[256];
    int t = threadIdx.x;
    unsigned int* mybm = &bm[t*33];
    #pragma unroll
    for (int i = 0; i < 32; i++) mybm[i] = 0u;
    int n = blockIdx.x*blockDim.x + t;
    int cnt = 0;
    if (n < NN){
        int k0 = rowptrS[n], k1 = rowptrS[n+1];
        for (int k = k0; k < k1; k++){
            int m = nbrS[k];
            int loc = m & (NPG-1);
            unsigned int w = (unsigned int)(loc >> 5);
            unsigned int bit = 1u << (loc & 31);
            unsigned int old = mybm[w];
            if (!(old & bit)){
                mybm[w] = old | bit;
                unbr[k0 + cnt] = m;
                cnt++;
            }
        }
        ucnt[n] = cnt;
    }
    red[t] = cnt; __syncthreads();
    for (int s = 128; s > 0; s >>= 1){ if (t < s) red[t] += red[t+s]; __syncthreads(); }
    if (t == 0) atomicAdd(&scal[0], (float)red[0]);
}

// ---------- conv1 aggregation: unit-stride logit plane + batched-4 h1 gathers ----------
__global__ void k_conv1_agg(const int* __restrict__ srcs, const int* __restrict__ rowptr,
                            const float* __restrict__ h1, const float* __restrict__ lg1T,
                            float* __restrict__ x1){
    int tid = blockIdx.x*blockDim.x + threadIdx.x;
    if (tid >= NN*NHEADS*2) return;
    int n = tid / (NHEADS*2);
    int r = tid - n*(NHEADS*2);
    int h = r >> 1;
    int q = r & 1;               // 3-channel half
    int k0 = rowptr[n], k1 = rowptr[n+1];
    const float* lgh = lg1T + (size_t)h*EE;
    float m = -INFINITY, den = 0.f;
    float acc[3] = {0.f, 0.f, 0.f};
    int k = k0;
    for (; k + 4 <= k1; k += 4){
        float l0 = lgh[k+0], l1 = lgh[k+1], l2 = lgh[k+2], l3 = lgh[k+3];
        int s0 = srcs[k+0], s1 = srcs[k+1], s2 = srcs[k+2], s3 = srcs[k+3];
        const float* p0 = h1 + (size_t)s0*HID + h*OUT1 + q*3;
        const float* p1 = h1 + (size_t)s1*HID + h*OUT1 + q*3;
        const float* p2 = h1 + (size_t)s2*HID + h*OUT1 + q*3;
        const float* p3 = h1 + (size_t)s3*HID + h*OUT1 + q*3;
        float mb = fmaxf(fmaxf(l0, l1), fmaxf(l2, l3));
        float mn = fmaxf(m, mb);
        float f  = expf(m - mn);       // first batch: exp(-inf)=0
        float e0 = expf(l0 - mn), e1 = expf(l1 - mn);
        float e2 = expf(l2 - mn), e3 = expf(l3 - mn);
        m = mn;
        den = den*f + e0 + e1 + e2 + e3;
        #pragma unroll
        for (int c = 0; c < 3; c++)
            acc[c] = acc[c]*f + e0*p0[c] + e1*p1[c] + e2*p2[c] + e3*p3[c];
    }
    for (; k < k1; k++){
        float l = lgh[k];
        int s = srcs[k];
        float mn = fmaxf(m, l);
        float f  = expf(m - mn);
        float ex = expf(l - mn);
        m = mn;
        den = den*f + ex;
        const float* hr = h1 + (size_t)s*HID + h*OUT1 + q*3;
        #pragma unroll
        for (int c = 0; c < 3; c++) acc[c] = acc[c]*f + ex*hr[c];
    }
    float inv = 1.f / (den + 1e-16f);
    #pragma unroll
    for (int c = 0; c < 3; c++) x1[(size_t)n*HID + h*OUT1 + q*3 + c] = acc[c]*inv;
}

// ---------- pool-conv1 prep: hp1 = x1@Wp1 (30x32); scalars ----------
__global__ void k_node_proj_p1(const float* __restrict__ x1, const float* __restrict__ Wp1,
                               const float* __restrict__ asp, const float* __restrict__ adp,
                               float* __restrict__ hp1, float* __restrict__ hsp, float* __restrict__ hdp){
    __shared__ float Ws[HID*C1];
    __shared__ float as_s[C1], ad_s[C1];
    for (int i = threadIdx.x; i < HID*C1; i += blockDim.x) Ws[i] = Wp1[i];
    if (threadIdx.x < C1){ as_s[threadIdx.x] = asp[threadIdx.x]; ad_s[threadIdx.x] = adp[threadIdx.x]; }
    __syncthreads();
    int n = blockIdx.x*blockDim.x + threadIdx.x;
    if (n >= NN) return;
    float xv[HID];
    #pragma unroll
    for (int d = 0; d < HID; d++) xv[d] = x1[(size_t)n*HID + d];
    float s = 0.f, dd = 0.f;
    for (int c = 0; c < C1; c++){
        float a = 0.f;
        #pragma unroll
        for (int d = 0; d < HID; d++) a += xv[d]*Ws[d*C1 + c];
        hp1[(size_t)n*C1 + c] = a;
        s += a*as_s[c]; dd += a*ad_s[c];
    }
    hsp[n] = s; hdp[n] = dd;
}

// ---------- pool logits: all-coalesced reads ----------
__global__ void k_plogit(const int* __restrict__ srcs, const int* __restrict__ dsts,
                         const float* __restrict__ hsp, const float* __restrict__ hdp,
                         const float* __restrict__ ewp1s, float* __restrict__ lgp){
    size_t k = xcd_chunk_base() + threadIdx.x;
    lgp[k] = lrelu(hsp[srcs[k]] + hdp[dsts[k]] + ewp1s[k]);
}

// ---------- pool-conv1 aggregation + fused cluster softmax (LDS exchange) ----------
__global__ void k_pool1_agg(const int* __restrict__ srcs, const int* __restrict__ rowptr,
                            const float* __restrict__ hp1, const float* __restrict__ lgp,
                            float* __restrict__ ssoft){
    __shared__ float sm[32*33];   // 32 nodes/block, padded row 33
    int tid = blockIdx.x*blockDim.x + threadIdx.x;
    int q = tid & 7;
    int n = tid >> 3;
    int nl = threadIdx.x >> 3;    // node-local 0..31
    int k0 = rowptr[n], k1 = rowptr[n+1];
    float m = -INFINITY, den = 0.f;
    float acc[4] = {0.f, 0.f, 0.f, 0.f};
    int k = k0;
    for (; k + 4 <= k1; k += 4){
        float l0 = lgp[k+0], l1 = lgp[k+1], l2 = lgp[k+2], l3 = lgp[k+3];
        int s0 = srcs[k+0], s1n = srcs[k+1], s2 = srcs[k+2], s3 = srcs[k+3];
        float4 v0 = *(const float4*)(hp1 + (size_t)s0*C1 + q*4);
        float4 v1 = *(const float4*)(hp1 + (size_t)s1n*C1 + q*4);
        float4 v2 = *(const float4*)(hp1 + (size_t)s2*C1 + q*4);
        float4 v3 = *(const float4*)(hp1 + (size_t)s3*C1 + q*4);
        float mb = fmaxf(fmaxf(l0, l1), fmaxf(l2, l3));
        float mn = fmaxf(m, mb);
        float f  = expf(m - mn);
        float e0 = expf(l0 - mn), e1 = expf(l1 - mn);
        float e2 = expf(l2 - mn), e3 = expf(l3 - mn);
        m = mn;
        den = den*f + e0 + e1 + e2 + e3;
        acc[0] = acc[0]*f + e0*v0.x + e1*v1.x + e2*v2.x + e3*v3.x;
        acc[1] = acc[1]*f + e0*v0.y + e1*v1.y + e2*v2.y + e3*v3.y;
        acc[2] = acc[2]*f + e0*v0.z + e1*v1.z + e2*v2.z + e3*v3.z;
        acc[3] = acc[3]*f + e0*v0.w + e1*v1.w + e2*v2.w + e3*v3.w;
    }
    for (; k < k1; k++){
        float l = lgp[k];
        int s = srcs[k];
        float mn = fmaxf(m, l);
        float f  = expf(m - mn);
        float ex = expf(l - mn);
        m = mn;
        den = den*f + ex;
        const float* hr = hp1 + (size_t)s*C1 + q*4;
        #pragma unroll
        for (int c = 0; c < 4; c++) acc[c] = acc[c]*f + ex*hr[c];
    }
    float inv = 1.f / (den + 1e-16f);
    #pragma unroll
    for (int c = 0; c < 4; c++) sm[nl*33 + q*4 + c] = acc[c]*inv;
    __syncthreads();
    // cluster softmax over the node's 32 channels (redundant per slice-thread)
    float mx = -INFINITY;
    #pragma unroll 8
    for (int i = 0; i < C1; i++) mx = fmaxf(mx, sm[nl*33 + i]);
    float sum = 0.f;
    #pragma unroll 8
    for (int i = 0; i < C1; i++) sum += expf(sm[nl*33 + i] - mx);
    float is = 1.f/sum;
    #pragma unroll
    for (int c = 0; c < 4; c++)
        ssoft[(size_t)n*C1 + q*4 + c] = expf(sm[nl*33 + q*4 + c] - mx)*is;
}

// ---------- T[n,:] = sum over unique out-neighbors, batched-4 float4 gathers ----------
__global__ void k_T(const int* __restrict__ rowptrS, const int* __restrict__ unbr,
                    const int* __restrict__ ucnt, const float* __restrict__ ssoft,
                    float* __restrict__ T){
    int tid = blockIdx.x*blockDim.x + threadIdx.x;
    if (tid >= NN*8) return;
    int q = tid & 7;
    int n = tid >> 3;
    int k0 = rowptrS[n];
    int cnt = ucnt[n];
    float acc[4] = {0.f, 0.f, 0.f, 0.f};
    int i = 0;
    for (; i + 4 <= cnt; i += 4){
        int m0 = unbr[k0+i+0], m1 = unbr[k0+i+1], m2 = unbr[k0+i+2], m3 = unbr[k0+i+3];
        float4 v0 = *(const float4*)(ssoft + (size_t)m0*C1 + q*4);
        float4 v1 = *(const float4*)(ssoft + (size_t)m1*C1 + q*4);
        float4 v2 = *(const float4*)(ssoft + (size_t)m2*C1 + q*4);
        float4 v3 = *(const float4*)(ssoft + (size_t)m3*C1 + q*4);
        acc[0] += v0.x + v1.x + v2.x + v3.x;
        acc[1] += v0.y + v1.y + v2.y + v3.y;
        acc[2] += v0.z + v1.z + v2.z + v3.z;
        acc[3] += v0.w + v1.w + v2.w + v3.w;
    }
    for (; i < cnt; i++){
        int m = unbr[k0 + i];
        const float* sr = ssoft + (size_t)m*C1 + q*4;
        #pragma unroll
        for (int c = 0; c < 4; c++) acc[c] += sr[c];
    }
    #pragma unroll
    for (int c = 0; c < 4; c++) T[(size_t)n*C1 + q*4 + c] = acc[c];
}

// ---------- fused partials over 64-node chunks ----------
__global__ void k_partials(const float* __restrict__ ssoft, const float* __restrict__ T,
                           const float* __restrict__ x1,
                           float* __restrict__ adj2, float* __restrict__ Gm,
                           float* __restrict__ x2){
    int b  = blockIdx.y;
    int n0 = blockIdx.x * 64;
    int t  = threadIdx.x;   // 256
    __shared__ float ssh[64*C1];
    __shared__ float tsh[64*C1];
    __shared__ float xsh[64*HID];
    {
        size_t sbase = ((size_t)b*NPG + n0)*C1;
        #pragma unroll
        for (int i = 0; i < 8; i++){
            int lin = t + i*256;
            ssh[lin] = ssoft[sbase + lin];
            tsh[lin] = T[sbase + lin];
        }
        size_t xbase = ((size_t)b*NPG + n0)*HID;
        for (int lin = t; lin < 64*HID; lin += 256) xsh[lin] = x1[xbase + lin];
    }
    __syncthreads();
    float accA[4] = {0,0,0,0}, accG[4] = {0,0,0,0}, accX[4] = {0,0,0,0};
    int cA[4], kA[4], cX[4], dX[4];
    #pragma unroll
    for (int q = 0; q < 4; q++){
        int p = t + q*256;
        cA[q] = p >> 5; kA[q] = p & 31;
        cX[q] = p / HID; dX[q] = p - cX[q]*HID;   // valid only when p < 960
    }
    for (int r = 0; r < 64; r++){
        const float* sr = ssh + r*C1;
        const float* tr = tsh + r*C1;
        const float* xr = xsh + r*HID;
        #pragma unroll
        for (int q = 0; q < 4; q++){
            float sc = sr[cA[q]];
            accA[q] += sc*tr[kA[q]];
            accG[q] += sc*sr[kA[q]];
        }
        #pragma unroll
        for (int q = 0; q < 4; q++){
            int p = t + q*256;
            if (p < C1*HID) accX[q] += sr[cX[q]]*xr[dX[q]];
        }
    }
    #pragma unroll
    for (int q = 0; q < 4; q++){
        int p = t + q*256;
        atomicAdd(&adj2[(size_t)b*1024 + p], accA[q]);
        atomicAdd(&Gm[(size_t)b*1024 + p], accG[q]);
        if (p < C1*HID) atomicAdd(&x2[((size_t)b*C1 + cX[q])*HID + dX[q]], accX[q]);
    }
}

// ---------- fused tail: finalize(reg1 parts) + pool-conv2 + diffpool2 + per-graph MLP ----------
__global__ void k_tail(const float* __restrict__ x2, const float* __restrict__ adj2,
                       const float* __restrict__ Gm,
                       const float* __restrict__ Wp2, const float* __restrict__ asp,
                       const float* __restrict__ adp, const float* __restrict__ Wep2,
                       const float* __restrict__ Wf1, const float* __restrict__ bf1,
                       const float* __restrict__ Wf2, const float* __restrict__ bf2,
                       float* __restrict__ out, float* __restrict__ scal){
    int b = blockIdx.x;
    int t = threadIdx.x;  // 256
    __shared__ float x2s[C1*HID];    // 960
    __shared__ float a2s[C1*C1];     // 1024
    __shared__ float Wps[HID*C2];    // 120
    __shared__ float h2s[C1*C2];
    __shared__ float hs2s[C1], hd2s[C1];
    __shared__ float sss[C1*C2];     // softmax(s2)
    __shared__ float x3s[C2*HID];    // 120
    __shared__ float zsh[32];
    __shared__ float red[256];
    for (int i = t; i < C1*HID; i += 256) x2s[i] = x2[(size_t)b*C1*HID + i];
    for (int i = t; i < C1*C1; i += 256) a2s[i] = adj2[(size_t)b*C1*C1 + i];
    if (t < HID*C2) Wps[t] = Wp2[t];
    __syncthreads();
    // finalize reg1 ingredients from this graph: trace(adj2), ||G||_F^2
    {
        float ltr = 0.f, lfr = 0.f;
        for (int p = t; p < 1024; p += 256){
            float g = Gm[(size_t)b*1024 + p];
            lfr += g*g;
            if ((p >> 5) == (p & 31)) ltr += a2s[p];
        }
        red[t] = ltr; __syncthreads();
        for (int s = 128; s > 0; s >>= 1){ if (t < s) red[t] += red[t+s]; __syncthreads(); }
        if (t == 0) atomicAdd(&scal[1], red[0]);
        __syncthreads();
        red[t] = lfr; __syncthreads();
        for (int s = 128; s > 0; s >>= 1){ if (t < s) red[t] += red[t+s]; __syncthreads(); }
        if (t == 0) atomicAdd(&scal[2], red[0]);
        __syncthreads();
    }
    // phase 1: h2 = x2@Wp2 + attention scalars
    if (t < C1){
        float s = 0.f, dd = 0.f;
        #pragma unroll
        for (int c = 0; c < C2; c++){
            float a = 0.f;
            #pragma unroll
            for (int d = 0; d < HID; d++) a += x2s[t*HID + d]*Wps[d*C2 + c];
            h2s[t*C2 + c] = a;
            s += a*asp[c]; dd += a*adp[c];
        }
        hs2s[t] = s; hd2s[t] = dd;
    }
    __syncthreads();
    // phase 2: dense EGAT agg over 32 sources + softmax over C2
    if (t < C1){
        int j = t;
        float hdv = hd2s[j];
        float wep = Wep2[0];
        float m = -INFINITY;
        for (int i = 0; i < C1; i++)
            m = fmaxf(m, lrelu(hs2s[i] + hdv + a2s[i*C1 + j]*wep));
        float den = 0.f;
        float acc[C2] = {0,0,0,0};
        for (int i = 0; i < C1; i++){
            float ex = expf(lrelu(hs2s[i] + hdv + a2s[i*C1 + j]*wep) - m);
            den += ex;
            #pragma unroll
            for (int c = 0; c < C2; c++) acc[c] += ex * h2s[i*C2 + c];
        }
        float inv = 1.f/(den + 1e-16f);
        float v[C2]; float mx = -INFINITY;
        #pragma unroll
        for (int c = 0; c < C2; c++){ v[c] = acc[c]*inv; mx = fmaxf(mx, v[c]); }
        float sum = 0.f;
        #pragma unroll
        for (int c = 0; c < C2; c++){ v[c] = expf(v[c] - mx); sum += v[c]; }
        float i2 = 1.f/sum;
        #pragma unroll
        for (int c = 0; c < C2; c++) sss[j*C2 + c] = v[c]*i2;
    }
    __syncthreads();
    // phase 3: x3 = S^T x2 (LDS only) and reg2
    if (t < C2*HID){
        int c = t / HID, d = t % HID;
        float a = 0.f;
        #pragma unroll
        for (int n = 0; n < C1; n++) a += sss[n*C2 + c]*x2s[n*HID + d];
        x3s[t] = a;
    }
    {
        float loc = 0.f;
        for (int p = t; p < 1024; p += 256){
            int n = p >> 5, mm = p & 31;
            float dot = 0.f;
            #pragma unroll
            for (int c = 0; c < C2; c++) dot += sss[n*C2 + c]*sss[mm*C2 + c];
            float df = a2s[p] - dot;
            loc += df*df;
        }
        red[t] = loc; __syncthreads();
        for (int s = 128; s > 0; s >>= 1){ if (t < s) red[t] += red[t+s]; __syncthreads(); }
        if (t == 0) atomicAdd(&scal[3], red[0]);
        __syncthreads();
    }
    // phase 4: per-graph MLP -> out[2b], out[2b+1]
    if (t < 32){
        float a = bf1[t];
        #pragma unroll 4
        for (int k = 0; k < C2*HID; k++) a += x3s[k]*Wf1[k*32 + t];
        zsh[t] = fmaxf(a, 0.f);
    }
    __syncthreads();
    if (t < 2){
        float a = bf2[t];
        #pragma unroll
        for (int j = 0; j < 32; j++) a += zsh[j]*Wf2[j*2 + t];
        out[b*2 + t] = a;
    }
}

// ---------- reg assembly (after all k_tail atomics) ----------
__global__ void k_reg(const float* __restrict__ scal, float* __restrict__ out){
    if (threadIdx.x == 0){
        float adjsum = scal[0], tr = scal[1], fr = scal[2], r2 = scal[3];
        float reg1 = (adjsum - 2.f*tr + fr) * (1.f/16777216.f);
        float reg2 = r2 * (1.f/16384.f);
        out[32] = 10.f*reg1 + 0.1f*reg2;
    }
}

extern "C" void kernel_launch(void* const* d_in, const int* in_sizes, int n_in,
                              void* d_out, int out_size, void* d_ws, size_t ws_size,
                              hipStream_t stream) {
    const float* x    = (const float*)d_in[0];
    const int*   ei   = (const int*)d_in[1];
    const float* ea   = (const float*)d_in[2];
    // d_in[3] = y (unused); d_in[4] = adj (algebraically eliminated — never read)
    const float* W1   = (const float*)d_in[5];
    const float* as1  = (const float*)d_in[6];
    const float* ad1  = (const float*)d_in[7];
    const float* We1  = (const float*)d_in[8];
    const float* Wp1  = (const float*)d_in[9];
    const float* asp1 = (const float*)d_in[10];
    const float* adp1 = (const float*)d_in[11];
    const float* Wep1 = (const float*)d_in[12];
    const float* Wp2  = (const float*)d_in[13];
    const float* asp2 = (const float*)d_in[14];
    const float* adp2 = (const float*)d_in[15];
    const float* Wep2 = (const float*)d_in[16];
    const float* Wf1  = (const float*)d_in[17];
    const float* bf1  = (const float*)d_in[18];
    const float* Wf2  = (const float*)d_in[19];
    const float* bf2  = (const float*)d_in[20];
    float* out = (float*)d_out;

    const int* srcA = ei;
    const int* dstA = ei + EE;

    char* wp = (char*)d_ws;
    auto carve = [&](size_t bytes)->char*{
        char* p = wp;
        wp += (bytes + 255) & ~(size_t)255;
        return p;
    };
    float* h1    = (float*)carve((size_t)NN*HID*4);
    float* hs1   = (float*)carve((size_t)NN*NHEADS*4);
    float* hd1   = (float*)carve((size_t)NN*NHEADS*4);
    float* lg1T  = (float*)carve((size_t)EE*NHEADS*4);
    float* ewp1s = (float*)carve((size_t)EE*4);
    float* lgp   = (float*)carve((size_t)EE*4);
    float* x1    = (float*)carve((size_t)NN*HID*4);
    float* hp1   = (float*)carve((size_t)NN*C1*4);
    float* hsp   = (float*)carve((size_t)NN*4);
    float* hdp   = (float*)carve((size_t)NN*4);
    float* ssoft = (float*)carve((size_t)NN*C1*4);
    float* T     = (float*)carve((size_t)NN*C1*4);
    // --- zero-init region (contiguous): x2, adj2, Gm ---
    float* x2    = (float*)carve((size_t)NB*C1*HID*4);   // 61440 B (256-aligned)
    float* adj2  = (float*)carve((size_t)NB*C1*C1*4);    // 65536 B
    float* Gm    = (float*)carve((size_t)NB*C1*C1*4);    // 65536 B
    // ---------------------------------------------------
    float* scal  = (float*)carve(16*4);
    int* histD   = (int*)carve((size_t)NB*CH*NPG*4);     // 1 MB
    int* histS   = (int*)carve((size_t)NB*CH*NPG*4);     // 1 MB
    int* rowptr  = (int*)carve((size_t)(NN+1)*4);
    int* rowptrS = (int*)carve((size_t)(NN+1)*4);
    int* srcs    = (int*)carve((size_t)EE*4);
    int* eid     = (int*)carve((size_t)EE*4);
    int* dsts    = (int*)carve((size_t)EE*4);
    int* nbrS    = (int*)carve((size_t)EE*4);
    int* unbr    = (int*)carve((size_t)EE*4);
    int* ucnt    = (int*)carve((size_t)NN*4);

    hipMemsetAsync(scal, 0, 16*4, stream);
    hipMemsetAsync(x2, 0, (size_t)(NB*C1*HID + 2*NB*C1*C1)*4, stream);  // x2+adj2+Gm

    const int TB = 256;
    dim3 gN((NN + TB - 1)/TB);

    // merged: per-chunk dual LDS histograms (256 blocks) + node projection (64 blocks)
    k_hist_chunk<<<dim3(256 + 64), TB, 0, stream>>>(srcA, dstA, histD, histS,
                                                    x, W1, as1, ad1, h1, hs1, hd1);
    // fused chunk-scan + per-graph node scan -> rowptr/rowptrS
    k_cumscan<<<dim3(2*NB), 1024, 0, stream>>>(histD, histS, rowptr, rowptrS);
    // deterministic scatter (LDS atomics only)
    k_scatter_det<<<dim3(256), TB, 0, stream>>>(srcA, dstA, rowptr, rowptrS,
                                                histD, histS, srcs, eid, dsts, nbrS);

    // edge proj + conv1 logit planes, then dedup
    k_elogit<<<dim3(2048), TB, 0, stream>>>(ea, We1, Wep1, srcs, eid, dsts, hs1, hd1, lg1T, ewp1s);
    k_dedup<<<dim3(NN/TB), TB, 0, stream>>>(rowptrS, nbrS, unbr, ucnt, scal);

    // conv1: unit-stride logit plane + batched-4 h1 gathers
    k_conv1_agg<<<dim3(NN*NHEADS*2/TB), TB, 0, stream>>>(srcs, rowptr, h1, lg1T, x1);

    // pool-conv1 (+fused cluster softmax)
    k_node_proj_p1<<<gN, TB, 0, stream>>>(x1, Wp1, asp1, adp1, hp1, hsp, hdp);
    k_plogit<<<dim3(2048), TB, 0, stream>>>(srcs, dsts, hsp, hdp, ewp1s, lgp);
    k_pool1_agg<<<dim3(NN*8/TB), TB, 0, stream>>>(srcs, rowptr, hp1, lgp, ssoft);

    // diffpool1
    k_T<<<dim3(NN*8/TB), TB, 0, stream>>>(rowptrS, unbr, ucnt, ssoft, T);
    k_partials<<<dim3(16, NB), TB, 0, stream>>>(ssoft, T, x1, adj2, Gm, x2);

    // fused tail: finalize + pool-conv2 + diffpool2 + per-graph MLP
    k_tail<<<dim3(NB), TB, 0, stream>>>(x2, adj2, Gm, Wp2, asp2, adp2, Wep2,
                                        Wf1, bf1, Wf2, bf2, out, scal);

    // reg assembly
    k_reg<<<1, 64, 0, stream>>>(scal, out);
}

// Round 15
// 288.017 us; speedup vs baseline: 1.0095x; 1.0095x over previous
//
#include <hip/hip_runtime.h>
#include <math.h>

#define NB 16
#define NPG 1024
#define DIN 16
#define ED 8
#define NHEADS 5
#define OUT1 6
#define HID 30
#define C1 32
#define C2 4
#define NN (NB*NPG)      // 16384 nodes
#define EE (NN*32)       // 524288 edges
#define EPG 32768        // edges per graph (graph-contiguous in edge_index)
#define CH 16            // chunks per graph
#define CE 2048          // edges per chunk

__device__ __forceinline__ float lrelu(float v){ return v >= 0.f ? v : 0.2f*v; }

// chunk mapping for 256-block edge kernels: XCD-affine, block -> (g, c)
__device__ __forceinline__ void chunk_gc(int& g, int& c){
    int x = blockIdx.x & 7;
    int j = blockIdx.x >> 3;     // 0..31
    g = x + 8*(j >> 4);          // 2 graphs per XCD
    c = j & 15;
}

// XCD-affinity mapping for 2048-block edge kernels
__device__ __forceinline__ size_t xcd_chunk_base(){
    int x = blockIdx.x & 7;
    int j = blockIdx.x >> 3;            // 0..255 position within this XCD
    int g = x + 8*(j >> 7);             // 2 graphs per XCD
    int c = j & 127;                    // 128 chunks per graph
    return (size_t)g*EPG + (size_t)c*256;
}

// ---------- merged: per-chunk dual LDS histograms (blocks 0..255) + node projection ----------
__global__ void k_hist_chunk(const int* __restrict__ src, const int* __restrict__ dst,
                             int* __restrict__ histD, int* __restrict__ histS,
                             const float* __restrict__ x, const float* __restrict__ W1,
                             const float* __restrict__ as1, const float* __restrict__ ad1,
                             float* __restrict__ h1, float* __restrict__ hs1, float* __restrict__ hd1){
    int t = threadIdx.x;
    if (blockIdx.x < 256){
        __shared__ int hD[NPG], hS[NPG];
        for (int i = t; i < NPG; i += 256){ hD[i] = 0; hS[i] = 0; }
        __syncthreads();
        int g, c; chunk_gc(g, c);
        size_t e0 = ((size_t)g*CH + c)*CE;
        #pragma unroll
        for (int i = 0; i < 8; i++){
            size_t e = e0 + i*256 + t;
            atomicAdd(&hD[dst[e] & (NPG-1)], 1);
            atomicAdd(&hS[src[e] & (NPG-1)], 1);
        }
        __syncthreads();
        size_t hb = ((size_t)g*CH + c)*NPG;
        for (int i = t; i < NPG; i += 256){
            histD[hb + i] = hD[i];
            histS[hb + i] = hS[i];
        }
        return;
    }
    // node projection part (blocks 256..319)
    __shared__ float Ws[DIN*HID];
    __shared__ float as_s[HID], ad_s[HID];
    for (int i = t; i < DIN*HID; i += blockDim.x) Ws[i] = W1[i];
    if (t < HID){ as_s[t] = as1[t]; ad_s[t] = ad1[t]; }
    __syncthreads();
    int n = (blockIdx.x - 256)*blockDim.x + t;
    if (n >= NN) return;
    float xv[DIN];
    #pragma unroll
    for (int i = 0; i < DIN; i++) xv[i] = x[n*DIN + i];
    float hv[HID];
    #pragma unroll
    for (int j = 0; j < HID; j++){
        float a = 0.f;
        #pragma unroll
        for (int i = 0; i < DIN; i++) a += xv[i]*Ws[i*HID + j];
        hv[j] = a; h1[(size_t)n*HID + j] = a;
    }
    #pragma unroll
    for (int h = 0; h < NHEADS; h++){
        float s = 0.f, d = 0.f;
        #pragma unroll
        for (int c2 = 0; c2 < OUT1; c2++){ s += hv[h*OUT1+c2]*as_s[h*OUT1+c2]; d += hv[h*OUT1+c2]*ad_s[h*OUT1+c2]; }
        hs1[n*NHEADS + h] = s; hd1[n*NHEADS + h] = d;
    }
}

// ---------- fused: per-(g,n) chunk scan (in place) + per-graph node scan -> rowptr ----------
__global__ __launch_bounds__(1024) void k_cumscan(int* __restrict__ histD, int* __restrict__ histS,
                                                  int* __restrict__ rowptr, int* __restrict__ rowptrS){
    __shared__ int wtot[16], wbase[16];
    bool isD = (blockIdx.x < NB);
    int b = isD ? blockIdx.x : (blockIdx.x - NB);
    int* hist = isD ? histD : histS;
    int* rp   = isD ? rowptr : rowptrS;
    int n = threadIdx.x;
    int run = 0;
    #pragma unroll
    for (int c = 0; c < CH; c++){
        size_t idx = ((size_t)b*CH + c)*NPG + n;
        int v = hist[idx];
        hist[idx] = run;
        run += v;
    }
    int lane = n & 63, wv = n >> 6;
    int sincl = run;
    #pragma unroll
    for (int off = 1; off < 64; off <<= 1){
        int v = __shfl_up(sincl, off, 64);
        if (lane >= off) sincl += v;
    }
    if (lane == 63) wtot[wv] = sincl;
    __syncthreads();
    if (n == 0){
        int r = 0;
        #pragma unroll
        for (int w = 0; w < 16; w++){ wbase[w] = r; r += wtot[w]; }
    }
    __syncthreads();
    int excl = wbase[wv] + sincl - run;
    rp[b*NPG + n] = b*EPG + excl;
    if (b == NB-1 && n == NPG-1) rp[NN] = EE;
}

// ---------- deterministic scatter: slot = rowptr + chunk-base + LDS rank (no global atomics) ----------
__global__ void k_scatter_det(const int* __restrict__ src, const int* __restrict__ dst,
                              const int* __restrict__ rowptr, const int* __restrict__ rowptrS,
                              const int* __restrict__ histD, const int* __restrict__ histS,
                              int* __restrict__ srcs, int* __restrict__ eid,
                              int* __restrict__ dsts, int* __restrict__ nbrS){
    __shared__ int baseD[NPG], baseS[NPG];
    int t = threadIdx.x;
    int g, c; chunk_gc(g, c);
    size_t hb = ((size_t)g*CH + c)*NPG;
    for (int i = t; i < NPG; i += 256){
        baseD[i] = rowptr[g*NPG + i] + histD[hb + i];
        baseS[i] = rowptrS[g*NPG + i] + histS[hb + i];
    }
    __syncthreads();
    size_t e0 = ((size_t)g*CH + c)*CE;
    #pragma unroll
    for (int i = 0; i < 8; i++){
        size_t e = e0 + i*256 + t;
        int s = src[e], d = dst[e];
        int p = atomicAdd(&baseD[d & (NPG-1)], 1);
        srcs[p] = s; eid[p] = (int)e; dsts[p] = d;
        int pS = atomicAdd(&baseS[s & (NPG-1)], 1);
        nbrS[pS] = d;
    }
}

// ---------- edge proj + conv1 LOGITS into per-head planes (2048 blocks) ----------
__global__ void k_elogit(const float* __restrict__ ea, const float* __restrict__ We1,
                         const float* __restrict__ Wep1,
                         const int* __restrict__ srcs, const int* __restrict__ eid,
                         const int* __restrict__ dsts,
                         const float* __restrict__ hs1, const float* __restrict__ hd1,
                         float* __restrict__ lg1T, float* __restrict__ ewp1s){
    __shared__ float W[ED*NHEADS];
    __shared__ float Wp[ED];
    int t = threadIdx.x;
    if (t < ED*NHEADS) W[t] = We1[t];
    if (t < ED) Wp[t] = Wep1[t];
    __syncthreads();
    size_t k = xcd_chunk_base() + t;
    int s = srcs[k], e = eid[k], d = dsts[k];
    float a[ED];
    #pragma unroll
    for (int i = 0; i < ED; i++) a[i] = ea[(size_t)e*ED + i];
    const float* hsr = hs1 + (size_t)s*NHEADS;
    const float* hdr = hd1 + (size_t)d*NHEADS;
    #pragma unroll
    for (int h = 0; h < NHEADS; h++){
        float sv = 0.f;
        #pragma unroll
        for (int i = 0; i < ED; i++) sv += a[i]*W[i*NHEADS + h];
        lg1T[(size_t)h*EE + k] = lrelu(hsr[h] + hdr[h] + sv);
    }
    float sv = 0.f;
    #pragma unroll
    for (int i = 0; i < ED; i++) sv += a[i]*Wp[i];
    ewp1s[k] = sv;
}

// ---------- dedup via per-thread LDS bitmap (64 blocks) ----------
__global__ void k_dedup(const int* __restrict__ rowptrS, const int* __restrict__ nbrS,
                        int* __restrict__ unbr, int* __restrict__ ucnt,
                        float* __restrict__ scal){
    __shared__ unsigned int bm[256*33];   // 33-word stride: bank = (t + w) & 31
    __shared__ int red[256];
    int t = threadIdx.x;
    unsigned int* mybm = &bm[t*33];
    #pragma unroll
    for (int i = 0; i < 32; i++) mybm[i] = 0u;
    int n = blockIdx.x*blockDim.x + t;
    int cnt = 0;
    if (n < NN){
        int k0 = rowptrS[n], k1 = rowptrS[n+1];
        for (int k = k0; k < k1; k++){
            int m = nbrS[k];
            int loc = m & (NPG-1);
            unsigned int w = (unsigned int)(loc >> 5);
            unsigned int bit = 1u << (loc & 31);
            unsigned int old = mybm[w];
            if (!(old & bit)){
                mybm[w] = old | bit;
                unbr[k0 + cnt] = m;
                cnt++;
            }
        }
        ucnt[n] = cnt;
    }
    red[t] = cnt; __syncthreads();
    for (int s = 128; s > 0; s >>= 1){ if (t < s) red[t] += red[t+s]; __syncthreads(); }
    if (t == 0) atomicAdd(&scal[0], (float)red[0]);
}

// ---------- conv1 aggregation: pair-split edges + shfl combine ----------
// 20 threads/node: (head, q-half, edge-half); edge-half pairs are adjacent lanes.
__global__ void k_conv1_agg(const int* __restrict__ srcs, const int* __restrict__ rowptr,
                            const float* __restrict__ h1, const float* __restrict__ lg1T,
                            float* __restrict__ x1){
    int tid = blockIdx.x*blockDim.x + threadIdx.x;
    if (tid >= NN*NHEADS*4) return;
    int n = tid / (NHEADS*4);
    int r = tid - n*(NHEADS*4);
    int h = r >> 2;
    int q = (r >> 1) & 1;        // 3-channel half
    int eh = r & 1;              // edge half (lane parity)
    int k0 = rowptr[n], k1 = rowptr[n+1];
    int mid = k0 + ((k1 - k0 + 1) >> 1);
    int ka = eh ? mid : k0;
    int kb = eh ? k1 : mid;
    const float* lgh = lg1T + (size_t)h*EE;
    float m = -INFINITY, den = 0.f;
    float acc[3] = {0.f, 0.f, 0.f};
    int k = ka;
    for (; k + 4 <= kb; k += 4){
        float l0 = lgh[k+0], l1 = lgh[k+1], l2 = lgh[k+2], l3 = lgh[k+3];
        int s0 = srcs[k+0], s1 = srcs[k+1], s2 = srcs[k+2], s3 = srcs[k+3];
        const float* p0 = h1 + (size_t)s0*HID + h*OUT1 + q*3;
        const float* p1 = h1 + (size_t)s1*HID + h*OUT1 + q*3;
        const float* p2 = h1 + (size_t)s2*HID + h*OUT1 + q*3;
        const float* p3 = h1 + (size_t)s3*HID + h*OUT1 + q*3;
        float mb = fmaxf(fmaxf(l0, l1), fmaxf(l2, l3));
        float mn = fmaxf(m, mb);
        float f  = expf(m - mn);       // first batch: exp(-inf)=0
        float e0 = expf(l0 - mn), e1 = expf(l1 - mn);
        float e2 = expf(l2 - mn), e3 = expf(l3 - mn);
        m = mn;
        den = den*f + e0 + e1 + e2 + e3;
        #pragma unroll
        for (int c = 0; c < 3; c++)
            acc[c] = acc[c]*f + e0*p0[c] + e1*p1[c] + e2*p2[c] + e3*p3[c];
    }
    for (; k < kb; k++){
        float l = lgh[k];
        int s = srcs[k];
        float mn = fmaxf(m, l);
        float f  = expf(m - mn);
        float ex = expf(l - mn);
        m = mn;
        den = den*f + ex;
        const float* hr = h1 + (size_t)s*HID + h*OUT1 + q*3;
        #pragma unroll
        for (int c = 0; c < 3; c++) acc[c] = acc[c]*f + ex*hr[c];
    }
    // combine the two edge-halves (adjacent lanes)
    float mo  = __shfl_xor(m, 1, 64);
    float dno = __shfl_xor(den, 1, 64);
    float ao0 = __shfl_xor(acc[0], 1, 64);
    float ao1 = __shfl_xor(acc[1], 1, 64);
    float ao2 = __shfl_xor(acc[2], 1, 64);
    float M = fmaxf(m, mo);
    float f1 = (m  == -INFINITY) ? 0.f : expf(m  - M);
    float f2 = (mo == -INFINITY) ? 0.f : expf(mo - M);
    float DEN = den*f1 + dno*f2;
    if (eh == 0){
        float inv = 1.f / (DEN + 1e-16f);
        x1[(size_t)n*HID + h*OUT1 + q*3 + 0] = (acc[0]*f1 + ao0*f2)*inv;
        x1[(size_t)n*HID + h*OUT1 + q*3 + 1] = (acc[1]*f1 + ao1*f2)*inv;
        x1[(size_t)n*HID + h*OUT1 + q*3 + 2] = (acc[2]*f1 + ao2*f2)*inv;
    }
}

// ---------- pool-conv1 prep: hp1 = x1@Wp1 (30x32); scalars ----------
__global__ void k_node_proj_p1(const float* __restrict__ x1, const float* __restrict__ Wp1,
                               const float* __restrict__ asp, const float* __restrict__ adp,
                               float* __restrict__ hp1, float* __restrict__ hsp, float* __restrict__ hdp){
    __shared__ float Ws[HID*C1];
    __shared__ float as_s[C1], ad_s[C1];
    for (int i = threadIdx.x; i < HID*C1; i += blockDim.x) Ws[i] = Wp1[i];
    if (threadIdx.x < C1){ as_s[threadIdx.x] = asp[threadIdx.x]; ad_s[threadIdx.x] = adp[threadIdx.x]; }
    __syncthreads();
    int n = blockIdx.x*blockDim.x + threadIdx.x;
    if (n >= NN) return;
    float xv[HID];
    #pragma unroll
    for (int d = 0; d < HID; d++) xv[d] = x1[(size_t)n*HID + d];
    float s = 0.f, dd = 0.f;
    for (int c = 0; c < C1; c++){
        float a = 0.f;
        #pragma unroll
        for (int d = 0; d < HID; d++) a += xv[d]*Ws[d*C1 + c];
        hp1[(size_t)n*C1 + c] = a;
        s += a*as_s[c]; dd += a*ad_s[c];
    }
    hsp[n] = s; hdp[n] = dd;
}

// ---------- pool logits: all-coalesced reads ----------
__global__ void k_plogit(const int* __restrict__ srcs, const int* __restrict__ dsts,
                         const float* __restrict__ hsp, const float* __restrict__ hdp,
                         const float* __restrict__ ewp1s, float* __restrict__ lgp){
    size_t k = xcd_chunk_base() + threadIdx.x;
    lgp[k] = lrelu(hsp[srcs[k]] + hdp[dsts[k]] + ewp1s[k]);
}

// ---------- pool-conv1 aggregation: pair-split + shfl combine + fused cluster softmax ----------
// 16 threads/node: (q-eighth, edge-half).
__global__ void k_pool1_agg(const int* __restrict__ srcs, const int* __restrict__ rowptr,
                            const float* __restrict__ hp1, const float* __restrict__ lgp,
                            float* __restrict__ ssoft){
    __shared__ float sm[16*33];   // 16 nodes/block, padded row 33
    int tid = blockIdx.x*blockDim.x + threadIdx.x;
    int r = tid & 15;
    int q = r >> 1;
    int eh = r & 1;
    int n = tid >> 4;
    int nl = threadIdx.x >> 4;    // node-local 0..15
    int k0 = rowptr[n], k1 = rowptr[n+1];
    int mid = k0 + ((k1 - k0 + 1) >> 1);
    int ka = eh ? mid : k0;
    int kb = eh ? k1 : mid;
    float m = -INFINITY, den = 0.f;
    float acc[4] = {0.f, 0.f, 0.f, 0.f};
    int k = ka;
    for (; k + 4 <= kb; k += 4){
        float l0 = lgp[k+0], l1 = lgp[k+1], l2 = lgp[k+2], l3 = lgp[k+3];
        int s0 = srcs[k+0], s1n = srcs[k+1], s2 = srcs[k+2], s3 = srcs[k+3];
        float4 v0 = *(const float4*)(hp1 + (size_t)s0*C1 + q*4);
        float4 v1 = *(const float4*)(hp1 + (size_t)s1n*C1 + q*4);
        float4 v2 = *(const float4*)(hp1 + (size_t)s2*C1 + q*4);
        float4 v3 = *(const float4*)(hp1 + (size_t)s3*C1 + q*4);
        float mb = fmaxf(fmaxf(l0, l1), fmaxf(l2, l3));
        float mn = fmaxf(m, mb);
        float f  = expf(m - mn);
        float e0 = expf(l0 - mn), e1 = expf(l1 - mn);
        float e2 = expf(l2 - mn), e3 = expf(l3 - mn);
        m = mn;
        den = den*f + e0 + e1 + e2 + e3;
        acc[0] = acc[0]*f + e0*v0.x + e1*v1.x + e2*v2.x + e3*v3.x;
        acc[1] = acc[1]*f + e0*v0.y + e1*v1.y + e2*v2.y + e3*v3.y;
        acc[2] = acc[2]*f + e0*v0.z + e1*v1.z + e2*v2.z + e3*v3.z;
        acc[3] = acc[3]*f + e0*v0.w + e1*v1.w + e2*v2.w + e3*v3.w;
    }
    for (; k < kb; k++){
        float l = lgp[k];
        int s = srcs[k];
        float mn = fmaxf(m, l);
        float f  = expf(m - mn);
        float ex = expf(l - mn);
        m = mn;
        den = den*f + ex;
        const float* hr = hp1 + (size_t)s*C1 + q*4;
        #pragma unroll
        for (int c = 0; c < 4; c++) acc[c] = acc[c]*f + ex*hr[c];
    }
    // combine edge-halves
    float mo  = __shfl_xor(m, 1, 64);
    float dno = __shfl_xor(den, 1, 64);
    float ao[4];
    #pragma unroll
    for (int c = 0; c < 4; c++) ao[c] = __shfl_xor(acc[c], 1, 64);
    float M = fmaxf(m, mo);
    float f1 = (m  == -INFINITY) ? 0.f : expf(m  - M);
    float f2 = (mo == -INFINITY) ? 0.f : expf(mo - M);
    float DEN = den*f1 + dno*f2;
    if (eh == 0){
        float inv = 1.f / (DEN + 1e-16f);
        #pragma unroll
        for (int c = 0; c < 4; c++) sm[nl*33 + q*4 + c] = (acc[c]*f1 + ao[c]*f2)*inv;
    }
    __syncthreads();
    // cluster softmax over the node's 32 channels (redundant per thread)
    float mx = -INFINITY;
    #pragma unroll 8
    for (int i = 0; i < C1; i++) mx = fmaxf(mx, sm[nl*33 + i]);
    float sum = 0.f;
    #pragma unroll 8
    for (int i = 0; i < C1; i++) sum += expf(sm[nl*33 + i] - mx);
    float is = 1.f/sum;
    if (eh == 0){
        #pragma unroll
        for (int c = 0; c < 4; c++)
            ssoft[(size_t)n*C1 + q*4 + c] = expf(sm[nl*33 + q*4 + c] - mx)*is;
    }
}

// ---------- T[n,:] = sum over unique out-neighbors, pair-split + shfl add ----------
__global__ void k_T(const int* __restrict__ rowptrS, const int* __restrict__ unbr,
                    const int* __restrict__ ucnt, const float* __restrict__ ssoft,
                    float* __restrict__ T){
    int tid = blockIdx.x*blockDim.x + threadIdx.x;
    int r = tid & 15;
    int q = r >> 1;
    int eh = r & 1;
    int n = tid >> 4;
    int k0 = rowptrS[n];
    int cnt = ucnt[n];
    int half = (cnt + 1) >> 1;
    int ia = eh ? half : 0;
    int ib = eh ? cnt : half;
    float acc[4] = {0.f, 0.f, 0.f, 0.f};
    int i = ia;
    for (; i + 4 <= ib; i += 4){
        int m0 = unbr[k0+i+0], m1 = unbr[k0+i+1], m2 = unbr[k0+i+2], m3 = unbr[k0+i+3];
        float4 v0 = *(const float4*)(ssoft + (size_t)m0*C1 + q*4);
        float4 v1 = *(const float4*)(ssoft + (size_t)m1*C1 + q*4);
        float4 v2 = *(const float4*)(ssoft + (size_t)m2*C1 + q*4);
        float4 v3 = *(const float4*)(ssoft + (size_t)m3*C1 + q*4);
        acc[0] += v0.x + v1.x + v2.x + v3.x;
        acc[1] += v0.y + v1.y + v2.y + v3.y;
        acc[2] += v0.z + v1.z + v2.z + v3.z;
        acc[3] += v0.w + v1.w + v2.w + v3.w;
    }
    for (; i < ib; i++){
        int m = unbr[k0 + i];
        const float* sr = ssoft + (size_t)m*C1 + q*4;
        #pragma unroll
        for (int c = 0; c < 4; c++) acc[c] += sr[c];
    }
    #pragma unroll
    for (int c = 0; c < 4; c++) acc[c] += __shfl_xor(acc[c], 1, 64);
    if (eh == 0){
        #pragma unroll
        for (int c = 0; c < 4; c++) T[(size_t)n*C1 + q*4 + c] = acc[c];
    }
}

// ---------- fused partials over 64-node chunks ----------
__global__ void k_partials(const float* __restrict__ ssoft, const float* __restrict__ T,
                           const float* __restrict__ x1,
                           float* __restrict__ adj2, float* __restrict__ Gm,
                           float* __restrict__ x2){
    int b  = blockIdx.y;
    int n0 = blockIdx.x * 64;
    int t  = threadIdx.x;   // 256
    __shared__ float ssh[64*C1];
    __shared__ float tsh[64*C1];
    __shared__ float xsh[64*HID];
    {
        size_t sbase = ((size_t)b*NPG + n0)*C1;
        #pragma unroll
        for (int i = 0; i < 8; i++){
            int lin = t + i*256;
            ssh[lin] = ssoft[sbase + lin];
            tsh[lin] = T[sbase + lin];
        }
        size_t xbase = ((size_t)b*NPG + n0)*HID;
        for (int lin = t; lin < 64*HID; lin += 256) xsh[lin] = x1[xbase + lin];
    }
    __syncthreads();
    float accA[4] = {0,0,0,0}, accG[4] = {0,0,0,0}, accX[4] = {0,0,0,0};
    int cA[4], kA[4], cX[4], dX[4];
    #pragma unroll
    for (int q = 0; q < 4; q++){
        int p = t + q*256;
        cA[q] = p >> 5; kA[q] = p & 31;
        cX[q] = p / HID; dX[q] = p - cX[q]*HID;   // valid only when p < 960
    }
    for (int r = 0; r < 64; r++){
        const float* sr = ssh + r*C1;
        const float* tr = tsh + r*C1;
        const float* xr = xsh + r*HID;
        #pragma unroll
        for (int q = 0; q < 4; q++){
            float sc = sr[cA[q]];
            accA[q] += sc*tr[kA[q]];
            accG[q] += sc*sr[kA[q]];
        }
        #pragma unroll
        for (int q = 0; q < 4; q++){
            int p = t + q*256;
            if (p < C1*HID) accX[q] += sr[cX[q]]*xr[dX[q]];
        }
    }
    #pragma unroll
    for (int q = 0; q < 4; q++){
        int p = t + q*256;
        atomicAdd(&adj2[(size_t)b*1024 + p], accA[q]);
        atomicAdd(&Gm[(size_t)b*1024 + p], accG[q]);
        if (p < C1*HID) atomicAdd(&x2[((size_t)b*C1 + cX[q])*HID + dX[q]], accX[q]);
    }
}

// ---------- fused tail: finalize(reg1 parts) + pool-conv2 + diffpool2 + per-graph MLP ----------
__global__ void k_tail(const float* __restrict__ x2, const float* __restrict__ adj2,
                       const float* __restrict__ Gm,
                       const float* __restrict__ Wp2, const float* __restrict__ asp,
                       const float* __restrict__ adp, const float* __restrict__ Wep2,
                       const float* __restrict__ Wf1, const float* __restrict__ bf1,
                       const float* __restrict__ Wf2, const float* __restrict__ bf2,
                       float* __restrict__ out, float* __restrict__ scal){
    int b = blockIdx.x;
    int t = threadIdx.x;  // 256
    __shared__ float x2s[C1*HID];    // 960
    __shared__ float a2s[C1*C1];     // 1024
    __shared__ float Wps[HID*C2];    // 120
    __shared__ float h2s[C1*C2];
    __shared__ float hs2s[C1], hd2s[C1];
    __shared__ float sss[C1*C2];     // softmax(s2)
    __shared__ float x3s[C2*HID];    // 120
    __shared__ float zsh[32];
    __shared__ float red[256];
    for (int i = t; i < C1*HID; i += 256) x2s[i] = x2[(size_t)b*C1*HID + i];
    for (int i = t; i < C1*C1; i += 256) a2s[i] = adj2[(size_t)b*C1*C1 + i];
    if (t < HID*C2) Wps[t] = Wp2[t];
    __syncthreads();
    // finalize reg1 ingredients from this graph: trace(adj2), ||G||_F^2
    {
        float ltr = 0.f, lfr = 0.f;
        for (int p = t; p < 1024; p += 256){
            float g = Gm[(size_t)b*1024 + p];
            lfr += g*g;
            if ((p >> 5) == (p & 31)) ltr += a2s[p];
        }
        red[t] = ltr; __syncthreads();
        for (int s = 128; s > 0; s >>= 1){ if (t < s) red[t] += red[t+s]; __syncthreads(); }
        if (t == 0) atomicAdd(&scal[1], red[0]);
        __syncthreads();
        red[t] = lfr; __syncthreads();
        for (int s = 128; s > 0; s >>= 1){ if (t < s) red[t] += red[t+s]; __syncthreads(); }
        if (t == 0) atomicAdd(&scal[2], red[0]);
        __syncthreads();
    }
    // phase 1: h2 = x2@Wp2 + attention scalars
    if (t < C1){
        float s = 0.f, dd = 0.f;
        #pragma unroll
        for (int c = 0; c < C2; c++){
            float a = 0.f;
            #pragma unroll
            for (int d = 0; d < HID; d++) a += x2s[t*HID + d]*Wps[d*C2 + c];
            h2s[t*C2 + c] = a;
            s += a*asp[c]; dd += a*adp[c];
        }
        hs2s[t] = s; hd2s[t] = dd;
    }
    __syncthreads();
    // phase 2: dense EGAT agg over 32 sources + softmax over C2
    if (t < C1){
        int j = t;
        float hdv = hd2s[j];
        float wep = Wep2[0];
        float m = -INFINITY;
        for (int i = 0; i < C1; i++)
            m = fmaxf(m, lrelu(hs2s[i] + hdv + a2s[i*C1 + j]*wep));
        float den = 0.f;
        float acc[C2] = {0,0,0,0};
        for (int i = 0; i < C1; i++){
            float ex = expf(lrelu(hs2s[i] + hdv + a2s[i*C1 + j]*wep) - m);
            den += ex;
            #pragma unroll
            for (int c = 0; c < C2; c++) acc[c] += ex * h2s[i*C2 + c];
        }
        float inv = 1.f/(den + 1e-16f);
        float v[C2]; float mx = -INFINITY;
        #pragma unroll
        for (int c = 0; c < C2; c++){ v[c] = acc[c]*inv; mx = fmaxf(mx, v[c]); }
        float sum = 0.f;
        #pragma unroll
        for (int c = 0; c < C2; c++){ v[c] = expf(v[c] - mx); sum += v[c]; }
        float i2 = 1.f/sum;
        #pragma unroll
        for (int c = 0; c < C2; c++) sss[j*C2 + c] = v[c]*i2;
    }
    __syncthreads();
    // phase 3: x3 = S^T x2 (LDS only) and reg2
    if (t < C2*HID){
        int c = t / HID, d = t % HID;
        float a = 0.f;
        #pragma unroll
        for (int n = 0; n < C1; n++) a += sss[n*C2 + c]*x2s[n*HID + d];
        x3s[t] = a;
    }
    {
        float loc = 0.f;
        for (int p = t; p < 1024; p += 256){
            int n = p >> 5, mm = p & 31;
            float dot = 0.f;
            #pragma unroll
            for (int c = 0; c < C2; c++) dot += sss[n*C2 + c]*sss[mm*C2 + c];
            float df = a2s[p] - dot;
            loc += df*df;
        }
        red[t] = loc; __syncthreads();
        for (int s = 128; s > 0; s >>= 1){ if (t < s) red[t] += red[t+s]; __syncthreads(); }
        if (t == 0) atomicAdd(&scal[3], red[0]);
        __syncthreads();
    }
    // phase 4: per-graph MLP -> out[2b], out[2b+1]
    if (t < 32){
        float a = bf1[t];
        #pragma unroll 4
        for (int k = 0; k < C2*HID; k++) a += x3s[k]*Wf1[k*32 + t];
        zsh[t] = fmaxf(a, 0.f);
    }
    __syncthreads();
    if (t < 2){
        float a = bf2[t];
        #pragma unroll
        for (int j = 0; j < 32; j++) a += zsh[j]*Wf2[j*2 + t];
        out[b*2 + t] = a;
    }
}

// ---------- reg assembly (after all k_tail atomics) ----------
__global__ void k_reg(const float* __restrict__ scal, float* __restrict__ out){
    if (threadIdx.x == 0){
        float adjsum = scal[0], tr = scal[1], fr = scal[2], r2 = scal[3];
        float reg1 = (adjsum - 2.f*tr + fr) * (1.f/16777216.f);
        float reg2 = r2 * (1.f/16384.f);
        out[32] = 10.f*reg1 + 0.1f*reg2;
    }
}

extern "C" void kernel_launch(void* const* d_in, const int* in_sizes, int n_in,
                              void* d_out, int out_size, void* d_ws, size_t ws_size,
                              hipStream_t stream) {
    const float* x    = (const float*)d_in[0];
    const int*   ei   = (const int*)d_in[1];
    const float* ea   = (const float*)d_in[2];
    // d_in[3] = y (unused); d_in[4] = adj (algebraically eliminated — never read)
    const float* W1   = (const float*)d_in[5];
    const float* as1  = (const float*)d_in[6];
    const float* ad1  = (const float*)d_in[7];
    const float* We1  = (const float*)d_in[8];
    const float* Wp1  = (const float*)d_in[9];
    const float* asp1 = (const float*)d_in[10];
    const float* adp1 = (const float*)d_in[11];
    const float* Wep1 = (const float*)d_in[12];
    const float* Wp2  = (const float*)d_in[13];
    const float* asp2 = (const float*)d_in[14];
    const float* adp2 = (const float*)d_in[15];
    const float* Wep2 = (const float*)d_in[16];
    const float* Wf1  = (const float*)d_in[17];
    const float* bf1  = (const float*)d_in[18];
    const float* Wf2  = (const float*)d_in[19];
    const float* bf2  = (const float*)d_in[20];
    float* out = (float*)d_out;

    const int* srcA = ei;
    const int* dstA = ei + EE;

    char* wp = (char*)d_ws;
    auto carve = [&](size_t bytes)->char*{
        char* p = wp;
        wp += (bytes + 255) & ~(size_t)255;
        return p;
    };
    float* h1    = (float*)carve((size_t)NN*HID*4);
    float* hs1   = (float*)carve((size_t)NN*NHEADS*4);
    float* hd1   = (float*)carve((size_t)NN*NHEADS*4);
    float* lg1T  = (float*)carve((size_t)EE*NHEADS*4);
    float* ewp1s = (float*)carve((size_t)EE*4);
    float* lgp   = (float*)carve((size_t)EE*4);
    float* x1    = (float*)carve((size_t)NN*HID*4);
    float* hp1   = (float*)carve((size_t)NN*C1*4);
    float* hsp   = (float*)carve((size_t)NN*4);
    float* hdp   = (float*)carve((size_t)NN*4);
    float* ssoft = (float*)carve((size_t)NN*C1*4);
    float* T     = (float*)carve((size_t)NN*C1*4);
    // --- zero-init region (contiguous): x2, adj2, Gm ---
    float* x2    = (float*)carve((size_t)NB*C1*HID*4);   // 61440 B (256-aligned)
    float* adj2  = (float*)carve((size_t)NB*C1*C1*4);    // 65536 B
    float* Gm    = (float*)carve((size_t)NB*C1*C1*4);    // 65536 B
    // ---------------------------------------------------
    float* scal  = (float*)carve(16*4);
    int* histD   = (int*)carve((size_t)NB*CH*NPG*4);     // 1 MB
    int* histS   = (int*)carve((size_t)NB*CH*NPG*4);     // 1 MB
    int* rowptr  = (int*)carve((size_t)(NN+1)*4);
    int* rowptrS = (int*)carve((size_t)(NN+1)*4);
    int* srcs    = (int*)carve((size_t)EE*4);
    int* eid     = (int*)carve((size_t)EE*4);
    int* dsts    = (int*)carve((size_t)EE*4);
    int* nbrS    = (int*)carve((size_t)EE*4);
    int* unbr    = (int*)carve((size_t)EE*4);
    int* ucnt    = (int*)carve((size_t)NN*4);

    hipMemsetAsync(scal, 0, 16*4, stream);
    hipMemsetAsync(x2, 0, (size_t)(NB*C1*HID + 2*NB*C1*C1)*4, stream);  // x2+adj2+Gm

    const int TB = 256;
    dim3 gN((NN + TB - 1)/TB);

    // merged: per-chunk dual LDS histograms (256 blocks) + node projection (64 blocks)
    k_hist_chunk<<<dim3(256 + 64), TB, 0, stream>>>(srcA, dstA, histD, histS,
                                                    x, W1, as1, ad1, h1, hs1, hd1);
    // fused chunk-scan + per-graph node scan -> rowptr/rowptrS
    k_cumscan<<<dim3(2*NB), 1024, 0, stream>>>(histD, histS, rowptr, rowptrS);
    // deterministic scatter (LDS atomics only)
    k_scatter_det<<<dim3(256), TB, 0, stream>>>(srcA, dstA, rowptr, rowptrS,
                                                histD, histS, srcs, eid, dsts, nbrS);

    // edge proj + conv1 logit planes, then dedup
    k_elogit<<<dim3(2048), TB, 0, stream>>>(ea, We1, Wep1, srcs, eid, dsts, hs1, hd1, lg1T, ewp1s);
    k_dedup<<<dim3(NN/TB), TB, 0, stream>>>(rowptrS, nbrS, unbr, ucnt, scal);

    // conv1: pair-split edges + shfl combine
    k_conv1_agg<<<dim3(NN*NHEADS*4/TB), TB, 0, stream>>>(srcs, rowptr, h1, lg1T, x1);

    // pool-conv1 (+fused cluster softmax)
    k_node_proj_p1<<<gN, TB, 0, stream>>>(x1, Wp1, asp1, adp1, hp1, hsp, hdp);
    k_plogit<<<dim3(2048), TB, 0, stream>>>(srcs, dsts, hsp, hdp, ewp1s, lgp);
    k_pool1_agg<<<dim3(NN*16/TB), TB, 0, stream>>>(srcs, rowptr, hp1, lgp, ssoft);

    // diffpool1
    k_T<<<dim3(NN*16/TB), TB, 0, stream>>>(rowptrS, unbr, ucnt, ssoft, T);
    k_partials<<<dim3(16, NB), TB, 0, stream>>>(ssoft, T, x1, adj2, Gm, x2);

    // fused tail: finalize + pool-conv2 + diffpool2 + per-graph MLP
    k_tail<<<dim3(NB), TB, 0, stream>>>(x2, adj2, Gm, Wp2, asp2, adp2, Wep2,
                                        Wf1, bf1, Wf2, bf2, out, scal);

    // reg assembly
    k_reg<<<1, 64, 0, stream>>>(scal, out);
}

// Round 16
// 285.820 us; speedup vs baseline: 1.0172x; 1.0077x over previous
//
#include <hip/hip_runtime.h>
#include <math.h>

#define NB 16
#define NPG 1024
#define DIN 16
#define ED 8
#define NHEADS 5
#define OUT1 6
#define HID 30
#define C1 32
#define C2 4
#define NN (NB*NPG)      // 16384 nodes
#define EE (NN*32)       // 524288 edges
#define EPG 32768        // edges per graph (graph-contiguous in edge_index)
#define CH 16            // chunks per graph
#define CE 2048          // edges per chunk

__device__ __forceinline__ float lrelu(float v){ return v >= 0.f ? v : 0.2f*v; }

// chunk mapping for 256-block edge kernels: XCD-affine, block -> (g, c)
__device__ __forceinline__ void chunk_gc(int& g, int& c){
    int x = blockIdx.x & 7;
    int j = blockIdx.x >> 3;     // 0..31
    g = x + 8*(j >> 4);          // 2 graphs per XCD
    c = j & 15;
}

// XCD-affinity mapping for 2048-block edge kernels
__device__ __forceinline__ size_t xcd_chunk_base(){
    int x = blockIdx.x & 7;
    int j = blockIdx.x >> 3;            // 0..255 position within this XCD
    int g = x + 8*(j >> 7);             // 2 graphs per XCD
    int c = j & 127;                    // 128 chunks per graph
    return (size_t)g*EPG + (size_t)c*256;
}

// ---------- merged: per-chunk dual LDS histograms (blocks 0..255) + node projection ----------
__global__ void k_hist_chunk(const int* __restrict__ src, const int* __restrict__ dst,
                             int* __restrict__ histD, int* __restrict__ histS,
                             const float* __restrict__ x, const float* __restrict__ W1,
                             const float* __restrict__ as1, const float* __restrict__ ad1,
                             float* __restrict__ h1, float* __restrict__ hs1, float* __restrict__ hd1){
    int t = threadIdx.x;
    if (blockIdx.x < 256){
        __shared__ int hD[NPG], hS[NPG];
        for (int i = t; i < NPG; i += 256){ hD[i] = 0; hS[i] = 0; }
        __syncthreads();
        int g, c; chunk_gc(g, c);
        size_t e0 = ((size_t)g*CH + c)*CE;
        #pragma unroll
        for (int i = 0; i < 8; i++){
            size_t e = e0 + i*256 + t;
            atomicAdd(&hD[dst[e] & (NPG-1)], 1);
            atomicAdd(&hS[src[e] & (NPG-1)], 1);
        }
        __syncthreads();
        size_t hb = ((size_t)g*CH + c)*NPG;
        for (int i = t; i < NPG; i += 256){
            histD[hb + i] = hD[i];
            histS[hb + i] = hS[i];
        }
        return;
    }
    // node projection part (blocks 256..319)
    __shared__ float Ws[DIN*HID];
    __shared__ float as_s[HID], ad_s[HID];
    for (int i = t; i < DIN*HID; i += blockDim.x) Ws[i] = W1[i];
    if (t < HID){ as_s[t] = as1[t]; ad_s[t] = ad1[t]; }
    __syncthreads();
    int n = (blockIdx.x - 256)*blockDim.x + t;
    if (n >= NN) return;
    float xv[DIN];
    #pragma unroll
    for (int i = 0; i < DIN; i++) xv[i] = x[n*DIN + i];
    float hv[HID];
    #pragma unroll
    for (int j = 0; j < HID; j++){
        float a = 0.f;
        #pragma unroll
        for (int i = 0; i < DIN; i++) a += xv[i]*Ws[i*HID + j];
        hv[j] = a; h1[(size_t)n*HID + j] = a;
    }
    #pragma unroll
    for (int h = 0; h < NHEADS; h++){
        float s = 0.f, d = 0.f;
        #pragma unroll
        for (int c2 = 0; c2 < OUT1; c2++){ s += hv[h*OUT1+c2]*as_s[h*OUT1+c2]; d += hv[h*OUT1+c2]*ad_s[h*OUT1+c2]; }
        hs1[n*NHEADS + h] = s; hd1[n*NHEADS + h] = d;
    }
}

// ---------- fused: per-(g,n) chunk scan (in place) + per-graph node scan -> rowptr ----------
__global__ __launch_bounds__(1024) void k_cumscan(int* __restrict__ histD, int* __restrict__ histS,
                                                  int* __restrict__ rowptr, int* __restrict__ rowptrS){
    __shared__ int wtot[16], wbase[16];
    bool isD = (blockIdx.x < NB);
    int b = isD ? blockIdx.x : (blockIdx.x - NB);
    int* hist = isD ? histD : histS;
    int* rp   = isD ? rowptr : rowptrS;
    int n = threadIdx.x;
    int run = 0;
    #pragma unroll
    for (int c = 0; c < CH; c++){
        size_t idx = ((size_t)b*CH + c)*NPG + n;
        int v = hist[idx];
        hist[idx] = run;
        run += v;
    }
    int lane = n & 63, wv = n >> 6;
    int sincl = run;
    #pragma unroll
    for (int off = 1; off < 64; off <<= 1){
        int v = __shfl_up(sincl, off, 64);
        if (lane >= off) sincl += v;
    }
    if (lane == 63) wtot[wv] = sincl;
    __syncthreads();
    if (n == 0){
        int r = 0;
        #pragma unroll
        for (int w = 0; w < 16; w++){ wbase[w] = r; r += wtot[w]; }
    }
    __syncthreads();
    int excl = wbase[wv] + sincl - run;
    rp[b*NPG + n] = b*EPG + excl;
    if (b == NB-1 && n == NPG-1) rp[NN] = EE;
}

// ---------- deterministic scatter: slot = rowptr + chunk-base + LDS rank (no global atomics) ----------
__global__ void k_scatter_det(const int* __restrict__ src, const int* __restrict__ dst,
                              const int* __restrict__ rowptr, const int* __restrict__ rowptrS,
                              const int* __restrict__ histD, const int* __restrict__ histS,
                              int* __restrict__ srcs, int* __restrict__ eid,
                              int* __restrict__ dsts, int* __restrict__ nbrS){
    __shared__ int baseD[NPG], baseS[NPG];
    int t = threadIdx.x;
    int g, c; chunk_gc(g, c);
    size_t hb = ((size_t)g*CH + c)*NPG;
    for (int i = t; i < NPG; i += 256){
        baseD[i] = rowptr[g*NPG + i] + histD[hb + i];
        baseS[i] = rowptrS[g*NPG + i] + histS[hb + i];
    }
    __syncthreads();
    size_t e0 = ((size_t)g*CH + c)*CE;
    #pragma unroll
    for (int i = 0; i < 8; i++){
        size_t e = e0 + i*256 + t;
        int s = src[e], d = dst[e];
        int p = atomicAdd(&baseD[d & (NPG-1)], 1);
        srcs[p] = s; eid[p] = (int)e; dsts[p] = d;
        int pS = atomicAdd(&baseS[s & (NPG-1)], 1);
        nbrS[pS] = d;
    }
}

// ---------- edge proj + conv1 LOGITS into per-head planes (2048 blocks) ----------
__global__ void k_elogit(const float* __restrict__ ea, const float* __restrict__ We1,
                         const float* __restrict__ Wep1,
                         const int* __restrict__ srcs, const int* __restrict__ eid,
                         const int* __restrict__ dsts,
                         const float* __restrict__ hs1, const float* __restrict__ hd1,
                         float* __restrict__ lg1T, float* __restrict__ ewp1s){
    __shared__ float W[ED*NHEADS];
    __shared__ float Wp[ED];
    int t = threadIdx.x;
    if (t < ED*NHEADS) W[t] = We1[t];
    if (t < ED) Wp[t] = Wep1[t];
    __syncthreads();
    size_t k = xcd_chunk_base() + t;
    int s = srcs[k], e = eid[k], d = dsts[k];
    float a[ED];
    #pragma unroll
    for (int i = 0; i < ED; i++) a[i] = ea[(size_t)e*ED + i];
    const float* hsr = hs1 + (size_t)s*NHEADS;
    const float* hdr = hd1 + (size_t)d*NHEADS;
    #pragma unroll
    for (int h = 0; h < NHEADS; h++){
        float sv = 0.f;
        #pragma unroll
        for (int i = 0; i < ED; i++) sv += a[i]*W[i*NHEADS + h];
        lg1T[(size_t)h*EE + k] = lrelu(hsr[h] + hdr[h] + sv);
    }
    float sv = 0.f;
    #pragma unroll
    for (int i = 0; i < ED; i++) sv += a[i]*Wp[i];
    ewp1s[k] = sv;
}

// ---------- conv1 aggregation: pair-split edges + shfl combine ----------
__global__ void k_conv1_agg(const int* __restrict__ srcs, const int* __restrict__ rowptr,
                            const float* __restrict__ h1, const float* __restrict__ lg1T,
                            float* __restrict__ x1){
    int tid = blockIdx.x*blockDim.x + threadIdx.x;
    if (tid >= NN*NHEADS*4) return;
    int n = tid / (NHEADS*4);
    int r = tid - n*(NHEADS*4);
    int h = r >> 2;
    int q = (r >> 1) & 1;        // 3-channel half
    int eh = r & 1;              // edge half (lane parity)
    int k0 = rowptr[n], k1 = rowptr[n+1];
    int mid = k0 + ((k1 - k0 + 1) >> 1);
    int ka = eh ? mid : k0;
    int kb = eh ? k1 : mid;
    const float* lgh = lg1T + (size_t)h*EE;
    float m = -INFINITY, den = 0.f;
    float acc[3] = {0.f, 0.f, 0.f};
    int k = ka;
    for (; k + 4 <= kb; k += 4){
        float l0 = lgh[k+0], l1 = lgh[k+1], l2 = lgh[k+2], l3 = lgh[k+3];
        int s0 = srcs[k+0], s1 = srcs[k+1], s2 = srcs[k+2], s3 = srcs[k+3];
        const float* p0 = h1 + (size_t)s0*HID + h*OUT1 + q*3;
        const float* p1 = h1 + (size_t)s1*HID + h*OUT1 + q*3;
        const float* p2 = h1 + (size_t)s2*HID + h*OUT1 + q*3;
        const float* p3 = h1 + (size_t)s3*HID + h*OUT1 + q*3;
        float mb = fmaxf(fmaxf(l0, l1), fmaxf(l2, l3));
        float mn = fmaxf(m, mb);
        float f  = expf(m - mn);       // first batch: exp(-inf)=0
        float e0 = expf(l0 - mn), e1 = expf(l1 - mn);
        float e2 = expf(l2 - mn), e3 = expf(l3 - mn);
        m = mn;
        den = den*f + e0 + e1 + e2 + e3;
        #pragma unroll
        for (int c = 0; c < 3; c++)
            acc[c] = acc[c]*f + e0*p0[c] + e1*p1[c] + e2*p2[c] + e3*p3[c];
    }
    for (; k < kb; k++){
        float l = lgh[k];
        int s = srcs[k];
        float mn = fmaxf(m, l);
        float f  = expf(m - mn);
        float ex = expf(l - mn);
        m = mn;
        den = den*f + ex;
        const float* hr = h1 + (size_t)s*HID + h*OUT1 + q*3;
        #pragma unroll
        for (int c = 0; c < 3; c++) acc[c] = acc[c]*f + ex*hr[c];
    }
    // combine the two edge-halves (adjacent lanes)
    float mo  = __shfl_xor(m, 1, 64);
    float dno = __shfl_xor(den, 1, 64);
    float ao0 = __shfl_xor(acc[0], 1, 64);
    float ao1 = __shfl_xor(acc[1], 1, 64);
    float ao2 = __shfl_xor(acc[2], 1, 64);
    float M = fmaxf(m, mo);
    float f1 = (m  == -INFINITY) ? 0.f : expf(m  - M);
    float f2 = (mo == -INFINITY) ? 0.f : expf(mo - M);
    float DEN = den*f1 + dno*f2;
    if (eh == 0){
        float inv = 1.f / (DEN + 1e-16f);
        x1[(size_t)n*HID + h*OUT1 + q*3 + 0] = (acc[0]*f1 + ao0*f2)*inv;
        x1[(size_t)n*HID + h*OUT1 + q*3 + 1] = (acc[1]*f1 + ao1*f2)*inv;
        x1[(size_t)n*HID + h*OUT1 + q*3 + 2] = (acc[2]*f1 + ao2*f2)*inv;
    }
}

// ---------- merged: pool-conv1 prep (blocks 0..63) + dedup (blocks 64..127) ----------
// Independent stages on disjoint CU sets; 128 blocks << 256 CUs so the 39 KB
// combined static LDS never caps effective occupancy.
__global__ void k_pd(const float* __restrict__ x1, const float* __restrict__ Wp1,
                     const float* __restrict__ asp, const float* __restrict__ adp,
                     float* __restrict__ hp1, float* __restrict__ hsp, float* __restrict__ hdp,
                     const int* __restrict__ rowptrS, const int* __restrict__ nbrS,
                     int* __restrict__ unbr, int* __restrict__ ucnt,
                     float* __restrict__ scal){
    __shared__ float Ws[HID*C1];
    __shared__ float as_s[C1], ad_s[C1];
    __shared__ unsigned int bm[256*33];
    __shared__ int red[256];
    int t = threadIdx.x;
    if (blockIdx.x < 64){
        // pool-conv1 prep: hp1 = x1@Wp1 (30x32); scalars
        for (int i = t; i < HID*C1; i += blockDim.x) Ws[i] = Wp1[i];
        if (t < C1){ as_s[t] = asp[t]; ad_s[t] = adp[t]; }
        __syncthreads();
        int n = blockIdx.x*blockDim.x + t;
        float xv[HID];
        #pragma unroll
        for (int d = 0; d < HID; d++) xv[d] = x1[(size_t)n*HID + d];
        float s = 0.f, dd = 0.f;
        for (int c = 0; c < C1; c++){
            float a = 0.f;
            #pragma unroll
            for (int d = 0; d < HID; d++) a += xv[d]*Ws[d*C1 + c];
            hp1[(size_t)n*C1 + c] = a;
            s += a*as_s[c]; dd += a*ad_s[c];
        }
        hsp[n] = s; hdp[n] = dd;
        return;
    }
    // dedup via per-thread LDS bitmap
    unsigned int* mybm = &bm[t*33];
    #pragma unroll
    for (int i = 0; i < 32; i++) mybm[i] = 0u;
    int n = (blockIdx.x - 64)*blockDim.x + t;
    int cnt = 0;
    {
        int k0 = rowptrS[n], k1 = rowptrS[n+1];
        for (int k = k0; k < k1; k++){
            int m = nbrS[k];
            int loc = m & (NPG-1);
            unsigned int w = (unsigned int)(loc >> 5);
            unsigned int bit = 1u << (loc & 31);
            unsigned int old = mybm[w];
            if (!(old & bit)){
                mybm[w] = old | bit;
                unbr[k0 + cnt] = m;
                cnt++;
            }
        }
        ucnt[n] = cnt;
    }
    red[t] = cnt; __syncthreads();
    for (int s = 128; s > 0; s >>= 1){ if (t < s) red[t] += red[t+s]; __syncthreads(); }
    if (t == 0) atomicAdd(&scal[0], (float)red[0]);
}

// ---------- pool logits: all-coalesced reads ----------
__global__ void k_plogit(const int* __restrict__ srcs, const int* __restrict__ dsts,
                         const float* __restrict__ hsp, const float* __restrict__ hdp,
                         const float* __restrict__ ewp1s, float* __restrict__ lgp){
    size_t k = xcd_chunk_base() + threadIdx.x;
    lgp[k] = lrelu(hsp[srcs[k]] + hdp[dsts[k]] + ewp1s[k]);
}

// ---------- pool-conv1 aggregation: pair-split + shfl combine + fused cluster softmax ----------
__global__ void k_pool1_agg(const int* __restrict__ srcs, const int* __restrict__ rowptr,
                            const float* __restrict__ hp1, const float* __restrict__ lgp,
                            float* __restrict__ ssoft){
    __shared__ float sm[16*33];   // 16 nodes/block, padded row 33
    int tid = blockIdx.x*blockDim.x + threadIdx.x;
    int r = tid & 15;
    int q = r >> 1;
    int eh = r & 1;
    int n = tid >> 4;
    int nl = threadIdx.x >> 4;    // node-local 0..15
    int k0 = rowptr[n], k1 = rowptr[n+1];
    int mid = k0 + ((k1 - k0 + 1) >> 1);
    int ka = eh ? mid : k0;
    int kb = eh ? k1 : mid;
    float m = -INFINITY, den = 0.f;
    float acc[4] = {0.f, 0.f, 0.f, 0.f};
    int k = ka;
    for (; k + 4 <= kb; k += 4){
        float l0 = lgp[k+0], l1 = lgp[k+1], l2 = lgp[k+2], l3 = lgp[k+3];
        int s0 = srcs[k+0], s1n = srcs[k+1], s2 = srcs[k+2], s3 = srcs[k+3];
        float4 v0 = *(const float4*)(hp1 + (size_t)s0*C1 + q*4);
        float4 v1 = *(const float4*)(hp1 + (size_t)s1n*C1 + q*4);
        float4 v2 = *(const float4*)(hp1 + (size_t)s2*C1 + q*4);
        float4 v3 = *(const float4*)(hp1 + (size_t)s3*C1 + q*4);
        float mb = fmaxf(fmaxf(l0, l1), fmaxf(l2, l3));
        float mn = fmaxf(m, mb);
        float f  = expf(m - mn);
        float e0 = expf(l0 - mn), e1 = expf(l1 - mn);
        float e2 = expf(l2 - mn), e3 = expf(l3 - mn);
        m = mn;
        den = den*f + e0 + e1 + e2 + e3;
        acc[0] = acc[0]*f + e0*v0.x + e1*v1.x + e2*v2.x + e3*v3.x;
        acc[1] = acc[1]*f + e0*v0.y + e1*v1.y + e2*v2.y + e3*v3.y;
        acc[2] = acc[2]*f + e0*v0.z + e1*v1.z + e2*v2.z + e3*v3.z;
        acc[3] = acc[3]*f + e0*v0.w + e1*v1.w + e2*v2.w + e3*v3.w;
    }
    for (; k < kb; k++){
        float l = lgp[k];
        int s = srcs[k];
        float mn = fmaxf(m, l);
        float f  = expf(m - mn);
        float ex = expf(l - mn);
        m = mn;
        den = den*f + ex;
        const float* hr = hp1 + (size_t)s*C1 + q*4;
        #pragma unroll
        for (int c = 0; c < 4; c++) acc[c] = acc[c]*f + ex*hr[c];
    }
    // combine edge-halves
    float mo  = __shfl_xor(m, 1, 64);
    float dno = __shfl_xor(den, 1, 64);
    float ao[4];
    #pragma unroll
    for (int c = 0; c < 4; c++) ao[c] = __shfl_xor(acc[c], 1, 64);
    float M = fmaxf(m, mo);
    float f1 = (m  == -INFINITY) ? 0.f : expf(m  - M);
    float f2 = (mo == -INFINITY) ? 0.f : expf(mo - M);
    float DEN = den*f1 + dno*f2;
    if (eh == 0){
        float inv = 1.f / (DEN + 1e-16f);
        #pragma unroll
        for (int c = 0; c < 4; c++) sm[nl*33 + q*4 + c] = (acc[c]*f1 + ao[c]*f2)*inv;
    }
    __syncthreads();
    // cluster softmax over the node's 32 channels (redundant per thread)
    float mx = -INFINITY;
    #pragma unroll 8
    for (int i = 0; i < C1; i++) mx = fmaxf(mx, sm[nl*33 + i]);
    float sum = 0.f;
    #pragma unroll 8
    for (int i = 0; i < C1; i++) sum += expf(sm[nl*33 + i] - mx);
    float is = 1.f/sum;
    if (eh == 0){
        #pragma unroll
        for (int c = 0; c < 4; c++)
            ssoft[(size_t)n*C1 + q*4 + c] = expf(sm[nl*33 + q*4 + c] - mx)*is;
    }
}

// ---------- T[n,:] = sum over unique out-neighbors, pair-split + shfl add ----------
__global__ void k_T(const int* __restrict__ rowptrS, const int* __restrict__ unbr,
                    const int* __restrict__ ucnt, const float* __restrict__ ssoft,
                    float* __restrict__ T){
    int tid = blockIdx.x*blockDim.x + threadIdx.x;
    int r = tid & 15;
    int q = r >> 1;
    int eh = r & 1;
    int n = tid >> 4;
    int k0 = rowptrS[n];
    int cnt = ucnt[n];
    int half = (cnt + 1) >> 1;
    int ia = eh ? half : 0;
    int ib = eh ? cnt : half;
    float acc[4] = {0.f, 0.f, 0.f, 0.f};
    int i = ia;
    for (; i + 4 <= ib; i += 4){
        int m0 = unbr[k0+i+0], m1 = unbr[k0+i+1], m2 = unbr[k0+i+2], m3 = unbr[k0+i+3];
        float4 v0 = *(const float4*)(ssoft + (size_t)m0*C1 + q*4);
        float4 v1 = *(const float4*)(ssoft + (size_t)m1*C1 + q*4);
        float4 v2 = *(const float4*)(ssoft + (size_t)m2*C1 + q*4);
        float4 v3 = *(const float4*)(ssoft + (size_t)m3*C1 + q*4);
        acc[0] += v0.x + v1.x + v2.x + v3.x;
        acc[1] += v0.y + v1.y + v2.y + v3.y;
        acc[2] += v0.z + v1.z + v2.z + v3.z;
        acc[3] += v0.w + v1.w + v2.w + v3.w;
    }
    for (; i < ib; i++){
        int m = unbr[k0 + i];
        const float* sr = ssoft + (size_t)m*C1 + q*4;
        #pragma unroll
        for (int c = 0; c < 4; c++) acc[c] += sr[c];
    }
    #pragma unroll
    for (int c = 0; c < 4; c++) acc[c] += __shfl_xor(acc[c], 1, 64);
    if (eh == 0){
        #pragma unroll
        for (int c = 0; c < 4; c++) T[(size_t)n*C1 + q*4 + c] = acc[c];
    }
}

// ---------- fused partials over 64-node chunks ----------
__global__ void k_partials(const float* __restrict__ ssoft, const float* __restrict__ T,
                           const float* __restrict__ x1,
                           float* __restrict__ adj2, float* __restrict__ Gm,
                           float* __restrict__ x2){
    int b  = blockIdx.y;
    int n0 = blockIdx.x * 64;
    int t  = threadIdx.x;   // 256
    __shared__ float ssh[64*C1];
    __shared__ float tsh[64*C1];
    __shared__ float xsh[64*HID];
    {
        size_t sbase = ((size_t)b*NPG + n0)*C1;
        #pragma unroll
        for (int i = 0; i < 8; i++){
            int lin = t + i*256;
            ssh[lin] = ssoft[sbase + lin];
            tsh[lin] = T[sbase + lin];
        }
        size_t xbase = ((size_t)b*NPG + n0)*HID;
        for (int lin = t; lin < 64*HID; lin += 256) xsh[lin] = x1[xbase + lin];
    }
    __syncthreads();
    float accA[4] = {0,0,0,0}, accG[4] = {0,0,0,0}, accX[4] = {0,0,0,0};
    int cA[4], kA[4], cX[4], dX[4];
    #pragma unroll
    for (int q = 0; q < 4; q++){
        int p = t + q*256;
        cA[q] = p >> 5; kA[q] = p & 31;
        cX[q] = p / HID; dX[q] = p - cX[q]*HID;   // valid only when p < 960
    }
    for (int r = 0; r < 64; r++){
        const float* sr = ssh + r*C1;
        const float* tr = tsh + r*C1;
        const float* xr = xsh + r*HID;
        #pragma unroll
        for (int q = 0; q < 4; q++){
            float sc = sr[cA[q]];
            accA[q] += sc*tr[kA[q]];
            accG[q] += sc*sr[kA[q]];
        }
        #pragma unroll
        for (int q = 0; q < 4; q++){
            int p = t + q*256;
            if (p < C1*HID) accX[q] += sr[cX[q]]*xr[dX[q]];
        }
    }
    #pragma unroll
    for (int q = 0; q < 4; q++){
        int p = t + q*256;
        atomicAdd(&adj2[(size_t)b*1024 + p], accA[q]);
        atomicAdd(&Gm[(size_t)b*1024 + p], accG[q]);
        if (p < C1*HID) atomicAdd(&x2[((size_t)b*C1 + cX[q])*HID + dX[q]], accX[q]);
    }
}

// ---------- fused tail: finalize + pool-conv2 + diffpool2 + per-graph MLP + reg (last block) ----------
__global__ void k_tail(const float* __restrict__ x2, const float* __restrict__ adj2,
                       const float* __restrict__ Gm,
                       const float* __restrict__ Wp2, const float* __restrict__ asp,
                       const float* __restrict__ adp, const float* __restrict__ Wep2,
                       const float* __restrict__ Wf1, const float* __restrict__ bf1,
                       const float* __restrict__ Wf2, const float* __restrict__ bf2,
                       float* __restrict__ out, float* __restrict__ scal,
                       unsigned int* __restrict__ ctr){
    int b = blockIdx.x;
    int t = threadIdx.x;  // 256
    __shared__ float x2s[C1*HID];    // 960
    __shared__ float a2s[C1*C1];     // 1024
    __shared__ float Wps[HID*C2];    // 120
    __shared__ float h2s[C1*C2];
    __shared__ float hs2s[C1], hd2s[C1];
    __shared__ float sss[C1*C2];     // softmax(s2)
    __shared__ float x3s[C2*HID];    // 120
    __shared__ float zsh[32];
    __shared__ float red[256];
    for (int i = t; i < C1*HID; i += 256) x2s[i] = x2[(size_t)b*C1*HID + i];
    for (int i = t; i < C1*C1; i += 256) a2s[i] = adj2[(size_t)b*C1*C1 + i];
    if (t < HID*C2) Wps[t] = Wp2[t];
    __syncthreads();
    // finalize reg1 ingredients from this graph: trace(adj2), ||G||_F^2
    {
        float ltr = 0.f, lfr = 0.f;
        for (int p = t; p < 1024; p += 256){
            float g = Gm[(size_t)b*1024 + p];
            lfr += g*g;
            if ((p >> 5) == (p & 31)) ltr += a2s[p];
        }
        red[t] = ltr; __syncthreads();
        for (int s = 128; s > 0; s >>= 1){ if (t < s) red[t] += red[t+s]; __syncthreads(); }
        if (t == 0) atomicAdd(&scal[1], red[0]);
        __syncthreads();
        red[t] = lfr; __syncthreads();
        for (int s = 128; s > 0; s >>= 1){ if (t < s) red[t] += red[t+s]; __syncthreads(); }
        if (t == 0) atomicAdd(&scal[2], red[0]);
        __syncthreads();
    }
    // phase 1: h2 = x2@Wp2 + attention scalars
    if (t < C1){
        float s = 0.f, dd = 0.f;
        #pragma unroll
        for (int c = 0; c < C2; c++){
            float a = 0.f;
            #pragma unroll
            for (int d = 0; d < HID; d++) a += x2s[t*HID + d]*Wps[d*C2 + c];
            h2s[t*C2 + c] = a;
            s += a*asp[c]; dd += a*adp[c];
        }
        hs2s[t] = s; hd2s[t] = dd;
    }
    __syncthreads();
    // phase 2: dense EGAT agg over 32 sources + softmax over C2
    if (t < C1){
        int j = t;
        float hdv = hd2s[j];
        float wep = Wep2[0];
        float m = -INFINITY;
        for (int i = 0; i < C1; i++)
            m = fmaxf(m, lrelu(hs2s[i] + hdv + a2s[i*C1 + j]*wep));
        float den = 0.f;
        float acc[C2] = {0,0,0,0};
        for (int i = 0; i < C1; i++){
            float ex = expf(lrelu(hs2s[i] + hdv + a2s[i*C1 + j]*wep) - m);
            den += ex;
            #pragma unroll
            for (int c = 0; c < C2; c++) acc[c] += ex * h2s[i*C2 + c];
        }
        float inv = 1.f/(den + 1e-16f);
        float v[C2]; float mx = -INFINITY;
        #pragma unroll
        for (int c = 0; c < C2; c++){ v[c] = acc[c]*inv; mx = fmaxf(mx, v[c]); }
        float sum = 0.f;
        #pragma unroll
        for (int c = 0; c < C2; c++){ v[c] = expf(v[c] - mx); sum += v[c]; }
        float i2 = 1.f/sum;
        #pragma unroll
        for (int c = 0; c < C2; c++) sss[j*C2 + c] = v[c]*i2;
    }
    __syncthreads();
    // phase 3: x3 = S^T x2 (LDS only) and reg2
    if (t < C2*HID){
        int c = t / HID, d = t % HID;
        float a = 0.f;
        #pragma unroll
        for (int n = 0; n < C1; n++) a += sss[n*C2 + c]*x2s[n*HID + d];
        x3s[t] = a;
    }
    {
        float loc = 0.f;
        for (int p = t; p < 1024; p += 256){
            int n = p >> 5, mm = p & 31;
            float dot = 0.f;
            #pragma unroll
            for (int c = 0; c < C2; c++) dot += sss[n*C2 + c]*sss[mm*C2 + c];
            float df = a2s[p] - dot;
            loc += df*df;
        }
        red[t] = loc; __syncthreads();
        for (int s = 128; s > 0; s >>= 1){ if (t < s) red[t] += red[t+s]; __syncthreads(); }
        if (t == 0) atomicAdd(&scal[3], red[0]);
        __syncthreads();
    }
    // phase 4: per-graph MLP -> out[2b], out[2b+1]
    if (t < 32){
        float a = bf1[t];
        #pragma unroll 4
        for (int k = 0; k < C2*HID; k++) a += x3s[k]*Wf1[k*32 + t];
        zsh[t] = fmaxf(a, 0.f);
    }
    __syncthreads();
    if (t < 2){
        float a = bf2[t];
        #pragma unroll
        for (int j = 0; j < 32; j++) a += zsh[j]*Wf2[j*2 + t];
        out[b*2 + t] = a;
    }
    // phase 5: last finished block assembles the reg scalar
    if (t == 0){
        __threadfence();
        unsigned int old = atomicAdd(ctr, 1u);
        if (old == NB - 1){
            float adjsum = atomicAdd(&scal[0], 0.f);
            float tr     = atomicAdd(&scal[1], 0.f);
            float fr     = atomicAdd(&scal[2], 0.f);
            float r2     = atomicAdd(&scal[3], 0.f);
            float reg1 = (adjsum - 2.f*tr + fr) * (1.f/16777216.f);
            float reg2 = r2 * (1.f/16384.f);
            out[32] = 10.f*reg1 + 0.1f*reg2;
        }
    }
}

extern "C" void kernel_launch(void* const* d_in, const int* in_sizes, int n_in,
                              void* d_out, int out_size, void* d_ws, size_t ws_size,
                              hipStream_t stream) {
    const float* x    = (const float*)d_in[0];
    const int*   ei   = (const int*)d_in[1];
    const float* ea   = (const float*)d_in[2];
    // d_in[3] = y (unused); d_in[4] = adj (algebraically eliminated — never read)
    const float* W1   = (const float*)d_in[5];
    const float* as1  = (const float*)d_in[6];
    const float* ad1  = (const float*)d_in[7];
    const float* We1  = (const float*)d_in[8];
    const float* Wp1  = (const float*)d_in[9];
    const float* asp1 = (const float*)d_in[10];
    const float* adp1 = (const float*)d_in[11];
    const float* Wep1 = (const float*)d_in[12];
    const float* Wp2  = (const float*)d_in[13];
    const float* asp2 = (const float*)d_in[14];
    const float* adp2 = (const float*)d_in[15];
    const float* Wep2 = (const float*)d_in[16];
    const float* Wf1  = (const float*)d_in[17];
    const float* bf1  = (const float*)d_in[18];
    const float* Wf2  = (const float*)d_in[19];
    const float* bf2  = (const float*)d_in[20];
    float* out = (float*)d_out;

    const int* srcA = ei;
    const int* dstA = ei + EE;

    char* wp = (char*)d_ws;
    auto carve = [&](size_t bytes)->char*{
        char* p = wp;
        wp += (bytes + 255) & ~(size_t)255;
        return p;
    };
    float* h1    = (float*)carve((size_t)NN*HID*4);
    float* hs1   = (float*)carve((size_t)NN*NHEADS*4);
    float* hd1   = (float*)carve((size_t)NN*NHEADS*4);
    float* lg1T  = (float*)carve((size_t)EE*NHEADS*4);
    float* ewp1s = (float*)carve((size_t)EE*4);
    float* lgp   = (float*)carve((size_t)EE*4);
    float* x1    = (float*)carve((size_t)NN*HID*4);
    float* hp1   = (float*)carve((size_t)NN*C1*4);
    float* hsp   = (float*)carve((size_t)NN*4);
    float* hdp   = (float*)carve((size_t)NN*4);
    float* ssoft = (float*)carve((size_t)NN*C1*4);
    float* T     = (float*)carve((size_t)NN*C1*4);
    // --- zero-init region (contiguous): x2, adj2, Gm ---
    float* x2    = (float*)carve((size_t)NB*C1*HID*4);   // 61440 B (256-aligned)
    float* adj2  = (float*)carve((size_t)NB*C1*C1*4);    // 65536 B
    float* Gm    = (float*)carve((size_t)NB*C1*C1*4);    // 65536 B
    // ---------------------------------------------------
    float* scal  = (float*)carve(16*4);                  // [0..3] sums, [8] ctr
    unsigned int* ctr = (unsigned int*)(scal + 8);
    int* histD   = (int*)carve((size_t)NB*CH*NPG*4);     // 1 MB
    int* histS   = (int*)carve((size_t)NB*CH*NPG*4);     // 1 MB
    int* rowptr  = (int*)carve((size_t)(NN+1)*4);
    int* rowptrS = (int*)carve((size_t)(NN+1)*4);
    int* srcs    = (int*)carve((size_t)EE*4);
    int* eid     = (int*)carve((size_t)EE*4);
    int* dsts    = (int*)carve((size_t)EE*4);
    int* nbrS    = (int*)carve((size_t)EE*4);
    int* unbr    = (int*)carve((size_t)EE*4);
    int* ucnt    = (int*)carve((size_t)NN*4);

    hipMemsetAsync(scal, 0, 16*4, stream);
    hipMemsetAsync(x2, 0, (size_t)(NB*C1*HID + 2*NB*C1*C1)*4, stream);  // x2+adj2+Gm

    const int TB = 256;

    // merged: per-chunk dual LDS histograms (256 blocks) + node projection (64 blocks)
    k_hist_chunk<<<dim3(256 + 64), TB, 0, stream>>>(srcA, dstA, histD, histS,
                                                    x, W1, as1, ad1, h1, hs1, hd1);
    // fused chunk-scan + per-graph node scan -> rowptr/rowptrS
    k_cumscan<<<dim3(2*NB), 1024, 0, stream>>>(histD, histS, rowptr, rowptrS);
    // deterministic scatter (LDS atomics only)
    k_scatter_det<<<dim3(256), TB, 0, stream>>>(srcA, dstA, rowptr, rowptrS,
                                                histD, histS, srcs, eid, dsts, nbrS);

    // edge proj + conv1 logit planes
    k_elogit<<<dim3(2048), TB, 0, stream>>>(ea, We1, Wep1, srcs, eid, dsts, hs1, hd1, lg1T, ewp1s);

    // conv1: pair-split edges + shfl combine
    k_conv1_agg<<<dim3(NN*NHEADS*4/TB), TB, 0, stream>>>(srcs, rowptr, h1, lg1T, x1);

    // merged: pool-conv1 prep (64 blocks) + dedup (64 blocks, concurrent)
    k_pd<<<dim3(128), TB, 0, stream>>>(x1, Wp1, asp1, adp1, hp1, hsp, hdp,
                                       rowptrS, nbrS, unbr, ucnt, scal);

    // pool-conv1 (+fused cluster softmax)
    k_plogit<<<dim3(2048), TB, 0, stream>>>(srcs, dsts, hsp, hdp, ewp1s, lgp);
    k_pool1_agg<<<dim3(NN*16/TB), TB, 0, stream>>>(srcs, rowptr, hp1, lgp, ssoft);

    // diffpool1
    k_T<<<dim3(NN*16/TB), TB, 0, stream>>>(rowptrS, unbr, ucnt, ssoft, T);
    k_partials<<<dim3(16, NB), TB, 0, stream>>>(ssoft, T, x1, adj2, Gm, x2);

    // fused tail: finalize + pool-conv2 + diffpool2 + per-graph MLP + reg assembly
    k_tail<<<dim3(NB), TB, 0, stream>>>(x2, adj2, Gm, Wp2, asp2, adp2, Wep2,
                                        Wf1, bf1, Wf2, bf2, out, scal, ctr);
}

// Round 17
// 280.189 us; speedup vs baseline: 1.0377x; 1.0201x over previous
//
#include <hip/hip_runtime.h>
#include <math.h>

#define NB 16
#define NPG 1024
#define DIN 16
#define ED 8
#define NHEADS 5
#define OUT1 6
#define HID 30
#define C1 32
#define C2 4
#define NN (NB*NPG)      // 16384 nodes
#define EE (NN*32)       // 524288 edges
#define EPG 32768        // edges per graph (graph-contiguous in edge_index)
#define CH 16            // chunks per graph
#define CE 2048          // edges per chunk

__device__ __forceinline__ float lrelu(float v){ return v >= 0.f ? v : 0.2f*v; }

// chunk mapping for 256-block edge kernels: XCD-affine, block -> (g, c)
__device__ __forceinline__ void chunk_gc(int& g, int& c){
    int x = blockIdx.x & 7;
    int j = blockIdx.x >> 3;     // 0..31
    g = x + 8*(j >> 4);          // 2 graphs per XCD
    c = j & 15;
}

// XCD-affinity mapping for 2048-block edge kernels
__device__ __forceinline__ size_t xcd_chunk_base(){
    int x = blockIdx.x & 7;
    int j = blockIdx.x >> 3;            // 0..255 position within this XCD
    int g = x + 8*(j >> 7);             // 2 graphs per XCD
    int c = j & 127;                    // 128 chunks per graph
    return (size_t)g*EPG + (size_t)c*256;
}

// ---------- merged: per-chunk dual LDS histograms (blocks 0..255) + node projection ----------
__global__ void k_hist_chunk(const int* __restrict__ src, const int* __restrict__ dst,
                             int* __restrict__ histD, int* __restrict__ histS,
                             const float* __restrict__ x, const float* __restrict__ W1,
                             const float* __restrict__ as1, const float* __restrict__ ad1,
                             float* __restrict__ h1, float* __restrict__ hs1, float* __restrict__ hd1){
    int t = threadIdx.x;
    if (blockIdx.x < 256){
        __shared__ int hD[NPG], hS[NPG];
        for (int i = t; i < NPG; i += 256){ hD[i] = 0; hS[i] = 0; }
        __syncthreads();
        int g, c; chunk_gc(g, c);
        size_t e0 = ((size_t)g*CH + c)*CE;
        #pragma unroll
        for (int i = 0; i < 8; i++){
            size_t e = e0 + i*256 + t;
            atomicAdd(&hD[dst[e] & (NPG-1)], 1);
            atomicAdd(&hS[src[e] & (NPG-1)], 1);
        }
        __syncthreads();
        size_t hb = ((size_t)g*CH + c)*NPG;
        for (int i = t; i < NPG; i += 256){
            histD[hb + i] = hD[i];
            histS[hb + i] = hS[i];
        }
        return;
    }
    // node projection part (blocks 256..319)
    __shared__ float Ws[DIN*HID];
    __shared__ float as_s[HID], ad_s[HID];
    for (int i = t; i < DIN*HID; i += blockDim.x) Ws[i] = W1[i];
    if (t < HID){ as_s[t] = as1[t]; ad_s[t] = ad1[t]; }
    __syncthreads();
    int n = (blockIdx.x - 256)*blockDim.x + t;
    if (n >= NN) return;
    float xv[DIN];
    #pragma unroll
    for (int i = 0; i < DIN; i++) xv[i] = x[n*DIN + i];
    float hv[HID];
    #pragma unroll
    for (int j = 0; j < HID; j++){
        float a = 0.f;
        #pragma unroll
        for (int i = 0; i < DIN; i++) a += xv[i]*Ws[i*HID + j];
        hv[j] = a; h1[(size_t)n*HID + j] = a;
    }
    #pragma unroll
    for (int h = 0; h < NHEADS; h++){
        float s = 0.f, d = 0.f;
        #pragma unroll
        for (int c2 = 0; c2 < OUT1; c2++){ s += hv[h*OUT1+c2]*as_s[h*OUT1+c2]; d += hv[h*OUT1+c2]*ad_s[h*OUT1+c2]; }
        hs1[n*NHEADS + h] = s; hd1[n*NHEADS + h] = d;
    }
}

// ---------- fused: per-(g,n) chunk scan (in place) + per-graph node scan -> rowptr ----------
__global__ __launch_bounds__(1024) void k_cumscan(int* __restrict__ histD, int* __restrict__ histS,
                                                  int* __restrict__ rowptr, int* __restrict__ rowptrS){
    __shared__ int wtot[16], wbase[16];
    bool isD = (blockIdx.x < NB);
    int b = isD ? blockIdx.x : (blockIdx.x - NB);
    int* hist = isD ? histD : histS;
    int* rp   = isD ? rowptr : rowptrS;
    int n = threadIdx.x;
    int run = 0;
    #pragma unroll
    for (int c = 0; c < CH; c++){
        size_t idx = ((size_t)b*CH + c)*NPG + n;
        int v = hist[idx];
        hist[idx] = run;
        run += v;
    }
    int lane = n & 63, wv = n >> 6;
    int sincl = run;
    #pragma unroll
    for (int off = 1; off < 64; off <<= 1){
        int v = __shfl_up(sincl, off, 64);
        if (lane >= off) sincl += v;
    }
    if (lane == 63) wtot[wv] = sincl;
    __syncthreads();
    if (n == 0){
        int r = 0;
        #pragma unroll
        for (int w = 0; w < 16; w++){ wbase[w] = r; r += wtot[w]; }
    }
    __syncthreads();
    int excl = wbase[wv] + sincl - run;
    rp[b*NPG + n] = b*EPG + excl;
    if (b == NB-1 && n == NPG-1) rp[NN] = EE;
}

// ---------- deterministic scatter: slot = rowptr + chunk-base + LDS rank (no global atomics) ----------
__global__ void k_scatter_det(const int* __restrict__ src, const int* __restrict__ dst,
                              const int* __restrict__ rowptr, const int* __restrict__ rowptrS,
                              const int* __restrict__ histD, const int* __restrict__ histS,
                              int* __restrict__ srcs, int* __restrict__ eid,
                              int* __restrict__ dsts, int* __restrict__ nbrS){
    __shared__ int baseD[NPG], baseS[NPG];
    int t = threadIdx.x;
    int g, c; chunk_gc(g, c);
    size_t hb = ((size_t)g*CH + c)*NPG;
    for (int i = t; i < NPG; i += 256){
        baseD[i] = rowptr[g*NPG + i] + histD[hb + i];
        baseS[i] = rowptrS[g*NPG + i] + histS[hb + i];
    }
    __syncthreads();
    size_t e0 = ((size_t)g*CH + c)*CE;
    #pragma unroll
    for (int i = 0; i < 8; i++){
        size_t e = e0 + i*256 + t;
        int s = src[e], d = dst[e];
        int p = atomicAdd(&baseD[d & (NPG-1)], 1);
        srcs[p] = s; eid[p] = (int)e; dsts[p] = d;
        int pS = atomicAdd(&baseS[s & (NPG-1)], 1);
        nbrS[pS] = d;
    }
}

// ---------- edge proj + conv1 LOGITS into per-head planes (2048 blocks) ----------
__global__ void k_elogit(const float* __restrict__ ea, const float* __restrict__ We1,
                         const float* __restrict__ Wep1,
                         const int* __restrict__ srcs, const int* __restrict__ eid,
                         const int* __restrict__ dsts,
                         const float* __restrict__ hs1, const float* __restrict__ hd1,
                         float* __restrict__ lg1T, float* __restrict__ ewp1s){
    __shared__ float W[ED*NHEADS];
    __shared__ float Wp[ED];
    int t = threadIdx.x;
    if (t < ED*NHEADS) W[t] = We1[t];
    if (t < ED) Wp[t] = Wep1[t];
    __syncthreads();
    size_t k = xcd_chunk_base() + t;
    int s = srcs[k], e = eid[k], d = dsts[k];
    float a[ED];
    #pragma unroll
    for (int i = 0; i < ED; i++) a[i] = ea[(size_t)e*ED + i];
    const float* hsr = hs1 + (size_t)s*NHEADS;
    const float* hdr = hd1 + (size_t)d*NHEADS;
    #pragma unroll
    for (int h = 0; h < NHEADS; h++){
        float sv = 0.f;
        #pragma unroll
        for (int i = 0; i < ED; i++) sv += a[i]*W[i*NHEADS + h];
        lg1T[(size_t)h*EE + k] = lrelu(hsr[h] + hdr[h] + sv);
    }
    float sv = 0.f;
    #pragma unroll
    for (int i = 0; i < ED; i++) sv += a[i]*Wp[i];
    ewp1s[k] = sv;
}

// ---------- conv1 aggregation: graph-local h1 staged in LDS ----------
// 256 blocks (16 per graph, XCD-affine) x 640 threads.
// Each block stages the whole graph's h1 (1024x30 = 120 KB) coalesced, then
// serves all feature gathers from LDS (no L2 line over-fetch).
// Thread -> (node-of-64-segment, head, q-half): t/10 = local node, t%10 = h*2+q.
__global__ __launch_bounds__(640) void k_conv1_agg(const int* __restrict__ srcs,
                            const int* __restrict__ rowptr,
                            const float* __restrict__ h1, const float* __restrict__ lg1T,
                            float* __restrict__ x1){
    __shared__ float hls[NPG*HID];   // 122880 B
    int t = threadIdx.x;
    int xx = blockIdx.x & 7;
    int j = blockIdx.x >> 3;         // 0..31
    int g = xx + 8*(j >> 4);         // 2 graphs per XCD
    int seg = j & 15;                // 64-node segment
    const float* hg = h1 + (size_t)g*NPG*HID;
    for (int i = t; i < NPG*HID; i += 640) hls[i] = hg[i];
    __syncthreads();
    int nl = seg*64 + t/10;
    int r = t - (t/10)*10;
    int h = r >> 1;
    int q = r & 1;
    int n = g*NPG + nl;
    int k0 = rowptr[n], k1 = rowptr[n+1];
    const float* lgh = lg1T + (size_t)h*EE;
    int off = h*OUT1 + q*3;
    float m = -INFINITY, den = 0.f;
    float acc[3] = {0.f, 0.f, 0.f};
    int k = k0;
    for (; k + 4 <= k1; k += 4){
        float l0 = lgh[k+0], l1 = lgh[k+1], l2 = lgh[k+2], l3 = lgh[k+3];
        int s0 = srcs[k+0] & (NPG-1), s1 = srcs[k+1] & (NPG-1);
        int s2 = srcs[k+2] & (NPG-1), s3 = srcs[k+3] & (NPG-1);
        const float* p0 = hls + s0*HID + off;
        const float* p1 = hls + s1*HID + off;
        const float* p2 = hls + s2*HID + off;
        const float* p3 = hls + s3*HID + off;
        float mb = fmaxf(fmaxf(l0, l1), fmaxf(l2, l3));
        float mn = fmaxf(m, mb);
        float f  = expf(m - mn);       // first batch: exp(-inf)=0
        float e0 = expf(l0 - mn), e1 = expf(l1 - mn);
        float e2 = expf(l2 - mn), e3 = expf(l3 - mn);
        m = mn;
        den = den*f + e0 + e1 + e2 + e3;
        #pragma unroll
        for (int c = 0; c < 3; c++)
            acc[c] = acc[c]*f + e0*p0[c] + e1*p1[c] + e2*p2[c] + e3*p3[c];
    }
    for (; k < k1; k++){
        float l = lgh[k];
        int s = srcs[k] & (NPG-1);
        float mn = fmaxf(m, l);
        float f  = expf(m - mn);
        float ex = expf(l - mn);
        m = mn;
        den = den*f + ex;
        const float* hr = hls + s*HID + off;
        #pragma unroll
        for (int c = 0; c < 3; c++) acc[c] = acc[c]*f + ex*hr[c];
    }
    float inv = 1.f / (den + 1e-16f);
    #pragma unroll
    for (int c = 0; c < 3; c++) x1[(size_t)n*HID + off + c] = acc[c]*inv;
}

// ---------- merged: pool-conv1 prep (blocks 0..63) + dedup (blocks 64..127) ----------
__global__ void k_pd(const float* __restrict__ x1, const float* __restrict__ Wp1,
                     const float* __restrict__ asp, const float* __restrict__ adp,
                     float* __restrict__ hp1, float* __restrict__ hsp, float* __restrict__ hdp,
                     const int* __restrict__ rowptrS, const int* __restrict__ nbrS,
                     int* __restrict__ unbr, int* __restrict__ ucnt,
                     float* __restrict__ scal){
    __shared__ float Ws[HID*C1];
    __shared__ float as_s[C1], ad_s[C1];
    __shared__ unsigned int bm[256*33];
    __shared__ int red[256];
    int t = threadIdx.x;
    if (blockIdx.x < 64){
        for (int i = t; i < HID*C1; i += blockDim.x) Ws[i] = Wp1[i];
        if (t < C1){ as_s[t] = asp[t]; ad_s[t] = adp[t]; }
        __syncthreads();
        int n = blockIdx.x*blockDim.x + t;
        float xv[HID];
        #pragma unroll
        for (int d = 0; d < HID; d++) xv[d] = x1[(size_t)n*HID + d];
        float s = 0.f, dd = 0.f;
        for (int c = 0; c < C1; c++){
            float a = 0.f;
            #pragma unroll
            for (int d = 0; d < HID; d++) a += xv[d]*Ws[d*C1 + c];
            hp1[(size_t)n*C1 + c] = a;
            s += a*as_s[c]; dd += a*ad_s[c];
        }
        hsp[n] = s; hdp[n] = dd;
        return;
    }
    // dedup via per-thread LDS bitmap
    unsigned int* mybm = &bm[t*33];
    #pragma unroll
    for (int i = 0; i < 32; i++) mybm[i] = 0u;
    int n = (blockIdx.x - 64)*blockDim.x + t;
    int cnt = 0;
    {
        int k0 = rowptrS[n], k1 = rowptrS[n+1];
        for (int k = k0; k < k1; k++){
            int m = nbrS[k];
            int loc = m & (NPG-1);
            unsigned int w = (unsigned int)(loc >> 5);
            unsigned int bit = 1u << (loc & 31);
            unsigned int old = mybm[w];
            if (!(old & bit)){
                mybm[w] = old | bit;
                unbr[k0 + cnt] = m;
                cnt++;
            }
        }
        ucnt[n] = cnt;
    }
    red[t] = cnt; __syncthreads();
    for (int s = 128; s > 0; s >>= 1){ if (t < s) red[t] += red[t+s]; __syncthreads(); }
    if (t == 0) atomicAdd(&scal[0], (float)red[0]);
}

// ---------- pool logits: all-coalesced reads ----------
__global__ void k_plogit(const int* __restrict__ srcs, const int* __restrict__ dsts,
                         const float* __restrict__ hsp, const float* __restrict__ hdp,
                         const float* __restrict__ ewp1s, float* __restrict__ lgp){
    size_t k = xcd_chunk_base() + threadIdx.x;
    lgp[k] = lrelu(hsp[srcs[k]] + hdp[dsts[k]] + ewp1s[k]);
}

// ---------- pool-conv1 aggregation: pair-split + shfl combine + fused cluster softmax ----------
__global__ void k_pool1_agg(const int* __restrict__ srcs, const int* __restrict__ rowptr,
                            const float* __restrict__ hp1, const float* __restrict__ lgp,
                            float* __restrict__ ssoft){
    __shared__ float sm[16*33];   // 16 nodes/block, padded row 33
    int tid = blockIdx.x*blockDim.x + threadIdx.x;
    int r = tid & 15;
    int q = r >> 1;
    int eh = r & 1;
    int n = tid >> 4;
    int nl = threadIdx.x >> 4;    // node-local 0..15
    int k0 = rowptr[n], k1 = rowptr[n+1];
    int mid = k0 + ((k1 - k0 + 1) >> 1);
    int ka = eh ? mid : k0;
    int kb = eh ? k1 : mid;
    float m = -INFINITY, den = 0.f;
    float acc[4] = {0.f, 0.f, 0.f, 0.f};
    int k = ka;
    for (; k + 4 <= kb; k += 4){
        float l0 = lgp[k+0], l1 = lgp[k+1], l2 = lgp[k+2], l3 = lgp[k+3];
        int s0 = srcs[k+0], s1n = srcs[k+1], s2 = srcs[k+2], s3 = srcs[k+3];
        float4 v0 = *(const float4*)(hp1 + (size_t)s0*C1 + q*4);
        float4 v1 = *(const float4*)(hp1 + (size_t)s1n*C1 + q*4);
        float4 v2 = *(const float4*)(hp1 + (size_t)s2*C1 + q*4);
        float4 v3 = *(const float4*)(hp1 + (size_t)s3*C1 + q*4);
        float mb = fmaxf(fmaxf(l0, l1), fmaxf(l2, l3));
        float mn = fmaxf(m, mb);
        float f  = expf(m - mn);
        float e0 = expf(l0 - mn), e1 = expf(l1 - mn);
        float e2 = expf(l2 - mn), e3 = expf(l3 - mn);
        m = mn;
        den = den*f + e0 + e1 + e2 + e3;
        acc[0] = acc[0]*f + e0*v0.x + e1*v1.x + e2*v2.x + e3*v3.x;
        acc[1] = acc[1]*f + e0*v0.y + e1*v1.y + e2*v2.y + e3*v3.y;
        acc[2] = acc[2]*f + e0*v0.z + e1*v1.z + e2*v2.z + e3*v3.z;
        acc[3] = acc[3]*f + e0*v0.w + e1*v1.w + e2*v2.w + e3*v3.w;
    }
    for (; k < kb; k++){
        float l = lgp[k];
        int s = srcs[k];
        float mn = fmaxf(m, l);
        float f  = expf(m - mn);
        float ex = expf(l - mn);
        m = mn;
        den = den*f + ex;
        const float* hr = hp1 + (size_t)s*C1 + q*4;
        #pragma unroll
        for (int c = 0; c < 4; c++) acc[c] = acc[c]*f + ex*hr[c];
    }
    // combine edge-halves
    float mo  = __shfl_xor(m, 1, 64);
    float dno = __shfl_xor(den, 1, 64);
    float ao[4];
    #pragma unroll
    for (int c = 0; c < 4; c++) ao[c] = __shfl_xor(acc[c], 1, 64);
    float M = fmaxf(m, mo);
    float f1 = (m  == -INFINITY) ? 0.f : expf(m  - M);
    float f2 = (mo == -INFINITY) ? 0.f : expf(mo - M);
    float DEN = den*f1 + dno*f2;
    if (eh == 0){
        float inv = 1.f / (DEN + 1e-16f);
        #pragma unroll
        for (int c = 0; c < 4; c++) sm[nl*33 + q*4 + c] = (acc[c]*f1 + ao[c]*f2)*inv;
    }
    __syncthreads();
    // cluster softmax over the node's 32 channels (redundant per thread)
    float mx = -INFINITY;
    #pragma unroll 8
    for (int i = 0; i < C1; i++) mx = fmaxf(mx, sm[nl*33 + i]);
    float sum = 0.f;
    #pragma unroll 8
    for (int i = 0; i < C1; i++) sum += expf(sm[nl*33 + i] - mx);
    float is = 1.f/sum;
    if (eh == 0){
        #pragma unroll
        for (int c = 0; c < 4; c++)
            ssoft[(size_t)n*C1 + q*4 + c] = expf(sm[nl*33 + q*4 + c] - mx)*is;
    }
}

// ---------- T[n,:] = sum over unique out-neighbors, pair-split + shfl add ----------
__global__ void k_T(const int* __restrict__ rowptrS, const int* __restrict__ unbr,
                    const int* __restrict__ ucnt, const float* __restrict__ ssoft,
                    float* __restrict__ T){
    int tid = blockIdx.x*blockDim.x + threadIdx.x;
    int r = tid & 15;
    int q = r >> 1;
    int eh = r & 1;
    int n = tid >> 4;
    int k0 = rowptrS[n];
    int cnt = ucnt[n];
    int half = (cnt + 1) >> 1;
    int ia = eh ? half : 0;
    int ib = eh ? cnt : half;
    float acc[4] = {0.f, 0.f, 0.f, 0.f};
    int i = ia;
    for (; i + 4 <= ib; i += 4){
        int m0 = unbr[k0+i+0], m1 = unbr[k0+i+1], m2 = unbr[k0+i+2], m3 = unbr[k0+i+3];
        float4 v0 = *(const float4*)(ssoft + (size_t)m0*C1 + q*4);
        float4 v1 = *(const float4*)(ssoft + (size_t)m1*C1 + q*4);
        float4 v2 = *(const float4*)(ssoft + (size_t)m2*C1 + q*4);
        float4 v3 = *(const float4*)(ssoft + (size_t)m3*C1 + q*4);
        acc[0] += v0.x + v1.x + v2.x + v3.x;
        acc[1] += v0.y + v1.y + v2.y + v3.y;
        acc[2] += v0.z + v1.z + v2.z + v3.z;
        acc[3] += v0.w + v1.w + v2.w + v3.w;
    }
    for (; i < ib; i++){
        int m = unbr[k0 + i];
        const float* sr = ssoft + (size_t)m*C1 + q*4;
        #pragma unroll
        for (int c = 0; c < 4; c++) acc[c] += sr[c];
    }
    #pragma unroll
    for (int c = 0; c < 4; c++) acc[c] += __shfl_xor(acc[c], 1, 64);
    if (eh == 0){
        #pragma unroll
        for (int c = 0; c < 4; c++) T[(size_t)n*C1 + q*4 + c] = acc[c];
    }
}

// ---------- fused partials over 64-node chunks ----------
__global__ void k_partials(const float* __restrict__ ssoft, const float* __restrict__ T,
                           const float* __restrict__ x1,
                           float* __restrict__ adj2, float* __restrict__ Gm,
                           float* __restrict__ x2){
    int b  = blockIdx.y;
    int n0 = blockIdx.x * 64;
    int t  = threadIdx.x;   // 256
    __shared__ float ssh[64*C1];
    __shared__ float tsh[64*C1];
    __shared__ float xsh[64*HID];
    {
        size_t sbase = ((size_t)b*NPG + n0)*C1;
        #pragma unroll
        for (int i = 0; i < 8; i++){
            int lin = t + i*256;
            ssh[lin] = ssoft[sbase + lin];
            tsh[lin] = T[sbase + lin];
        }
        size_t xbase = ((size_t)b*NPG + n0)*HID;
        for (int lin = t; lin < 64*HID; lin += 256) xsh[lin] = x1[xbase + lin];
    }
    __syncthreads();
    float accA[4] = {0,0,0,0}, accG[4] = {0,0,0,0}, accX[4] = {0,0,0,0};
    int cA[4], kA[4], cX[4], dX[4];
    #pragma unroll
    for (int q = 0; q < 4; q++){
        int p = t + q*256;
        cA[q] = p >> 5; kA[q] = p & 31;
        cX[q] = p / HID; dX[q] = p - cX[q]*HID;   // valid only when p < 960
    }
    for (int r = 0; r < 64; r++){
        const float* sr = ssh + r*C1;
        const float* tr = tsh + r*C1;
        const float* xr = xsh + r*HID;
        #pragma unroll
        for (int q = 0; q < 4; q++){
            float sc = sr[cA[q]];
            accA[q] += sc*tr[kA[q]];
            accG[q] += sc*sr[kA[q]];
        }
        #pragma unroll
        for (int q = 0; q < 4; q++){
            int p = t + q*256;
            if (p < C1*HID) accX[q] += sr[cX[q]]*xr[dX[q]];
        }
    }
    #pragma unroll
    for (int q = 0; q < 4; q++){
        int p = t + q*256;
        atomicAdd(&adj2[(size_t)b*1024 + p], accA[q]);
        atomicAdd(&Gm[(size_t)b*1024 + p], accG[q]);
        if (p < C1*HID) atomicAdd(&x2[((size_t)b*C1 + cX[q])*HID + dX[q]], accX[q]);
    }
}

// ---------- fused tail: finalize + pool-conv2 + diffpool2 + per-graph MLP + reg (last block) ----------
__global__ void k_tail(const float* __restrict__ x2, const float* __restrict__ adj2,
                       const float* __restrict__ Gm,
                       const float* __restrict__ Wp2, const float* __restrict__ asp,
                       const float* __restrict__ adp, const float* __restrict__ Wep2,
                       const float* __restrict__ Wf1, const float* __restrict__ bf1,
                       const float* __restrict__ Wf2, const float* __restrict__ bf2,
                       float* __restrict__ out, float* __restrict__ scal,
                       unsigned int* __restrict__ ctr){
    int b = blockIdx.x;
    int t = threadIdx.x;  // 256
    __shared__ float x2s[C1*HID];    // 960
    __shared__ float a2s[C1*C1];     // 1024
    __shared__ float Wps[HID*C2];    // 120
    __shared__ float h2s[C1*C2];
    __shared__ float hs2s[C1], hd2s[C1];
    __shared__ float sss[C1*C2];     // softmax(s2)
    __shared__ float x3s[C2*HID];    // 120
    __shared__ float zsh[32];
    __shared__ float red[256];
    for (int i = t; i < C1*HID; i += 256) x2s[i] = x2[(size_t)b*C1*HID + i];
    for (int i = t; i < C1*C1; i += 256) a2s[i] = adj2[(size_t)b*C1*C1 + i];
    if (t < HID*C2) Wps[t] = Wp2[t];
    __syncthreads();
    // finalize reg1 ingredients from this graph: trace(adj2), ||G||_F^2
    {
        float ltr = 0.f, lfr = 0.f;
        for (int p = t; p < 1024; p += 256){
            float g = Gm[(size_t)b*1024 + p];
            lfr += g*g;
            if ((p >> 5) == (p & 31)) ltr += a2s[p];
        }
        red[t] = ltr; __syncthreads();
        for (int s = 128; s > 0; s >>= 1){ if (t < s) red[t] += red[t+s]; __syncthreads(); }
        if (t == 0) atomicAdd(&scal[1], red[0]);
        __syncthreads();
        red[t] = lfr; __syncthreads();
        for (int s = 128; s > 0; s >>= 1){ if (t < s) red[t] += red[t+s]; __syncthreads(); }
        if (t == 0) atomicAdd(&scal[2], red[0]);
        __syncthreads();
    }
    // phase 1: h2 = x2@Wp2 + attention scalars
    if (t < C1){
        float s = 0.f, dd = 0.f;
        #pragma unroll
        for (int c = 0; c < C2; c++){
            float a = 0.f;
            #pragma unroll
            for (int d = 0; d < HID; d++) a += x2s[t*HID + d]*Wps[d*C2 + c];
            h2s[t*C2 + c] = a;
            s += a*asp[c]; dd += a*adp[c];
        }
        hs2s[t] = s; hd2s[t] = dd;
    }
    __syncthreads();
    // phase 2: dense EGAT agg over 32 sources + softmax over C2
    if (t < C1){
        int j = t;
        float hdv = hd2s[j];
        float wep = Wep2[0];
        float m = -INFINITY;
        for (int i = 0; i < C1; i++)
            m = fmaxf(m, lrelu(hs2s[i] + hdv + a2s[i*C1 + j]*wep));
        float den = 0.f;
        float acc[C2] = {0,0,0,0};
        for (int i = 0; i < C1; i++){
            float ex = expf(lrelu(hs2s[i] + hdv + a2s[i*C1 + j]*wep) - m);
            den += ex;
            #pragma unroll
            for (int c = 0; c < C2; c++) acc[c] += ex * h2s[i*C2 + c];
        }
        float inv = 1.f/(den + 1e-16f);
        float v[C2]; float mx = -INFINITY;
        #pragma unroll
        for (int c = 0; c < C2; c++){ v[c] = acc[c]*inv; mx = fmaxf(mx, v[c]); }
        float sum = 0.f;
        #pragma unroll
        for (int c = 0; c < C2; c++){ v[c] = expf(v[c] - mx); sum += v[c]; }
        float i2 = 1.f/sum;
        #pragma unroll
        for (int c = 0; c < C2; c++) sss[j*C2 + c] = v[c]*i2;
    }
    __syncthreads();
    // phase 3: x3 = S^T x2 (LDS only) and reg2
    if (t < C2*HID){
        int c = t / HID, d = t % HID;
        float a = 0.f;
        #pragma unroll
        for (int n = 0; n < C1; n++) a += sss[n*C2 + c]*x2s[n*HID + d];
        x3s[t] = a;
    }
    {
        float loc = 0.f;
        for (int p = t; p < 1024; p += 256){
            int n = p >> 5, mm = p & 31;
            float dot = 0.f;
            #pragma unroll
            for (int c = 0; c < C2; c++) dot += sss[n*C2 + c]*sss[mm*C2 + c];
            float df = a2s[p] - dot;
            loc += df*df;
        }
        red[t] = loc; __syncthreads();
        for (int s = 128; s > 0; s >>= 1){ if (t < s) red[t] += red[t+s]; __syncthreads(); }
        if (t == 0) atomicAdd(&scal[3], red[0]);
        __syncthreads();
    }
    // phase 4: per-graph MLP -> out[2b], out[2b+1]
    if (t < 32){
        float a = bf1[t];
        #pragma unroll 4
        for (int k = 0; k < C2*HID; k++) a += x3s[k]*Wf1[k*32 + t];
        zsh[t] = fmaxf(a, 0.f);
    }
    __syncthreads();
    if (t < 2){
        float a = bf2[t];
        #pragma unroll
        for (int j = 0; j < 32; j++) a += zsh[j]*Wf2[j*2 + t];
        out[b*2 + t] = a;
    }
    // phase 5: last finished block assembles the reg scalar
    if (t == 0){
        __threadfence();
        unsigned int old = atomicAdd(ctr, 1u);
        if (old == NB - 1){
            float adjsum = atomicAdd(&scal[0], 0.f);
            float tr     = atomicAdd(&scal[1], 0.f);
            float fr     = atomicAdd(&scal[2], 0.f);
            float r2     = atomicAdd(&scal[3], 0.f);
            float reg1 = (adjsum - 2.f*tr + fr) * (1.f/16777216.f);
            float reg2 = r2 * (1.f/16384.f);
            out[32] = 10.f*reg1 + 0.1f*reg2;
        }
    }
}

extern "C" void kernel_launch(void* const* d_in, const int* in_sizes, int n_in,
                              void* d_out, int out_size, void* d_ws, size_t ws_size,
                              hipStream_t stream) {
    const float* x    = (const float*)d_in[0];
    const int*   ei   = (const int*)d_in[1];
    const float* ea   = (const float*)d_in[2];
    // d_in[3] = y (unused); d_in[4] = adj (algebraically eliminated — never read)
    const float* W1   = (const float*)d_in[5];
    const float* as1  = (const float*)d_in[6];
    const float* ad1  = (const float*)d_in[7];
    const float* We1  = (const float*)d_in[8];
    const float* Wp1  = (const float*)d_in[9];
    const float* asp1 = (const float*)d_in[10];
    const float* adp1 = (const float*)d_in[11];
    const float* Wep1 = (const float*)d_in[12];
    const float* Wp2  = (const float*)d_in[13];
    const float* asp2 = (const float*)d_in[14];
    const float* adp2 = (const float*)d_in[15];
    const float* Wep2 = (const float*)d_in[16];
    const float* Wf1  = (const float*)d_in[17];
    const float* bf1  = (const float*)d_in[18];
    const float* Wf2  = (const float*)d_in[19];
    const float* bf2  = (const float*)d_in[20];
    float* out = (float*)d_out;

    const int* srcA = ei;
    const int* dstA = ei + EE;

    char* wp = (char*)d_ws;
    auto carve = [&](size_t bytes)->char*{
        char* p = wp;
        wp += (bytes + 255) & ~(size_t)255;
        return p;
    };
    float* h1    = (float*)carve((size_t)NN*HID*4);
    float* hs1   = (float*)carve((size_t)NN*NHEADS*4);
    float* hd1   = (float*)carve((size_t)NN*NHEADS*4);
    float* lg1T  = (float*)carve((size_t)EE*NHEADS*4);
    float* ewp1s = (float*)carve((size_t)EE*4);
    float* lgp   = (float*)carve((size_t)EE*4);
    float* x1    = (float*)carve((size_t)NN*HID*4);
    float* hp1   = (float*)carve((size_t)NN*C1*4);
    float* hsp   = (float*)carve((size_t)NN*4);
    float* hdp   = (float*)carve((size_t)NN*4);
    float* ssoft = (float*)carve((size_t)NN*C1*4);
    float* T     = (float*)carve((size_t)NN*C1*4);
    // --- zero-init region (contiguous): x2, adj2, Gm ---
    float* x2    = (float*)carve((size_t)NB*C1*HID*4);   // 61440 B (256-aligned)
    float* adj2  = (float*)carve((size_t)NB*C1*C1*4);    // 65536 B
    float* Gm    = (float*)carve((size_t)NB*C1*C1*4);    // 65536 B
    // ---------------------------------------------------
    float* scal  = (float*)carve(16*4);                  // [0..3] sums, [8] ctr
    unsigned int* ctr = (unsigned int*)(scal + 8);
    int* histD   = (int*)carve((size_t)NB*CH*NPG*4);     // 1 MB
    int* histS   = (int*)carve((size_t)NB*CH*NPG*4);     // 1 MB
    int* rowptr  = (int*)carve((size_t)(NN+1)*4);
    int* rowptrS = (int*)carve((size_t)(NN+1)*4);
    int* srcs    = (int*)carve((size_t)EE*4);
    int* eid     = (int*)carve((size_t)EE*4);
    int* dsts    = (int*)carve((size_t)EE*4);
    int* nbrS    = (int*)carve((size_t)EE*4);
    int* unbr    = (int*)carve((size_t)EE*4);
    int* ucnt    = (int*)carve((size_t)NN*4);

    hipMemsetAsync(scal, 0, 16*4, stream);
    hipMemsetAsync(x2, 0, (size_t)(NB*C1*HID + 2*NB*C1*C1)*4, stream);  // x2+adj2+Gm

    const int TB = 256;

    // merged: per-chunk dual LDS histograms (256 blocks) + node projection (64 blocks)
    k_hist_chunk<<<dim3(256 + 64), TB, 0, stream>>>(srcA, dstA, histD, histS,
                                                    x, W1, as1, ad1, h1, hs1, hd1);
    // fused chunk-scan + per-graph node scan -> rowptr/rowptrS
    k_cumscan<<<dim3(2*NB), 1024, 0, stream>>>(histD, histS, rowptr, rowptrS);
    // deterministic scatter (LDS atomics only)
    k_scatter_det<<<dim3(256), TB, 0, stream>>>(srcA, dstA, rowptr, rowptrS,
                                                histD, histS, srcs, eid, dsts, nbrS);

    // edge proj + conv1 logit planes
    k_elogit<<<dim3(2048), TB, 0, stream>>>(ea, We1, Wep1, srcs, eid, dsts, hs1, hd1, lg1T, ewp1s);

    // conv1: graph-local h1 staged in LDS (256 blocks x 640 threads)
    k_conv1_agg<<<dim3(256), 640, 0, stream>>>(srcs, rowptr, h1, lg1T, x1);

    // merged: pool-conv1 prep (64 blocks) + dedup (64 blocks, concurrent)
    k_pd<<<dim3(128), TB, 0, stream>>>(x1, Wp1, asp1, adp1, hp1, hsp, hdp,
                                       rowptrS, nbrS, unbr, ucnt, scal);

    // pool-conv1 (+fused cluster softmax)
    k_plogit<<<dim3(2048), TB, 0, stream>>>(srcs, dsts, hsp, hdp, ewp1s, lgp);
    k_pool1_agg<<<dim3(NN*16/TB), TB, 0, stream>>>(srcs, rowptr, hp1, lgp, ssoft);

    // diffpool1
    k_T<<<dim3(NN*16/TB), TB, 0, stream>>>(rowptrS, unbr, ucnt, ssoft, T);
    k_partials<<<dim3(16, NB), TB, 0, stream>>>(ssoft, T, x1, adj2, Gm, x2);

    // fused tail: finalize + pool-conv2 + diffpool2 + per-graph MLP + reg assembly
    k_tail<<<dim3(NB), TB, 0, stream>>>(x2, adj2, Gm, Wp2, asp2, adp2, Wep2,
                                        Wf1, bf1, Wf2, bf2, out, scal, ctr);
}

// Round 18
// 277.769 us; speedup vs baseline: 1.0467x; 1.0087x over previous
//
#include <hip/hip_runtime.h>
#include <math.h>

#define NB 16
#define NPG 1024
#define DIN 16
#define ED 8
#define NHEADS 5
#define OUT1 6
#define HID 30
#define C1 32
#define C2 4
#define NN (NB*NPG)      // 16384 nodes
#define EE (NN*32)       // 524288 edges
#define EPG 32768        // edges per graph (graph-contiguous in edge_index)
#define CH 16            // chunks per graph
#define CE 2048          // edges per chunk

__device__ __forceinline__ float lrelu(float v){ return v >= 0.f ? v : 0.2f*v; }

// chunk mapping for 256-block edge kernels: XCD-affine, block -> (g, c)
__device__ __forceinline__ void chunk_gc(int& g, int& c){
    int x = blockIdx.x & 7;
    int j = blockIdx.x >> 3;     // 0..31
    g = x + 8*(j >> 4);          // 2 graphs per XCD
    c = j & 15;
}

// XCD-affinity mapping for 2048-block edge kernels
__device__ __forceinline__ size_t xcd_chunk_base(){
    int x = blockIdx.x & 7;
    int j = blockIdx.x >> 3;            // 0..255 position within this XCD
    int g = x + 8*(j >> 7);             // 2 graphs per XCD
    int c = j & 127;                    // 128 chunks per graph
    return (size_t)g*EPG + (size_t)c*256;
}

// ---------- merged: per-chunk dual LDS histograms (blocks 0..255) + node projection ----------
__global__ void k_hist_chunk(const int* __restrict__ src, const int* __restrict__ dst,
                             int* __restrict__ histD, int* __restrict__ histS,
                             const float* __restrict__ x, const float* __restrict__ W1,
                             const float* __restrict__ as1, const float* __restrict__ ad1,
                             float* __restrict__ h1, float* __restrict__ hs1, float* __restrict__ hd1){
    int t = threadIdx.x;
    if (blockIdx.x < 256){
        __shared__ int hD[NPG], hS[NPG];
        for (int i = t; i < NPG; i += 256){ hD[i] = 0; hS[i] = 0; }
        __syncthreads();
        int g, c; chunk_gc(g, c);
        size_t e0 = ((size_t)g*CH + c)*CE;
        #pragma unroll
        for (int i = 0; i < 8; i++){
            size_t e = e0 + i*256 + t;
            atomicAdd(&hD[dst[e] & (NPG-1)], 1);
            atomicAdd(&hS[src[e] & (NPG-1)], 1);
        }
        __syncthreads();
        size_t hb = ((size_t)g*CH + c)*NPG;
        for (int i = t; i < NPG; i += 256){
            histD[hb + i] = hD[i];
            histS[hb + i] = hS[i];
        }
        return;
    }
    // node projection part (blocks 256..319)
    __shared__ float Ws[DIN*HID];
    __shared__ float as_s[HID], ad_s[HID];
    for (int i = t; i < DIN*HID; i += blockDim.x) Ws[i] = W1[i];
    if (t < HID){ as_s[t] = as1[t]; ad_s[t] = ad1[t]; }
    __syncthreads();
    int n = (blockIdx.x - 256)*blockDim.x + t;
    if (n >= NN) return;
    float xv[DIN];
    #pragma unroll
    for (int i = 0; i < DIN; i++) xv[i] = x[n*DIN + i];
    float hv[HID];
    #pragma unroll
    for (int j = 0; j < HID; j++){
        float a = 0.f;
        #pragma unroll
        for (int i = 0; i < DIN; i++) a += xv[i]*Ws[i*HID + j];
        hv[j] = a; h1[(size_t)n*HID + j] = a;
    }
    #pragma unroll
    for (int h = 0; h < NHEADS; h++){
        float s = 0.f, d = 0.f;
        #pragma unroll
        for (int c2 = 0; c2 < OUT1; c2++){ s += hv[h*OUT1+c2]*as_s[h*OUT1+c2]; d += hv[h*OUT1+c2]*ad_s[h*OUT1+c2]; }
        hs1[n*NHEADS + h] = s; hd1[n*NHEADS + h] = d;
    }
}

// ---------- fused: per-(g,n) chunk scan (in place) + per-graph node scan -> rowptr ----------
__global__ __launch_bounds__(1024) void k_cumscan(int* __restrict__ histD, int* __restrict__ histS,
                                                  int* __restrict__ rowptr, int* __restrict__ rowptrS){
    __shared__ int wtot[16], wbase[16];
    bool isD = (blockIdx.x < NB);
    int b = isD ? blockIdx.x : (blockIdx.x - NB);
    int* hist = isD ? histD : histS;
    int* rp   = isD ? rowptr : rowptrS;
    int n = threadIdx.x;
    int run = 0;
    #pragma unroll
    for (int c = 0; c < CH; c++){
        size_t idx = ((size_t)b*CH + c)*NPG + n;
        int v = hist[idx];
        hist[idx] = run;
        run += v;
    }
    int lane = n & 63, wv = n >> 6;
    int sincl = run;
    #pragma unroll
    for (int off = 1; off < 64; off <<= 1){
        int v = __shfl_up(sincl, off, 64);
        if (lane >= off) sincl += v;
    }
    if (lane == 63) wtot[wv] = sincl;
    __syncthreads();
    if (n == 0){
        int r = 0;
        #pragma unroll
        for (int w = 0; w < 16; w++){ wbase[w] = r; r += wtot[w]; }
    }
    __syncthreads();
    int excl = wbase[wv] + sincl - run;
    rp[b*NPG + n] = b*EPG + excl;
    if (b == NB-1 && n == NPG-1) rp[NN] = EE;
}

// ---------- deterministic scatter: slot = rowptr + chunk-base + LDS rank (no global atomics) ----------
__global__ void k_scatter_det(const int* __restrict__ src, const int* __restrict__ dst,
                              const int* __restrict__ rowptr, const int* __restrict__ rowptrS,
                              const int* __restrict__ histD, const int* __restrict__ histS,
                              int* __restrict__ srcs, int* __restrict__ eid,
                              int* __restrict__ dsts, int* __restrict__ nbrS){
    __shared__ int baseD[NPG], baseS[NPG];
    int t = threadIdx.x;
    int g, c; chunk_gc(g, c);
    size_t hb = ((size_t)g*CH + c)*NPG;
    for (int i = t; i < NPG; i += 256){
        baseD[i] = rowptr[g*NPG + i] + histD[hb + i];
        baseS[i] = rowptrS[g*NPG + i] + histS[hb + i];
    }
    __syncthreads();
    size_t e0 = ((size_t)g*CH + c)*CE;
    #pragma unroll
    for (int i = 0; i < 8; i++){
        size_t e = e0 + i*256 + t;
        int s = src[e], d = dst[e];
        int p = atomicAdd(&baseD[d & (NPG-1)], 1);
        srcs[p] = s; eid[p] = (int)e; dsts[p] = d;
        int pS = atomicAdd(&baseS[s & (NPG-1)], 1);
        nbrS[pS] = d;
    }
}

// ---------- edge proj + conv1 LOGITS into per-head planes (2048 blocks) ----------
__global__ void k_elogit(const float* __restrict__ ea, const float* __restrict__ We1,
                         const float* __restrict__ Wep1,
                         const int* __restrict__ srcs, const int* __restrict__ eid,
                         const int* __restrict__ dsts,
                         const float* __restrict__ hs1, const float* __restrict__ hd1,
                         float* __restrict__ lg1T, float* __restrict__ ewp1s){
    __shared__ float W[ED*NHEADS];
    __shared__ float Wp[ED];
    int t = threadIdx.x;
    if (t < ED*NHEADS) W[t] = We1[t];
    if (t < ED) Wp[t] = Wep1[t];
    __syncthreads();
    size_t k = xcd_chunk_base() + t;
    int s = srcs[k], e = eid[k], d = dsts[k];
    float a[ED];
    #pragma unroll
    for (int i = 0; i < ED; i++) a[i] = ea[(size_t)e*ED + i];
    const float* hsr = hs1 + (size_t)s*NHEADS;
    const float* hdr = hd1 + (size_t)d*NHEADS;
    #pragma unroll
    for (int h = 0; h < NHEADS; h++){
        float sv = 0.f;
        #pragma unroll
        for (int i = 0; i < ED; i++) sv += a[i]*W[i*NHEADS + h];
        lg1T[(size_t)h*EE + k] = lrelu(hsr[h] + hdr[h] + sv);
    }
    float sv = 0.f;
    #pragma unroll
    for (int i = 0; i < ED; i++) sv += a[i]*Wp[i];
    ewp1s[k] = sv;
}

// ---------- conv1 aggregation: graph-local h1 staged in LDS ----------
__global__ __launch_bounds__(640) void k_conv1_agg(const int* __restrict__ srcs,
                            const int* __restrict__ rowptr,
                            const float* __restrict__ h1, const float* __restrict__ lg1T,
                            float* __restrict__ x1){
    __shared__ float hls[NPG*HID];   // 122880 B
    int t = threadIdx.x;
    int xx = blockIdx.x & 7;
    int j = blockIdx.x >> 3;         // 0..31
    int g = xx + 8*(j >> 4);         // 2 graphs per XCD
    int seg = j & 15;                // 64-node segment
    const float* hg = h1 + (size_t)g*NPG*HID;
    for (int i = t; i < NPG*HID; i += 640) hls[i] = hg[i];
    __syncthreads();
    int nl = seg*64 + t/10;
    int r = t - (t/10)*10;
    int h = r >> 1;
    int q = r & 1;
    int n = g*NPG + nl;
    int k0 = rowptr[n], k1 = rowptr[n+1];
    const float* lgh = lg1T + (size_t)h*EE;
    int off = h*OUT1 + q*3;
    float m = -INFINITY, den = 0.f;
    float acc[3] = {0.f, 0.f, 0.f};
    int k = k0;
    for (; k + 4 <= k1; k += 4){
        float l0 = lgh[k+0], l1 = lgh[k+1], l2 = lgh[k+2], l3 = lgh[k+3];
        int s0 = srcs[k+0] & (NPG-1), s1 = srcs[k+1] & (NPG-1);
        int s2 = srcs[k+2] & (NPG-1), s3 = srcs[k+3] & (NPG-1);
        const float* p0 = hls + s0*HID + off;
        const float* p1 = hls + s1*HID + off;
        const float* p2 = hls + s2*HID + off;
        const float* p3 = hls + s3*HID + off;
        float mb = fmaxf(fmaxf(l0, l1), fmaxf(l2, l3));
        float mn = fmaxf(m, mb);
        float f  = expf(m - mn);       // first batch: exp(-inf)=0
        float e0 = expf(l0 - mn), e1 = expf(l1 - mn);
        float e2 = expf(l2 - mn), e3 = expf(l3 - mn);
        m = mn;
        den = den*f + e0 + e1 + e2 + e3;
        #pragma unroll
        for (int c = 0; c < 3; c++)
            acc[c] = acc[c]*f + e0*p0[c] + e1*p1[c] + e2*p2[c] + e3*p3[c];
    }
    for (; k < k1; k++){
        float l = lgh[k];
        int s = srcs[k] & (NPG-1);
        float mn = fmaxf(m, l);
        float f  = expf(m - mn);
        float ex = expf(l - mn);
        m = mn;
        den = den*f + ex;
        const float* hr = hls + s*HID + off;
        #pragma unroll
        for (int c = 0; c < 3; c++) acc[c] = acc[c]*f + ex*hr[c];
    }
    float inv = 1.f / (den + 1e-16f);
    #pragma unroll
    for (int c = 0; c < 3; c++) x1[(size_t)n*HID + off + c] = acc[c]*inv;
}

// ---------- merged: pool-conv1 prep (blocks 0..63) + dedup (blocks 64..127) ----------
__global__ void k_pd(const float* __restrict__ x1, const float* __restrict__ Wp1,
                     const float* __restrict__ asp, const float* __restrict__ adp,
                     float* __restrict__ hp1, float* __restrict__ hsp, float* __restrict__ hdp,
                     const int* __restrict__ rowptrS, const int* __restrict__ nbrS,
                     int* __restrict__ unbr, int* __restrict__ ucnt,
                     float* __restrict__ scal){
    __shared__ float Ws[HID*C1];
    __shared__ float as_s[C1], ad_s[C1];
    __shared__ unsigned int bm[256*33];
    __shared__ int red[256];
    int t = threadIdx.x;
    if (blockIdx.x < 64){
        for (int i = t; i < HID*C1; i += blockDim.x) Ws[i] = Wp1[i];
        if (t < C1){ as_s[t] = asp[t]; ad_s[t] = adp[t]; }
        __syncthreads();
        int n = blockIdx.x*blockDim.x + t;
        float xv[HID];
        #pragma unroll
        for (int d = 0; d < HID; d++) xv[d] = x1[(size_t)n*HID + d];
        float s = 0.f, dd = 0.f;
        for (int c = 0; c < C1; c++){
            float a = 0.f;
            #pragma unroll
            for (int d = 0; d < HID; d++) a += xv[d]*Ws[d*C1 + c];
            hp1[(size_t)n*C1 + c] = a;
            s += a*as_s[c]; dd += a*ad_s[c];
        }
        hsp[n] = s; hdp[n] = dd;
        return;
    }
    // dedup via per-thread LDS bitmap
    unsigned int* mybm = &bm[t*33];
    #pragma unroll
    for (int i = 0; i < 32; i++) mybm[i] = 0u;
    int n = (blockIdx.x - 64)*blockDim.x + t;
    int cnt = 0;
    {
        int k0 = rowptrS[n], k1 = rowptrS[n+1];
        for (int k = k0; k < k1; k++){
            int m = nbrS[k];
            int loc = m & (NPG-1);
            unsigned int w = (unsigned int)(loc >> 5);
            unsigned int bit = 1u << (loc & 31);
            unsigned int old = mybm[w];
            if (!(old & bit)){
                mybm[w] = old | bit;
                unbr[k0 + cnt] = m;
                cnt++;
            }
        }
        ucnt[n] = cnt;
    }
    red[t] = cnt; __syncthreads();
    for (int s = 128; s > 0; s >>= 1){ if (t < s) red[t] += red[t+s]; __syncthreads(); }
    if (t == 0) atomicAdd(&scal[0], (float)red[0]);
}

// ---------- pool logits: all-coalesced reads ----------
__global__ void k_plogit(const int* __restrict__ srcs, const int* __restrict__ dsts,
                         const float* __restrict__ hsp, const float* __restrict__ hdp,
                         const float* __restrict__ ewp1s, float* __restrict__ lgp){
    size_t k = xcd_chunk_base() + threadIdx.x;
    lgp[k] = lrelu(hsp[srcs[k]] + hdp[dsts[k]] + ewp1s[k]);
}

// ---------- pool-conv1 aggregation: graph-local hp1 staged in LDS (stride-33) + fused softmax ----------
// 256 blocks (16/graph) x 512 threads (64 nodes x 8 q-slices).
__global__ __launch_bounds__(512) void k_pool1_agg(const int* __restrict__ srcs,
                            const int* __restrict__ rowptr,
                            const float* __restrict__ hp1, const float* __restrict__ lgp,
                            float* __restrict__ ssoft){
    __shared__ float hls[NPG*33];   // 135168 B, padded rows -> banks rotate
    __shared__ float sm[64*33];     // 8448 B
    int t = threadIdx.x;
    int xx = blockIdx.x & 7;
    int j = blockIdx.x >> 3;
    int g = xx + 8*(j >> 4);
    int seg = j & 15;
    const float* hg = hp1 + (size_t)g*NPG*C1;
    for (int i = t; i < NPG*C1; i += 512){
        int s = i >> 5, c = i & 31;
        hls[s*33 + c] = hg[i];
    }
    __syncthreads();
    int nl = t >> 3, q = t & 7;
    int n = g*NPG + seg*64 + nl;
    int k0 = rowptr[n], k1 = rowptr[n+1];
    float m = -INFINITY, den = 0.f;
    float acc[4] = {0.f, 0.f, 0.f, 0.f};
    int k = k0;
    for (; k + 4 <= k1; k += 4){
        float l0 = lgp[k+0], l1 = lgp[k+1], l2 = lgp[k+2], l3 = lgp[k+3];
        int b0 = (srcs[k+0] & (NPG-1))*33 + q*4;
        int b1 = (srcs[k+1] & (NPG-1))*33 + q*4;
        int b2 = (srcs[k+2] & (NPG-1))*33 + q*4;
        int b3 = (srcs[k+3] & (NPG-1))*33 + q*4;
        float mb = fmaxf(fmaxf(l0, l1), fmaxf(l2, l3));
        float mn = fmaxf(m, mb);
        float f  = expf(m - mn);
        float e0 = expf(l0 - mn), e1 = expf(l1 - mn);
        float e2 = expf(l2 - mn), e3 = expf(l3 - mn);
        m = mn;
        den = den*f + e0 + e1 + e2 + e3;
        #pragma unroll
        for (int c = 0; c < 4; c++)
            acc[c] = acc[c]*f + e0*hls[b0+c] + e1*hls[b1+c] + e2*hls[b2+c] + e3*hls[b3+c];
    }
    for (; k < k1; k++){
        float l = lgp[k];
        int b = (srcs[k] & (NPG-1))*33 + q*4;
        float mn = fmaxf(m, l);
        float f  = expf(m - mn);
        float ex = expf(l - mn);
        m = mn;
        den = den*f + ex;
        #pragma unroll
        for (int c = 0; c < 4; c++) acc[c] = acc[c]*f + ex*hls[b+c];
    }
    float inv = 1.f / (den + 1e-16f);
    #pragma unroll
    for (int c = 0; c < 4; c++) sm[nl*33 + q*4 + c] = acc[c]*inv;
    __syncthreads();
    // cluster softmax over the node's 32 channels (redundant per slice-thread)
    float mx = -INFINITY;
    #pragma unroll 8
    for (int i = 0; i < C1; i++) mx = fmaxf(mx, sm[nl*33 + i]);
    float sum = 0.f;
    #pragma unroll 8
    for (int i = 0; i < C1; i++) sum += expf(sm[nl*33 + i] - mx);
    float is = 1.f/sum;
    #pragma unroll
    for (int c = 0; c < 4; c++)
        ssoft[(size_t)n*C1 + q*4 + c] = expf(sm[nl*33 + q*4 + c] - mx)*is;
}

// ---------- T: graph-local ssoft staged in LDS (stride-33) ----------
// 256 blocks (16/graph) x 512 threads (64 nodes x 8 q-slices).
__global__ __launch_bounds__(512) void k_T(const int* __restrict__ rowptrS,
                    const int* __restrict__ unbr,
                    const int* __restrict__ ucnt, const float* __restrict__ ssoft,
                    float* __restrict__ T){
    __shared__ float sls[NPG*33];   // 135168 B
    int t = threadIdx.x;
    int xx = blockIdx.x & 7;
    int j = blockIdx.x >> 3;
    int g = xx + 8*(j >> 4);
    int seg = j & 15;
    const float* sg = ssoft + (size_t)g*NPG*C1;
    for (int i = t; i < NPG*C1; i += 512){
        int s = i >> 5, c = i & 31;
        sls[s*33 + c] = sg[i];
    }
    __syncthreads();
    int nl = t >> 3, q = t & 7;
    int n = g*NPG + seg*64 + nl;
    int k0 = rowptrS[n];
    int cnt = ucnt[n];
    float acc[4] = {0.f, 0.f, 0.f, 0.f};
    int i = 0;
    for (; i + 4 <= cnt; i += 4){
        int b0 = (unbr[k0+i+0] & (NPG-1))*33 + q*4;
        int b1 = (unbr[k0+i+1] & (NPG-1))*33 + q*4;
        int b2 = (unbr[k0+i+2] & (NPG-1))*33 + q*4;
        int b3 = (unbr[k0+i+3] & (NPG-1))*33 + q*4;
        #pragma unroll
        for (int c = 0; c < 4; c++)
            acc[c] += sls[b0+c] + sls[b1+c] + sls[b2+c] + sls[b3+c];
    }
    for (; i < cnt; i++){
        int b = (unbr[k0+i] & (NPG-1))*33 + q*4;
        #pragma unroll
        for (int c = 0; c < 4; c++) acc[c] += sls[b+c];
    }
    #pragma unroll
    for (int c = 0; c < 4; c++) T[(size_t)n*C1 + q*4 + c] = acc[c];
}

// ---------- fused partials over 64-node chunks ----------
__global__ void k_partials(const float* __restrict__ ssoft, const float* __restrict__ T,
                           const float* __restrict__ x1,
                           float* __restrict__ adj2, float* __restrict__ Gm,
                           float* __restrict__ x2){
    int b  = blockIdx.y;
    int n0 = blockIdx.x * 64;
    int t  = threadIdx.x;   // 256
    __shared__ float ssh[64*C1];
    __shared__ float tsh[64*C1];
    __shared__ float xsh[64*HID];
    {
        size_t sbase = ((size_t)b*NPG + n0)*C1;
        #pragma unroll
        for (int i = 0; i < 8; i++){
            int lin = t + i*256;
            ssh[lin] = ssoft[sbase + lin];
            tsh[lin] = T[sbase + lin];
        }
        size_t xbase = ((size_t)b*NPG + n0)*HID;
        for (int lin = t; lin < 64*HID; lin += 256) xsh[lin] = x1[xbase + lin];
    }
    __syncthreads();
    float accA[4] = {0,0,0,0}, accG[4] = {0,0,0,0}, accX[4] = {0,0,0,0};
    int cA[4], kA[4], cX[4], dX[4];
    #pragma unroll
    for (int q = 0; q < 4; q++){
        int p = t + q*256;
        cA[q] = p >> 5; kA[q] = p & 31;
        cX[q] = p / HID; dX[q] = p - cX[q]*HID;   // valid only when p < 960
    }
    for (int r = 0; r < 64; r++){
        const float* sr = ssh + r*C1;
        const float* tr = tsh + r*C1;
        const float* xr = xsh + r*HID;
        #pragma unroll
        for (int q = 0; q < 4; q++){
            float sc = sr[cA[q]];
            accA[q] += sc*tr[kA[q]];
            accG[q] += sc*sr[kA[q]];
        }
        #pragma unroll
        for (int q = 0; q < 4; q++){
            int p = t + q*256;
            if (p < C1*HID) accX[q] += sr[cX[q]]*xr[dX[q]];
        }
    }
    #pragma unroll
    for (int q = 0; q < 4; q++){
        int p = t + q*256;
        atomicAdd(&adj2[(size_t)b*1024 + p], accA[q]);
        atomicAdd(&Gm[(size_t)b*1024 + p], accG[q]);
        if (p < C1*HID) atomicAdd(&x2[((size_t)b*C1 + cX[q])*HID + dX[q]], accX[q]);
    }
}

// ---------- fused tail: finalize + pool-conv2 + diffpool2 + per-graph MLP + reg (last block) ----------
__global__ void k_tail(const float* __restrict__ x2, const float* __restrict__ adj2,
                       const float* __restrict__ Gm,
                       const float* __restrict__ Wp2, const float* __restrict__ asp,
                       const float* __restrict__ adp, const float* __restrict__ Wep2,
                       const float* __restrict__ Wf1, const float* __restrict__ bf1,
                       const float* __restrict__ Wf2, const float* __restrict__ bf2,
                       float* __restrict__ out, float* __restrict__ scal,
                       unsigned int* __restrict__ ctr){
    int b = blockIdx.x;
    int t = threadIdx.x;  // 256
    __shared__ float x2s[C1*HID];    // 960
    __shared__ float a2s[C1*C1];     // 1024
    __shared__ float Wps[HID*C2];    // 120
    __shared__ float h2s[C1*C2];
    __shared__ float hs2s[C1], hd2s[C1];
    __shared__ float sss[C1*C2];     // softmax(s2)
    __shared__ float x3s[C2*HID];    // 120
    __shared__ float zsh[32];
    __shared__ float red[256];
    for (int i = t; i < C1*HID; i += 256) x2s[i] = x2[(size_t)b*C1*HID + i];
    for (int i = t; i < C1*C1; i += 256) a2s[i] = adj2[(size_t)b*C1*C1 + i];
    if (t < HID*C2) Wps[t] = Wp2[t];
    __syncthreads();
    // finalize reg1 ingredients from this graph: trace(adj2), ||G||_F^2
    {
        float ltr = 0.f, lfr = 0.f;
        for (int p = t; p < 1024; p += 256){
            float g = Gm[(size_t)b*1024 + p];
            lfr += g*g;
            if ((p >> 5) == (p & 31)) ltr += a2s[p];
        }
        red[t] = ltr; __syncthreads();
        for (int s = 128; s > 0; s >>= 1){ if (t < s) red[t] += red[t+s]; __syncthreads(); }
        if (t == 0) atomicAdd(&scal[1], red[0]);
        __syncthreads();
        red[t] = lfr; __syncthreads();
        for (int s = 128; s > 0; s >>= 1){ if (t < s) red[t] += red[t+s]; __syncthreads(); }
        if (t == 0) atomicAdd(&scal[2], red[0]);
        __syncthreads();
    }
    // phase 1: h2 = x2@Wp2 + attention scalars
    if (t < C1){
        float s = 0.f, dd = 0.f;
        #pragma unroll
        for (int c = 0; c < C2; c++){
            float a = 0.f;
            #pragma unroll
            for (int d = 0; d < HID; d++) a += x2s[t*HID + d]*Wps[d*C2 + c];
            h2s[t*C2 + c] = a;
            s += a*asp[c]; dd += a*adp[c];
        }
        hs2s[t] = s; hd2s[t] = dd;
    }
    __syncthreads();
    // phase 2: dense EGAT agg over 32 sources + softmax over C2
    if (t < C1){
        int j = t;
        float hdv = hd2s[j];
        float wep = Wep2[0];
        float m = -INFINITY;
        for (int i = 0; i < C1; i++)
            m = fmaxf(m, lrelu(hs2s[i] + hdv + a2s[i*C1 + j]*wep));
        float den = 0.f;
        float acc[C2] = {0,0,0,0};
        for (int i = 0; i < C1; i++){
            float ex = expf(lrelu(hs2s[i] + hdv + a2s[i*C1 + j]*wep) - m);
            den += ex;
            #pragma unroll
            for (int c = 0; c < C2; c++) acc[c] += ex * h2s[i*C2 + c];
        }
        float inv = 1.f/(den + 1e-16f);
        float v[C2]; float mx = -INFINITY;
        #pragma unroll
        for (int c = 0; c < C2; c++){ v[c] = acc[c]*inv; mx = fmaxf(mx, v[c]); }
        float sum = 0.f;
        #pragma unroll
        for (int c = 0; c < C2; c++){ v[c] = expf(v[c] - mx); sum += v[c]; }
        float i2 = 1.f/sum;
        #pragma unroll
        for (int c = 0; c < C2; c++) sss[j*C2 + c] = v[c]*i2;
    }
    __syncthreads();
    // phase 3: x3 = S^T x2 (LDS only) and reg2
    if (t < C2*HID){
        int c = t / HID, d = t % HID;
        float a = 0.f;
        #pragma unroll
        for (int n = 0; n < C1; n++) a += sss[n*C2 + c]*x2s[n*HID + d];
        x3s[t] = a;
    }
    {
        float loc = 0.f;
        for (int p = t; p < 1024; p += 256){
            int n = p >> 5, mm = p & 31;
            float dot = 0.f;
            #pragma unroll
            for (int c = 0; c < C2; c++) dot += sss[n*C2 + c]*sss[mm*C2 + c];
            float df = a2s[p] - dot;
            loc += df*df;
        }
        red[t] = loc; __syncthreads();
        for (int s = 128; s > 0; s >>= 1){ if (t < s) red[t] += red[t+s]; __syncthreads(); }
        if (t == 0) atomicAdd(&scal[3], red[0]);
        __syncthreads();
    }
    // phase 4: per-graph MLP -> out[2b], out[2b+1]
    if (t < 32){
        float a = bf1[t];
        #pragma unroll 4
        for (int k = 0; k < C2*HID; k++) a += x3s[k]*Wf1[k*32 + t];
        zsh[t] = fmaxf(a, 0.f);
    }
    __syncthreads();
    if (t < 2){
        float a = bf2[t];
        #pragma unroll
        for (int j = 0; j < 32; j++) a += zsh[j]*Wf2[j*2 + t];
        out[b*2 + t] = a;
    }
    // phase 5: last finished block assembles the reg scalar
    if (t == 0){
        __threadfence();
        unsigned int old = atomicAdd(ctr, 1u);
        if (old == NB - 1){
            float adjsum = atomicAdd(&scal[0], 0.f);
            float tr     = atomicAdd(&scal[1], 0.f);
            float fr     = atomicAdd(&scal[2], 0.f);
            float r2     = atomicAdd(&scal[3], 0.f);
            float reg1 = (adjsum - 2.f*tr + fr) * (1.f/16777216.f);
            float reg2 = r2 * (1.f/16384.f);
            out[32] = 10.f*reg1 + 0.1f*reg2;
        }
    }
}

extern "C" void kernel_launch(void* const* d_in, const int* in_sizes, int n_in,
                              void* d_out, int out_size, void* d_ws, size_t ws_size,
                              hipStream_t stream) {
    const float* x    = (const float*)d_in[0];
    const int*   ei   = (const int*)d_in[1];
    const float* ea   = (const float*)d_in[2];
    // d_in[3] = y (unused); d_in[4] = adj (algebraically eliminated — never read)
    const float* W1   = (const float*)d_in[5];
    const float* as1  = (const float*)d_in[6];
    const float* ad1  = (const float*)d_in[7];
    const float* We1  = (const float*)d_in[8];
    const float* Wp1  = (const float*)d_in[9];
    const float* asp1 = (const float*)d_in[10];
    const float* adp1 = (const float*)d_in[11];
    const float* Wep1 = (const float*)d_in[12];
    const float* Wp2  = (const float*)d_in[13];
    const float* asp2 = (const float*)d_in[14];
    const float* adp2 = (const float*)d_in[15];
    const float* Wep2 = (const float*)d_in[16];
    const float* Wf1  = (const float*)d_in[17];
    const float* bf1  = (const float*)d_in[18];
    const float* Wf2  = (const float*)d_in[19];
    const float* bf2  = (const float*)d_in[20];
    float* out = (float*)d_out;

    const int* srcA = ei;
    const int* dstA = ei + EE;

    char* wp = (char*)d_ws;
    auto carve = [&](size_t bytes)->char*{
        char* p = wp;
        wp += (bytes + 255) & ~(size_t)255;
        return p;
    };
    float* h1    = (float*)carve((size_t)NN*HID*4);
    float* hs1   = (float*)carve((size_t)NN*NHEADS*4);
    float* hd1   = (float*)carve((size_t)NN*NHEADS*4);
    float* lg1T  = (float*)carve((size_t)EE*NHEADS*4);
    float* ewp1s = (float*)carve((size_t)EE*4);
    float* lgp   = (float*)carve((size_t)EE*4);
    float* x1    = (float*)carve((size_t)NN*HID*4);
    float* hp1   = (float*)carve((size_t)NN*C1*4);
    float* hsp   = (float*)carve((size_t)NN*4);
    float* hdp   = (float*)carve((size_t)NN*4);
    float* ssoft = (float*)carve((size_t)NN*C1*4);
    float* T     = (float*)carve((size_t)NN*C1*4);
    // --- zero-init region (contiguous): x2, adj2, Gm ---
    float* x2    = (float*)carve((size_t)NB*C1*HID*4);   // 61440 B (256-aligned)
    float* adj2  = (float*)carve((size_t)NB*C1*C1*4);    // 65536 B
    float* Gm    = (float*)carve((size_t)NB*C1*C1*4);    // 65536 B
    // ---------------------------------------------------
    float* scal  = (float*)carve(16*4);                  // [0..3] sums, [8] ctr
    unsigned int* ctr = (unsigned int*)(scal + 8);
    int* histD   = (int*)carve((size_t)NB*CH*NPG*4);     // 1 MB
    int* histS   = (int*)carve((size_t)NB*CH*NPG*4);     // 1 MB
    int* rowptr  = (int*)carve((size_t)(NN+1)*4);
    int* rowptrS = (int*)carve((size_t)(NN+1)*4);
    int* srcs    = (int*)carve((size_t)EE*4);
    int* eid     = (int*)carve((size_t)EE*4);
    int* dsts    = (int*)carve((size_t)EE*4);
    int* nbrS    = (int*)carve((size_t)EE*4);
    int* unbr    = (int*)carve((size_t)EE*4);
    int* ucnt    = (int*)carve((size_t)NN*4);

    hipMemsetAsync(scal, 0, 16*4, stream);
    hipMemsetAsync(x2, 0, (size_t)(NB*C1*HID + 2*NB*C1*C1)*4, stream);  // x2+adj2+Gm

    const int TB = 256;

    // merged: per-chunk dual LDS histograms (256 blocks) + node projection (64 blocks)
    k_hist_chunk<<<dim3(256 + 64), TB, 0, stream>>>(srcA, dstA, histD, histS,
                                                    x, W1, as1, ad1, h1, hs1, hd1);
    // fused chunk-scan + per-graph node scan -> rowptr/rowptrS
    k_cumscan<<<dim3(2*NB), 1024, 0, stream>>>(histD, histS, rowptr, rowptrS);
    // deterministic scatter (LDS atomics only)
    k_scatter_det<<<dim3(256), TB, 0, stream>>>(srcA, dstA, rowptr, rowptrS,
                                                histD, histS, srcs, eid, dsts, nbrS);

    // edge proj + conv1 logit planes
    k_elogit<<<dim3(2048), TB, 0, stream>>>(ea, We1, Wep1, srcs, eid, dsts, hs1, hd1, lg1T, ewp1s);

    // conv1: graph-local h1 staged in LDS (256 blocks x 640 threads)
    k_conv1_agg<<<dim3(256), 640, 0, stream>>>(srcs, rowptr, h1, lg1T, x1);

    // merged: pool-conv1 prep (64 blocks) + dedup (64 blocks, concurrent)
    k_pd<<<dim3(128), TB, 0, stream>>>(x1, Wp1, asp1, adp1, hp1, hsp, hdp,
                                       rowptrS, nbrS, unbr, ucnt, scal);

    // pool-conv1 (+fused cluster softmax), graph-local LDS staging
    k_plogit<<<dim3(2048), TB, 0, stream>>>(srcs, dsts, hsp, hdp, ewp1s, lgp);
    k_pool1_agg<<<dim3(256), 512, 0, stream>>>(srcs, rowptr, hp1, lgp, ssoft);

    // diffpool1 (T with graph-local LDS staging)
    k_T<<<dim3(256), 512, 0, stream>>>(rowptrS, unbr, ucnt, ssoft, T);
    k_partials<<<dim3(16, NB), TB, 0, stream>>>(ssoft, T, x1, adj2, Gm, x2);

    // fused tail: finalize + pool-conv2 + diffpool2 + per-graph MLP + reg assembly
    k_tail<<<dim3(NB), TB, 0, stream>>>(x2, adj2, Gm, Wp2, asp2, adp2, Wep2,
                                        Wf1, bf1, Wf2, bf2, out, scal, ctr);
}

// Round 19
// 275.858 us; speedup vs baseline: 1.0540x; 1.0069x over previous
//
#include <hip/hip_runtime.h>
#include <math.h>

#define NB 16
#define NPG 1024
#define DIN 16
#define ED 8
#define NHEADS 5
#define OUT1 6
#define HID 30
#define C1 32
#define C2 4
#define NN (NB*NPG)      // 16384 nodes
#define EE (NN*32)       // 524288 edges
#define EPG 32768        // edges per graph (graph-contiguous in edge_index)
#define CH 16            // chunks per graph
#define CE 2048          // edges per chunk

__device__ __forceinline__ float lrelu(float v){ return v >= 0.f ? v : 0.2f*v; }

// chunk mapping for 256-block edge kernels: XCD-affine, block -> (g, c)
__device__ __forceinline__ void chunk_gc(int& g, int& c){
    int x = blockIdx.x & 7;
    int j = blockIdx.x >> 3;     // 0..31
    g = x + 8*(j >> 4);          // 2 graphs per XCD
    c = j & 15;
}

// XCD-affinity mapping for 2048-block edge kernels
__device__ __forceinline__ size_t xcd_chunk_base(){
    int x = blockIdx.x & 7;
    int j = blockIdx.x >> 3;            // 0..255 position within this XCD
    int g = x + 8*(j >> 7);             // 2 graphs per XCD
    int c = j & 127;                    // 128 chunks per graph
    return (size_t)g*EPG + (size_t)c*256;
}

// ---------- merged: per-chunk dual LDS histograms (blocks 0..255) + node projection ----------
__global__ void k_hist_chunk(const int* __restrict__ src, const int* __restrict__ dst,
                             int* __restrict__ histD, int* __restrict__ histS,
                             const float* __restrict__ x, const float* __restrict__ W1,
                             const float* __restrict__ as1, const float* __restrict__ ad1,
                             float* __restrict__ h1, float* __restrict__ hs1, float* __restrict__ hd1){
    int t = threadIdx.x;
    if (blockIdx.x < 256){
        __shared__ int hD[NPG], hS[NPG];
        for (int i = t; i < NPG; i += 256){ hD[i] = 0; hS[i] = 0; }
        __syncthreads();
        int g, c; chunk_gc(g, c);
        size_t e0 = ((size_t)g*CH + c)*CE;
        #pragma unroll
        for (int i = 0; i < 8; i++){
            size_t e = e0 + i*256 + t;
            atomicAdd(&hD[dst[e] & (NPG-1)], 1);
            atomicAdd(&hS[src[e] & (NPG-1)], 1);
        }
        __syncthreads();
        size_t hb = ((size_t)g*CH + c)*NPG;
        for (int i = t; i < NPG; i += 256){
            histD[hb + i] = hD[i];
            histS[hb + i] = hS[i];
        }
        return;
    }
    // node projection part (blocks 256..319)
    __shared__ float Ws[DIN*HID];
    __shared__ float as_s[HID], ad_s[HID];
    for (int i = t; i < DIN*HID; i += blockDim.x) Ws[i] = W1[i];
    if (t < HID){ as_s[t] = as1[t]; ad_s[t] = ad1[t]; }
    __syncthreads();
    int n = (blockIdx.x - 256)*blockDim.x + t;
    if (n >= NN) return;
    float xv[DIN];
    #pragma unroll
    for (int i = 0; i < DIN; i++) xv[i] = x[n*DIN + i];
    float hv[HID];
    #pragma unroll
    for (int j = 0; j < HID; j++){
        float a = 0.f;
        #pragma unroll
        for (int i = 0; i < DIN; i++) a += xv[i]*Ws[i*HID + j];
        hv[j] = a; h1[(size_t)n*HID + j] = a;
    }
    #pragma unroll
    for (int h = 0; h < NHEADS; h++){
        float s = 0.f, d = 0.f;
        #pragma unroll
        for (int c2 = 0; c2 < OUT1; c2++){ s += hv[h*OUT1+c2]*as_s[h*OUT1+c2]; d += hv[h*OUT1+c2]*ad_s[h*OUT1+c2]; }
        hs1[n*NHEADS + h] = s; hd1[n*NHEADS + h] = d;
    }
}

// ---------- fused: per-(g,n) chunk scan (in place) + per-graph node scan -> rowptr ----------
__global__ __launch_bounds__(1024) void k_cumscan(int* __restrict__ histD, int* __restrict__ histS,
                                                  int* __restrict__ rowptr, int* __restrict__ rowptrS){
    __shared__ int wtot[16], wbase[16];
    bool isD = (blockIdx.x < NB);
    int b = isD ? blockIdx.x : (blockIdx.x - NB);
    int* hist = isD ? histD : histS;
    int* rp   = isD ? rowptr : rowptrS;
    int n = threadIdx.x;
    int run = 0;
    #pragma unroll
    for (int c = 0; c < CH; c++){
        size_t idx = ((size_t)b*CH + c)*NPG + n;
        int v = hist[idx];
        hist[idx] = run;
        run += v;
    }
    int lane = n & 63, wv = n >> 6;
    int sincl = run;
    #pragma unroll
    for (int off = 1; off < 64; off <<= 1){
        int v = __shfl_up(sincl, off, 64);
        if (lane >= off) sincl += v;
    }
    if (lane == 63) wtot[wv] = sincl;
    __syncthreads();
    if (n == 0){
        int r = 0;
        #pragma unroll
        for (int w = 0; w < 16; w++){ wbase[w] = r; r += wtot[w]; }
    }
    __syncthreads();
    int excl = wbase[wv] + sincl - run;
    rp[b*NPG + n] = b*EPG + excl;
    if (b == NB-1 && n == NPG-1) rp[NN] = EE;
}

// ---------- deterministic scatter: slot = rowptr + chunk-base + LDS rank (no global atomics) ----------
__global__ void k_scatter_det(const int* __restrict__ src, const int* __restrict__ dst,
                              const int* __restrict__ rowptr, const int* __restrict__ rowptrS,
                              const int* __restrict__ histD, const int* __restrict__ histS,
                              int* __restrict__ srcs, int* __restrict__ eid,
                              int* __restrict__ dsts, int* __restrict__ nbrS){
    __shared__ int baseD[NPG], baseS[NPG];
    int t = threadIdx.x;
    int g, c; chunk_gc(g, c);
    size_t hb = ((size_t)g*CH + c)*NPG;
    for (int i = t; i < NPG; i += 256){
        baseD[i] = rowptr[g*NPG + i] + histD[hb + i];
        baseS[i] = rowptrS[g*NPG + i] + histS[hb + i];
    }
    __syncthreads();
    size_t e0 = ((size_t)g*CH + c)*CE;
    #pragma unroll
    for (int i = 0; i < 8; i++){
        size_t e = e0 + i*256 + t;
        int s = src[e], d = dst[e];
        int p = atomicAdd(&baseD[d & (NPG-1)], 1);
        srcs[p] = s; eid[p] = (int)e; dsts[p] = d;
        int pS = atomicAdd(&baseS[s & (NPG-1)], 1);
        nbrS[pS] = d;
    }
}

// ---------- edge proj + conv1 LOGITS into per-head planes (2048 blocks) ----------
__global__ void k_elogit(const float* __restrict__ ea, const float* __restrict__ We1,
                         const float* __restrict__ Wep1,
                         const int* __restrict__ srcs, const int* __restrict__ eid,
                         const int* __restrict__ dsts,
                         const float* __restrict__ hs1, const float* __restrict__ hd1,
                         float* __restrict__ lg1T, float* __restrict__ ewp1s){
    __shared__ float W[ED*NHEADS];
    __shared__ float Wp[ED];
    int t = threadIdx.x;
    if (t < ED*NHEADS) W[t] = We1[t];
    if (t < ED) Wp[t] = Wep1[t];
    __syncthreads();
    size_t k = xcd_chunk_base() + t;
    int s = srcs[k], e = eid[k], d = dsts[k];
    float a[ED];
    #pragma unroll
    for (int i = 0; i < ED; i++) a[i] = ea[(size_t)e*ED + i];
    const float* hsr = hs1 + (size_t)s*NHEADS;
    const float* hdr = hd1 + (size_t)d*NHEADS;
    #pragma unroll
    for (int h = 0; h < NHEADS; h++){
        float sv = 0.f;
        #pragma unroll
        for (int i = 0; i < ED; i++) sv += a[i]*W[i*NHEADS + h];
        lg1T[(size_t)h*EE + k] = lrelu(hsr[h] + hdr[h] + sv);
    }
    float sv = 0.f;
    #pragma unroll
    for (int i = 0; i < ED; i++) sv += a[i]*Wp[i];
    ewp1s[k] = sv;
}

// ---------- conv1 aggregation: graph-local h1 staged in LDS ----------
__global__ __launch_bounds__(640) void k_conv1_agg(const int* __restrict__ srcs,
                            const int* __restrict__ rowptr,
                            const float* __restrict__ h1, const float* __restrict__ lg1T,
                            float* __restrict__ x1){
    __shared__ float hls[NPG*HID];   // 122880 B
    int t = threadIdx.x;
    int xx = blockIdx.x & 7;
    int j = blockIdx.x >> 3;         // 0..31
    int g = xx + 8*(j >> 4);         // 2 graphs per XCD
    int seg = j & 15;                // 64-node segment
    const float* hg = h1 + (size_t)g*NPG*HID;
    for (int i = t; i < NPG*HID; i += 640) hls[i] = hg[i];
    __syncthreads();
    int nl = seg*64 + t/10;
    int r = t - (t/10)*10;
    int h = r >> 1;
    int q = r & 1;
    int n = g*NPG + nl;
    int k0 = rowptr[n], k1 = rowptr[n+1];
    const float* lgh = lg1T + (size_t)h*EE;
    int off = h*OUT1 + q*3;
    float m = -INFINITY, den = 0.f;
    float acc[3] = {0.f, 0.f, 0.f};
    int k = k0;
    for (; k + 4 <= k1; k += 4){
        float l0 = lgh[k+0], l1 = lgh[k+1], l2 = lgh[k+2], l3 = lgh[k+3];
        int s0 = srcs[k+0] & (NPG-1), s1 = srcs[k+1] & (NPG-1);
        int s2 = srcs[k+2] & (NPG-1), s3 = srcs[k+3] & (NPG-1);
        const float* p0 = hls + s0*HID + off;
        const float* p1 = hls + s1*HID + off;
        const float* p2 = hls + s2*HID + off;
        const float* p3 = hls + s3*HID + off;
        float mb = fmaxf(fmaxf(l0, l1), fmaxf(l2, l3));
        float mn = fmaxf(m, mb);
        float f  = expf(m - mn);       // first batch: exp(-inf)=0
        float e0 = expf(l0 - mn), e1 = expf(l1 - mn);
        float e2 = expf(l2 - mn), e3 = expf(l3 - mn);
        m = mn;
        den = den*f + e0 + e1 + e2 + e3;
        #pragma unroll
        for (int c = 0; c < 3; c++)
            acc[c] = acc[c]*f + e0*p0[c] + e1*p1[c] + e2*p2[c] + e3*p3[c];
    }
    for (; k < k1; k++){
        float l = lgh[k];
        int s = srcs[k] & (NPG-1);
        float mn = fmaxf(m, l);
        float f  = expf(m - mn);
        float ex = expf(l - mn);
        m = mn;
        den = den*f + ex;
        const float* hr = hls + s*HID + off;
        #pragma unroll
        for (int c = 0; c < 3; c++) acc[c] = acc[c]*f + ex*hr[c];
    }
    float inv = 1.f / (den + 1e-16f);
    #pragma unroll
    for (int c = 0; c < 3; c++) x1[(size_t)n*HID + off + c] = acc[c]*inv;
}

// ---------- merged: pool-conv1 prep (blocks 0..63) + dedup (blocks 64..127) ----------
__global__ void k_pd(const float* __restrict__ x1, const float* __restrict__ Wp1,
                     const float* __restrict__ asp, const float* __restrict__ adp,
                     float* __restrict__ hp1, float* __restrict__ hsp, float* __restrict__ hdp,
                     const int* __restrict__ rowptrS, const int* __restrict__ nbrS,
                     int* __restrict__ unbr, int* __restrict__ ucnt,
                     float* __restrict__ scal){
    __shared__ float Ws[HID*C1];
    __shared__ float as_s[C1], ad_s[C1];
    __shared__ unsigned int bm[256*33];
    __shared__ int red[256];
    int t = threadIdx.x;
    if (blockIdx.x < 64){
        for (int i = t; i < HID*C1; i += blockDim.x) Ws[i] = Wp1[i];
        if (t < C1){ as_s[t] = asp[t]; ad_s[t] = adp[t]; }
        __syncthreads();
        int n = blockIdx.x*blockDim.x + t;
        float xv[HID];
        #pragma unroll
        for (int d = 0; d < HID; d++) xv[d] = x1[(size_t)n*HID + d];
        float s = 0.f, dd = 0.f;
        for (int c = 0; c < C1; c++){
            float a = 0.f;
            #pragma unroll
            for (int d = 0; d < HID; d++) a += xv[d]*Ws[d*C1 + c];
            hp1[(size_t)n*C1 + c] = a;
            s += a*as_s[c]; dd += a*ad_s[c];
        }
        hsp[n] = s; hdp[n] = dd;
        return;
    }
    // dedup via per-thread LDS bitmap
    unsigned int* mybm = &bm[t*33];
    #pragma unroll
    for (int i = 0; i < 32; i++) mybm[i] = 0u;
    int n = (blockIdx.x - 64)*blockDim.x + t;
    int cnt = 0;
    {
        int k0 = rowptrS[n], k1 = rowptrS[n+1];
        for (int k = k0; k < k1; k++){
            int m = nbrS[k];
            int loc = m & (NPG-1);
            unsigned int w = (unsigned int)(loc >> 5);
            unsigned int bit = 1u << (loc & 31);
            unsigned int old = mybm[w];
            if (!(old & bit)){
                mybm[w] = old | bit;
                unbr[k0 + cnt] = m;
                cnt++;
            }
        }
        ucnt[n] = cnt;
    }
    red[t] = cnt; __syncthreads();
    for (int s = 128; s > 0; s >>= 1){ if (t < s) red[t] += red[t+s]; __syncthreads(); }
    if (t == 0) atomicAdd(&scal[0], (float)red[0]);
}

// ---------- pool-conv1 aggregation: graph-local hp1+hsp staged in LDS, inline logits,
//            fused cluster softmax. 256 blocks (16/graph) x 512 threads. ----------
__global__ __launch_bounds__(512) void k_pool1_agg(const int* __restrict__ srcs,
                            const int* __restrict__ rowptr,
                            const float* __restrict__ hp1, const float* __restrict__ hsp,
                            const float* __restrict__ hdp, const float* __restrict__ ewp1s,
                            float* __restrict__ ssoft){
    __shared__ float hls[NPG*33];   // 135168 B, padded rows -> banks rotate
    __shared__ float sm[64*33];     // 8448 B
    __shared__ float hsps[NPG];     // 4096 B
    __shared__ float hdps[64];      // 256 B
    int t = threadIdx.x;
    int xx = blockIdx.x & 7;
    int j = blockIdx.x >> 3;
    int g = xx + 8*(j >> 4);
    int seg = j & 15;
    const float* hg = hp1 + (size_t)g*NPG*C1;
    for (int i = t; i < NPG*C1; i += 512){
        int s = i >> 5, c = i & 31;
        hls[s*33 + c] = hg[i];
    }
    for (int i = t; i < NPG; i += 512) hsps[i] = hsp[g*NPG + i];
    if (t < 64) hdps[t] = hdp[g*NPG + seg*64 + t];
    __syncthreads();
    int nl = t >> 3, q = t & 7;
    int n = g*NPG + seg*64 + nl;
    int k0 = rowptr[n], k1 = rowptr[n+1];
    float hdv = hdps[nl];
    float m = -INFINITY, den = 0.f;
    float acc[4] = {0.f, 0.f, 0.f, 0.f};
    int k = k0;
    for (; k + 4 <= k1; k += 4){
        int sl0 = srcs[k+0] & (NPG-1), sl1 = srcs[k+1] & (NPG-1);
        int sl2 = srcs[k+2] & (NPG-1), sl3 = srcs[k+3] & (NPG-1);
        float l0 = lrelu(hsps[sl0] + hdv + ewp1s[k+0]);
        float l1 = lrelu(hsps[sl1] + hdv + ewp1s[k+1]);
        float l2 = lrelu(hsps[sl2] + hdv + ewp1s[k+2]);
        float l3 = lrelu(hsps[sl3] + hdv + ewp1s[k+3]);
        int b0 = sl0*33 + q*4, b1 = sl1*33 + q*4;
        int b2 = sl2*33 + q*4, b3 = sl3*33 + q*4;
        float mb = fmaxf(fmaxf(l0, l1), fmaxf(l2, l3));
        float mn = fmaxf(m, mb);
        float f  = expf(m - mn);
        float e0 = expf(l0 - mn), e1 = expf(l1 - mn);
        float e2 = expf(l2 - mn), e3 = expf(l3 - mn);
        m = mn;
        den = den*f + e0 + e1 + e2 + e3;
        #pragma unroll
        for (int c = 0; c < 4; c++)
            acc[c] = acc[c]*f + e0*hls[b0+c] + e1*hls[b1+c] + e2*hls[b2+c] + e3*hls[b3+c];
    }
    for (; k < k1; k++){
        int sl = srcs[k] & (NPG-1);
        float l = lrelu(hsps[sl] + hdv + ewp1s[k]);
        int b = sl*33 + q*4;
        float mn = fmaxf(m, l);
        float f  = expf(m - mn);
        float ex = expf(l - mn);
        m = mn;
        den = den*f + ex;
        #pragma unroll
        for (int c = 0; c < 4; c++) acc[c] = acc[c]*f + ex*hls[b+c];
    }
    float inv = 1.f / (den + 1e-16f);
    #pragma unroll
    for (int c = 0; c < 4; c++) sm[nl*33 + q*4 + c] = acc[c]*inv;
    __syncthreads();
    // cluster softmax over the node's 32 channels (redundant per slice-thread)
    float mx = -INFINITY;
    #pragma unroll 8
    for (int i = 0; i < C1; i++) mx = fmaxf(mx, sm[nl*33 + i]);
    float sum = 0.f;
    #pragma unroll 8
    for (int i = 0; i < C1; i++) sum += expf(sm[nl*33 + i] - mx);
    float is = 1.f/sum;
    #pragma unroll
    for (int c = 0; c < 4; c++)
        ssoft[(size_t)n*C1 + q*4 + c] = expf(sm[nl*33 + q*4 + c] - mx)*is;
}

// ---------- T: graph-local ssoft staged in LDS (stride-33) ----------
__global__ __launch_bounds__(512) void k_T(const int* __restrict__ rowptrS,
                    const int* __restrict__ unbr,
                    const int* __restrict__ ucnt, const float* __restrict__ ssoft,
                    float* __restrict__ T){
    __shared__ float sls[NPG*33];   // 135168 B
    int t = threadIdx.x;
    int xx = blockIdx.x & 7;
    int j = blockIdx.x >> 3;
    int g = xx + 8*(j >> 4);
    int seg = j & 15;
    const float* sg = ssoft + (size_t)g*NPG*C1;
    for (int i = t; i < NPG*C1; i += 512){
        int s = i >> 5, c = i & 31;
        sls[s*33 + c] = sg[i];
    }
    __syncthreads();
    int nl = t >> 3, q = t & 7;
    int n = g*NPG + seg*64 + nl;
    int k0 = rowptrS[n];
    int cnt = ucnt[n];
    float acc[4] = {0.f, 0.f, 0.f, 0.f};
    int i = 0;
    for (; i + 4 <= cnt; i += 4){
        int b0 = (unbr[k0+i+0] & (NPG-1))*33 + q*4;
        int b1 = (unbr[k0+i+1] & (NPG-1))*33 + q*4;
        int b2 = (unbr[k0+i+2] & (NPG-1))*33 + q*4;
        int b3 = (unbr[k0+i+3] & (NPG-1))*33 + q*4;
        #pragma unroll
        for (int c = 0; c < 4; c++)
            acc[c] += sls[b0+c] + sls[b1+c] + sls[b2+c] + sls[b3+c];
    }
    for (; i < cnt; i++){
        int b = (unbr[k0+i] & (NPG-1))*33 + q*4;
        #pragma unroll
        for (int c = 0; c < 4; c++) acc[c] += sls[b+c];
    }
    #pragma unroll
    for (int c = 0; c < 4; c++) T[(size_t)n*C1 + q*4 + c] = acc[c];
}

// ---------- fused partials over 64-node chunks ----------
__global__ void k_partials(const float* __restrict__ ssoft, const float* __restrict__ T,
                           const float* __restrict__ x1,
                           float* __restrict__ adj2, float* __restrict__ Gm,
                           float* __restrict__ x2){
    int b  = blockIdx.y;
    int n0 = blockIdx.x * 64;
    int t  = threadIdx.x;   // 256
    __shared__ float ssh[64*C1];
    __shared__ float tsh[64*C1];
    __shared__ float xsh[64*HID];
    {
        size_t sbase = ((size_t)b*NPG + n0)*C1;
        #pragma unroll
        for (int i = 0; i < 8; i++){
            int lin = t + i*256;
            ssh[lin] = ssoft[sbase + lin];
            tsh[lin] = T[sbase + lin];
        }
        size_t xbase = ((size_t)b*NPG + n0)*HID;
        for (int lin = t; lin < 64*HID; lin += 256) xsh[lin] = x1[xbase + lin];
    }
    __syncthreads();
    float accA[4] = {0,0,0,0}, accG[4] = {0,0,0,0}, accX[4] = {0,0,0,0};
    int cA[4], kA[4], cX[4], dX[4];
    #pragma unroll
    for (int q = 0; q < 4; q++){
        int p = t + q*256;
        cA[q] = p >> 5; kA[q] = p & 31;
        cX[q] = p / HID; dX[q] = p - cX[q]*HID;   // valid only when p < 960
    }
    for (int r = 0; r < 64; r++){
        const float* sr = ssh + r*C1;
        const float* tr = tsh + r*C1;
        const float* xr = xsh + r*HID;
        #pragma unroll
        for (int q = 0; q < 4; q++){
            float sc = sr[cA[q]];
            accA[q] += sc*tr[kA[q]];
            accG[q] += sc*sr[kA[q]];
        }
        #pragma unroll
        for (int q = 0; q < 4; q++){
            int p = t + q*256;
            if (p < C1*HID) accX[q] += sr[cX[q]]*xr[dX[q]];
        }
    }
    #pragma unroll
    for (int q = 0; q < 4; q++){
        int p = t + q*256;
        atomicAdd(&adj2[(size_t)b*1024 + p], accA[q]);
        atomicAdd(&Gm[(size_t)b*1024 + p], accG[q]);
        if (p < C1*HID) atomicAdd(&x2[((size_t)b*C1 + cX[q])*HID + dX[q]], accX[q]);
    }
}

// ---------- fused tail: finalize + pool-conv2 + diffpool2 + per-graph MLP + reg (last block) ----------
__global__ void k_tail(const float* __restrict__ x2, const float* __restrict__ adj2,
                       const float* __restrict__ Gm,
                       const float* __restrict__ Wp2, const float* __restrict__ asp,
                       const float* __restrict__ adp, const float* __restrict__ Wep2,
                       const float* __restrict__ Wf1, const float* __restrict__ bf1,
                       const float* __restrict__ Wf2, const float* __restrict__ bf2,
                       float* __restrict__ out, float* __restrict__ scal,
                       unsigned int* __restrict__ ctr){
    int b = blockIdx.x;
    int t = threadIdx.x;  // 256
    __shared__ float x2s[C1*HID];    // 960
    __shared__ float a2s[C1*C1];     // 1024
    __shared__ float Wps[HID*C2];    // 120
    __shared__ float h2s[C1*C2];
    __shared__ float hs2s[C1], hd2s[C1];
    __shared__ float sss[C1*C2];     // softmax(s2)
    __shared__ float x3s[C2*HID];    // 120
    __shared__ float zsh[32];
    __shared__ float red[256];
    for (int i = t; i < C1*HID; i += 256) x2s[i] = x2[(size_t)b*C1*HID + i];
    for (int i = t; i < C1*C1; i += 256) a2s[i] = adj2[(size_t)b*C1*C1 + i];
    if (t < HID*C2) Wps[t] = Wp2[t];
    __syncthreads();
    // finalize reg1 ingredients from this graph: trace(adj2), ||G||_F^2
    {
        float ltr = 0.f, lfr = 0.f;
        for (int p = t; p < 1024; p += 256){
            float g = Gm[(size_t)b*1024 + p];
            lfr += g*g;
            if ((p >> 5) == (p & 31)) ltr += a2s[p];
        }
        red[t] = ltr; __syncthreads();
        for (int s = 128; s > 0; s >>= 1){ if (t < s) red[t] += red[t+s]; __syncthreads(); }
        if (t == 0) atomicAdd(&scal[1], red[0]);
        __syncthreads();
        red[t] = lfr; __syncthreads();
        for (int s = 128; s > 0; s >>= 1){ if (t < s) red[t] += red[t+s]; __syncthreads(); }
        if (t == 0) atomicAdd(&scal[2], red[0]);
        __syncthreads();
    }
    // phase 1: h2 = x2@Wp2 + attention scalars
    if (t < C1){
        float s = 0.f, dd = 0.f;
        #pragma unroll
        for (int c = 0; c < C2; c++){
            float a = 0.f;
            #pragma unroll
            for (int d = 0; d < HID; d++) a += x2s[t*HID + d]*Wps[d*C2 + c];
            h2s[t*C2 + c] = a;
            s += a*asp[c]; dd += a*adp[c];
        }
        hs2s[t] = s; hd2s[t] = dd;
    }
    __syncthreads();
    // phase 2: dense EGAT agg over 32 sources + softmax over C2
    if (t < C1){
        int j = t;
        float hdv = hd2s[j];
        float wep = Wep2[0];
        float m = -INFINITY;
        for (int i = 0; i < C1; i++)
            m = fmaxf(m, lrelu(hs2s[i] + hdv + a2s[i*C1 + j]*wep));
        float den = 0.f;
        float acc[C2] = {0,0,0,0};
        for (int i = 0; i < C1; i++){
            float ex = expf(lrelu(hs2s[i] + hdv + a2s[i*C1 + j]*wep) - m);
            den += ex;
            #pragma unroll
            for (int c = 0; c < C2; c++) acc[c] += ex * h2s[i*C2 + c];
        }
        float inv = 1.f/(den + 1e-16f);
        float v[C2]; float mx = -INFINITY;
        #pragma unroll
        for (int c = 0; c < C2; c++){ v[c] = acc[c]*inv; mx = fmaxf(mx, v[c]); }
        float sum = 0.f;
        #pragma unroll
        for (int c = 0; c < C2; c++){ v[c] = expf(v[c] - mx); sum += v[c]; }
        float i2 = 1.f/sum;
        #pragma unroll
        for (int c = 0; c < C2; c++) sss[j*C2 + c] = v[c]*i2;
    }
    __syncthreads();
    // phase 3: x3 = S^T x2 (LDS only) and reg2
    if (t < C2*HID){
        int c = t / HID, d = t % HID;
        float a = 0.f;
        #pragma unroll
        for (int n = 0; n < C1; n++) a += sss[n*C2 + c]*x2s[n*HID + d];
        x3s[t] = a;
    }
    {
        float loc = 0.f;
        for (int p = t; p < 1024; p += 256){
            int n = p >> 5, mm = p & 31;
            float dot = 0.f;
            #pragma unroll
            for (int c = 0; c < C2; c++) dot += sss[n*C2 + c]*sss[mm*C2 + c];
            float df = a2s[p] - dot;
            loc += df*df;
        }
        red[t] = loc; __syncthreads();
        for (int s = 128; s > 0; s >>= 1){ if (t < s) red[t] += red[t+s]; __syncthreads(); }
        if (t == 0) atomicAdd(&scal[3], red[0]);
        __syncthreads();
    }
    // phase 4: per-graph MLP -> out[2b], out[2b+1]
    if (t < 32){
        float a = bf1[t];
        #pragma unroll 4
        for (int k = 0; k < C2*HID; k++) a += x3s[k]*Wf1[k*32 + t];
        zsh[t] = fmaxf(a, 0.f);
    }
    __syncthreads();
    if (t < 2){
        float a = bf2[t];
        #pragma unroll
        for (int j = 0; j < 32; j++) a += zsh[j]*Wf2[j*2 + t];
        out[b*2 + t] = a;
    }
    // phase 5: last finished block assembles the reg scalar
    if (t == 0){
        __threadfence();
        unsigned int old = atomicAdd(ctr, 1u);
        if (old == NB - 1){
            float adjsum = atomicAdd(&scal[0], 0.f);
            float tr     = atomicAdd(&scal[1], 0.f);
            float fr     = atomicAdd(&scal[2], 0.f);
            float r2     = atomicAdd(&scal[3], 0.f);
            float reg1 = (adjsum - 2.f*tr + fr) * (1.f/16777216.f);
            float reg2 = r2 * (1.f/16384.f);
            out[32] = 10.f*reg1 + 0.1f*reg2;
        }
    }
}

extern "C" void kernel_launch(void* const* d_in, const int* in_sizes, int n_in,
                              void* d_out, int out_size, void* d_ws, size_t ws_size,
                              hipStream_t stream) {
    const float* x    = (const float*)d_in[0];
    const int*   ei   = (const int*)d_in[1];
    const float* ea   = (const float*)d_in[2];
    // d_in[3] = y (unused); d_in[4] = adj (algebraically eliminated — never read)
    const float* W1   = (const float*)d_in[5];
    const float* as1  = (const float*)d_in[6];
    const float* ad1  = (const float*)d_in[7];
    const float* We1  = (const float*)d_in[8];
    const float* Wp1  = (const float*)d_in[9];
    const float* asp1 = (const float*)d_in[10];
    const float* adp1 = (const float*)d_in[11];
    const float* Wep1 = (const float*)d_in[12];
    const float* Wp2  = (const float*)d_in[13];
    const float* asp2 = (const float*)d_in[14];
    const float* adp2 = (const float*)d_in[15];
    const float* Wep2 = (const float*)d_in[16];
    const float* Wf1  = (const float*)d_in[17];
    const float* bf1  = (const float*)d_in[18];
    const float* Wf2  = (const float*)d_in[19];
    const float* bf2  = (const float*)d_in[20];
    float* out = (float*)d_out;

    const int* srcA = ei;
    const int* dstA = ei + EE;

    char* wp = (char*)d_ws;
    auto carve = [&](size_t bytes)->char*{
        char* p = wp;
        wp += (bytes + 255) & ~(size_t)255;
        return p;
    };
    float* h1    = (float*)carve((size_t)NN*HID*4);
    float* hs1   = (float*)carve((size_t)NN*NHEADS*4);
    float* hd1   = (float*)carve((size_t)NN*NHEADS*4);
    float* lg1T  = (float*)carve((size_t)EE*NHEADS*4);
    float* ewp1s = (float*)carve((size_t)EE*4);
    float* x1    = (float*)carve((size_t)NN*HID*4);
    float* hp1   = (float*)carve((size_t)NN*C1*4);
    float* hsp   = (float*)carve((size_t)NN*4);
    float* hdp   = (float*)carve((size_t)NN*4);
    float* ssoft = (float*)carve((size_t)NN*C1*4);
    float* T     = (float*)carve((size_t)NN*C1*4);
    // --- zero-init region (contiguous): x2, adj2, Gm ---
    float* x2    = (float*)carve((size_t)NB*C1*HID*4);   // 61440 B (256-aligned)
    float* adj2  = (float*)carve((size_t)NB*C1*C1*4);    // 65536 B
    float* Gm    = (float*)carve((size_t)NB*C1*C1*4);    // 65536 B
    // ---------------------------------------------------
    float* scal  = (float*)carve(16*4);                  // [0..3] sums, [8] ctr
    unsigned int* ctr = (unsigned int*)(scal + 8);
    int* histD   = (int*)carve((size_t)NB*CH*NPG*4);     // 1 MB
    int* histS   = (int*)carve((size_t)NB*CH*NPG*4);     // 1 MB
    int* rowptr  = (int*)carve((size_t)(NN+1)*4);
    int* rowptrS = (int*)carve((size_t)(NN+1)*4);
    int* srcs    = (int*)carve((size_t)EE*4);
    int* eid     = (int*)carve((size_t)EE*4);
    int* dsts    = (int*)carve((size_t)EE*4);
    int* nbrS    = (int*)carve((size_t)EE*4);
    int* unbr    = (int*)carve((size_t)EE*4);
    int* ucnt    = (int*)carve((size_t)NN*4);

    hipMemsetAsync(scal, 0, 16*4, stream);
    hipMemsetAsync(x2, 0, (size_t)(NB*C1*HID + 2*NB*C1*C1)*4, stream);  // x2+adj2+Gm

    const int TB = 256;

    // merged: per-chunk dual LDS histograms (256 blocks) + node projection (64 blocks)
    k_hist_chunk<<<dim3(256 + 64), TB, 0, stream>>>(srcA, dstA, histD, histS,
                                                    x, W1, as1, ad1, h1, hs1, hd1);
    // fused chunk-scan + per-graph node scan -> rowptr/rowptrS
    k_cumscan<<<dim3(2*NB), 1024, 0, stream>>>(histD, histS, rowptr, rowptrS);
    // deterministic scatter (LDS atomics only)
    k_scatter_det<<<dim3(256), TB, 0, stream>>>(srcA, dstA, rowptr, rowptrS,
                                                histD, histS, srcs, eid, dsts, nbrS);

    // edge proj + conv1 logit planes
    k_elogit<<<dim3(2048), TB, 0, stream>>>(ea, We1, Wep1, srcs, eid, dsts, hs1, hd1, lg1T, ewp1s);

    // conv1: graph-local h1 staged in LDS (256 blocks x 640 threads)
    k_conv1_agg<<<dim3(256), 640, 0, stream>>>(srcs, rowptr, h1, lg1T, x1);

    // merged: pool-conv1 prep (64 blocks) + dedup (64 blocks, concurrent)
    k_pd<<<dim3(128), TB, 0, stream>>>(x1, Wp1, asp1, adp1, hp1, hsp, hdp,
                                       rowptrS, nbrS, unbr, ucnt, scal);

    // pool-conv1: inline logits + graph-local LDS staging + fused cluster softmax
    k_pool1_agg<<<dim3(256), 512, 0, stream>>>(srcs, rowptr, hp1, hsp, hdp, ewp1s, ssoft);

    // diffpool1 (T with graph-local LDS staging)
    k_T<<<dim3(256), 512, 0, stream>>>(rowptrS, unbr, ucnt, ssoft, T);
    k_partials<<<dim3(16, NB), TB, 0, stream>>>(ssoft, T, x1, adj2, Gm, x2);

    // fused tail: finalize + pool-conv2 + diffpool2 + per-graph MLP + reg assembly
    k_tail<<<dim3(NB), TB, 0, stream>>>(x2, adj2, Gm, Wp2, asp2, adp2, Wep2,
                                        Wf1, bf1, Wf2, bf2, out, scal, ctr);
}